// Round 1
// baseline (878.686 us; speedup 1.0000x reference)
//
#include <hip/hip_runtime.h>
#include <math.h>

#define NPED 8192
#define OBS 8

// ---- workspace layout (float offsets) ----
#define WS_WIHE   0          // 1024   Wih@pe_w  [512][2]
#define WS_BEFF   1024       // 512    bih+bhh+Wih@pe_b
#define WS_WK2    1536       // 8192   wk@rp_w2  [128][64]
#define WS_WV2T   9728       // 8192   (wv@rp_w2)^T [64][128]
#define WS_BQKV   17920      // 384    [bq | bk+wk@rp_b2 | bv+wv@rp_b2]
#define WS_WQKVT  18304      // 49152  [128][384] transposed [wq|wk|wv]
#define WS_WOT    67456      // 16384  wo^T [128][128]
#define WS_OPWT   83840      // 32768  op_w^T [256][128]
#define WS_MPW1T  116608     // 32768  mp_w1^T [256][128]
#define WS_TDW1T  149376     // 163840 per-mode [256][128]
#define WS_TDW2T  313216     // 81920  per-mode [128][128]
#define WS_FEAT   395136     // 1048576  node_features [8192][128]
#define WS_QKV    1443712    // 3145728  [8192][384]: Q(->ctx) | K0(->AO) | V0(->EDGE)
#define WS_H1     4589440    // 1048576
#define WS_TD2    5638016    // 1048576
// end: 6686592 floats = 25.5 MiB

__global__ __launch_bounds__(256) void prep1(
    const float* __restrict__ wih, const float* __restrict__ bih, const float* __restrict__ bhh,
    const float* __restrict__ pew, const float* __restrict__ peb,
    const float* __restrict__ wk, const float* __restrict__ wv,
    const float* __restrict__ rpw2, const float* __restrict__ rpb2,
    const float* __restrict__ bq, const float* __restrict__ bk, const float* __restrict__ bv,
    float* __restrict__ ws) {
  int tid = blockIdx.x * 256 + threadIdx.x;
  if (tid < 512) {
    int d = tid;
    float s0 = 0.f, s1 = 0.f, sb = 0.f;
    for (int e = 0; e < 64; ++e) {
      float w = wih[d * 64 + e];
      s0 += w * pew[e * 2]; s1 += w * pew[e * 2 + 1]; sb += w * peb[e];
    }
    ws[WS_WIHE + d * 2] = s0; ws[WS_WIHE + d * 2 + 1] = s1;
    ws[WS_BEFF + d] = bih[d] + bhh[d] + sb;
  } else if (tid < 8704) {            // wk2 [128][64]
    int idx = tid - 512; int d = idx >> 6, e = idx & 63;
    float s = 0.f;
    for (int c = 0; c < 128; ++c) s += wk[d * 128 + c] * rpw2[c * 64 + e];
    ws[WS_WK2 + idx] = s;
  } else if (tid < 16896) {           // wv2T [64][128]
    int idx = tid - 8704; int e = idx >> 7, hd = idx & 127;
    float s = 0.f;
    for (int c = 0; c < 128; ++c) s += wv[hd * 128 + c] * rpw2[c * 64 + e];
    ws[WS_WV2T + idx] = s;
  } else if (tid < 17024) {           // bk_eff
    int d = tid - 16896;
    float s = bk[d];
    for (int c = 0; c < 128; ++c) s += wk[d * 128 + c] * rpb2[c];
    ws[WS_BQKV + 128 + d] = s;
  } else if (tid < 17152) {           // bv_eff
    int d = tid - 17024;
    float s = bv[d];
    for (int c = 0; c < 128; ++c) s += wv[d * 128 + c] * rpb2[c];
    ws[WS_BQKV + 256 + d] = s;
  } else if (tid < 17280) {           // bq copy
    int d = tid - 17152;
    ws[WS_BQKV + d] = bq[d];
  }
}

__global__ __launch_bounds__(256) void prep2(
    const float* __restrict__ wq, const float* __restrict__ wk, const float* __restrict__ wv,
    const float* __restrict__ wo, const float* __restrict__ opw, const float* __restrict__ mpw1,
    const float* __restrict__ tdw1, const float* __restrict__ tdw2, float* __restrict__ ws) {
  int tid = blockIdx.x * 256 + threadIdx.x;
  if (tid < 49152) {                  // wqkvT [128][384]
    int k = tid / 384, c = tid % 384;
    const float* src = (c < 128) ? wq : (c < 256) ? wk : wv;
    ws[WS_WQKVT + tid] = src[(c & 127) * 128 + k];
  } else if (tid < 65536) {           // woT [128][128]
    int idx = tid - 49152; int k = idx >> 7, c = idx & 127;
    ws[WS_WOT + idx] = wo[c * 128 + k];
  } else if (tid < 98304) {           // opwT [256][128]
    int idx = tid - 65536; int k = idx >> 7, c = idx & 127;
    ws[WS_OPWT + idx] = opw[c * 256 + k];
  } else if (tid < 131072) {          // mpw1T [256][128]
    int idx = tid - 98304; int k = idx >> 7, c = idx & 127;
    ws[WS_MPW1T + idx] = mpw1[c * 256 + k];
  } else if (tid < 294912) {          // tdw1T [5][256][128]
    int idx = tid - 131072; int m = idx >> 15, r = idx & 32767;
    int k = r >> 7, c = r & 127;
    ws[WS_TDW1T + idx] = tdw1[(m * 128 + c) * 256 + k];
  } else if (tid < 376832) {          // tdw2T [5][128][128]
    int idx = tid - 294912; int m = idx >> 14, r = idx & 16383;
    int k = r >> 7, c = r & 127;
    ws[WS_TDW2T + idx] = tdw2[(m * 128 + c) * 128 + k];
  }
}

// LSTM: one block = 32 peds, all 8 timesteps in-block. 512 threads.
// thread t: pg = t>>5 (2 peds: pg*2, pg*2+1), dg = t&31 (4 h-dims dg*4..+3), 4 gates.
__global__ __launch_bounds__(512) void lstm_kernel(
    const float* __restrict__ obs, const float* __restrict__ whh,
    const float* __restrict__ ws, float* __restrict__ feat) {
  __shared__ float Wt[16][516];   // [k within chunk][512 gate dims]
  __shared__ float Hs[32][129];
  const float* wihe = ws + WS_WIHE;
  const float* beff = ws + WS_BEFF;
  int t = threadIdx.x;
  int pg = t >> 5, dg = t & 31;
  int nb = blockIdx.x * 32;
  int p0 = nb + pg * 2, p1 = p0 + 1;

  float wx0[4][4], wx1[4][4], be[4][4];
#pragma unroll
  for (int g = 0; g < 4; ++g)
#pragma unroll
    for (int j = 0; j < 4; ++j) {
      int gd = g * 128 + dg * 4 + j;
      wx0[g][j] = wihe[gd * 2]; wx1[g][j] = wihe[gd * 2 + 1]; be[g][j] = beff[gd];
    }
  for (int idx = t; idx < 4096; idx += 512) Hs[idx >> 7][idx & 127] = 0.f;
  float cc[2][4] = {{0.f,0.f,0.f,0.f},{0.f,0.f,0.f,0.f}};
  __syncthreads();

  for (int ts = 0; ts < 8; ++ts) {
    float ox0 = obs[ts * 16384 + p0 * 2], oy0 = obs[ts * 16384 + p0 * 2 + 1];
    float ox1 = obs[ts * 16384 + p1 * 2], oy1 = obs[ts * 16384 + p1 * 2 + 1];
    float acc[2][4][4];
#pragma unroll
    for (int g = 0; g < 4; ++g)
#pragma unroll
      for (int j = 0; j < 4; ++j) {
        acc[0][g][j] = be[g][j] + wx0[g][j] * ox0 + wx1[g][j] * oy0;
        acc[1][g][j] = be[g][j] + wx0[g][j] * ox1 + wx1[g][j] * oy1;
      }
    for (int kc = 0; kc < 8; ++kc) {
      __syncthreads();
      {
        const float4* src = (const float4*)(whh + t * 128 + kc * 16);
#pragma unroll
        for (int j4 = 0; j4 < 4; ++j4) {
          float4 v = src[j4];
          Wt[j4 * 4 + 0][t] = v.x; Wt[j4 * 4 + 1][t] = v.y;
          Wt[j4 * 4 + 2][t] = v.z; Wt[j4 * 4 + 3][t] = v.w;
        }
      }
      __syncthreads();
#pragma unroll 4
      for (int kk = 0; kk < 16; ++kk) {
        float h0 = Hs[pg * 2][kc * 16 + kk];
        float h1 = Hs[pg * 2 + 1][kc * 16 + kk];
#pragma unroll
        for (int g = 0; g < 4; ++g) {
          float4 w = *(const float4*)&Wt[kk][g * 128 + dg * 4];
          acc[0][g][0] += h0 * w.x; acc[0][g][1] += h0 * w.y;
          acc[0][g][2] += h0 * w.z; acc[0][g][3] += h0 * w.w;
          acc[1][g][0] += h1 * w.x; acc[1][g][1] += h1 * w.y;
          acc[1][g][2] += h1 * w.z; acc[1][g][3] += h1 * w.w;
        }
      }
    }
    __syncthreads();
#pragma unroll
    for (int p = 0; p < 2; ++p)
#pragma unroll
      for (int j = 0; j < 4; ++j) {
        float ig = 1.f / (1.f + expf(-acc[p][0][j]));
        float fg = 1.f / (1.f + expf(-acc[p][1][j]));
        float gg = tanhf(acc[p][2][j]);
        float og = 1.f / (1.f + expf(-acc[p][3][j]));
        cc[p][j] = fg * cc[p][j] + ig * gg;
        float h = og * tanhf(cc[p][j]);
        Hs[pg * 2 + p][dg * 4 + j] = h;
        if (ts == 7) feat[(size_t)(nb + pg * 2 + p) * 128 + dg * 4 + j] = h;
      }
  }
}

// Generic fp32 GEMM: out[M][*] tile 32x128. A = [A1 | A2] along K (pre-transposed WT [K][ldw]).
__global__ __launch_bounds__(256) void gemm_kernel(
    const float* A1, const float* A2, int K1, int K, int lda1, int lda2,
    const float* __restrict__ WT, int ldw, const float* __restrict__ bias,
    float* out, int ldo, int ooff, int relu) {
  __shared__ float As[64][40];
  __shared__ float Ws[64][132];
  int t = threadIdx.x;
  int row0 = blockIdx.x * 32, col0 = blockIdx.y * 128;
  int pg = t >> 5, ocg = t & 31;
  float acc[4][4] = {};
  for (int kb = 0; kb < K; kb += 64) {
    __syncthreads();
    for (int idx = t; idx < 2048; idx += 256) {
      int k = idx & 63, p = idx >> 6;
      int kg = kb + k;
      float v = (kg < K1) ? A1[(size_t)(row0 + p) * lda1 + kg]
                          : A2[(size_t)(row0 + p) * lda2 + (kg - K1)];
      As[k][p] = v;
    }
    for (int idx = t; idx < 8192; idx += 256) {
      int c = idx & 127, k = idx >> 7;
      Ws[k][c] = WT[(size_t)(kb + k) * ldw + col0 + c];
    }
    __syncthreads();
#pragma unroll 4
    for (int k = 0; k < 64; ++k) {
      float4 w = *(const float4*)&Ws[k][ocg * 4];
      float4 a = *(const float4*)&As[k][pg * 4];
      acc[0][0] += a.x * w.x; acc[0][1] += a.x * w.y; acc[0][2] += a.x * w.z; acc[0][3] += a.x * w.w;
      acc[1][0] += a.y * w.x; acc[1][1] += a.y * w.y; acc[1][2] += a.y * w.z; acc[1][3] += a.y * w.w;
      acc[2][0] += a.z * w.x; acc[2][1] += a.z * w.y; acc[2][2] += a.z * w.z; acc[2][3] += a.z * w.w;
      acc[3][0] += a.w * w.x; acc[3][1] += a.w * w.y; acc[3][2] += a.w * w.z; acc[3][3] += a.w * w.w;
    }
  }
  float4 bv = make_float4(0.f, 0.f, 0.f, 0.f);
  if (bias) bv = *(const float4*)&bias[col0 + ocg * 4];
#pragma unroll
  for (int i = 0; i < 4; ++i) {
    float4 o;
    o.x = acc[i][0] + bv.x; o.y = acc[i][1] + bv.y;
    o.z = acc[i][2] + bv.z; o.w = acc[i][3] + bv.w;
    if (relu) {
      o.x = fmaxf(o.x, 0.f); o.y = fmaxf(o.y, 0.f);
      o.z = fmaxf(o.z, 0.f); o.w = fmaxf(o.w, 0.f);
    }
    *(float4*)(out + (size_t)(row0 + pg * 4 + i) * ldo + ooff + col0 + ocg * 4) = o;
  }
}

// attention: block = (scene, 4 query peds). ctx written into QKV col 0 (Q slot).
__global__ __launch_bounds__(256) void attn_kernel(
    const float* __restrict__ obs, float* QKV, const float* __restrict__ ws,
    const float* __restrict__ rpw1, const float* __restrict__ rpb1) {
  __shared__ float renc[4][32][65];
  __shared__ float K0s[32][129];
  __shared__ float Qi[4][128];
  __shared__ float QW[4][4][64];
  __shared__ float att[4][4][32];
  __shared__ float AR[4][4][64];
  __shared__ float posS[32][2];
  __shared__ float posI[4][2];
  const float* wk2 = ws + WS_WK2;
  const float* wv2T = ws + WS_WV2T;
  int t = threadIdx.x;
  int scene = blockIdx.x >> 3, ic = blockIdx.x & 7;
  int i0 = ic * 4, sbase = scene * 32;

  for (int idx = t; idx < 4096; idx += 256) {
    int j = idx >> 7, d = idx & 127;
    K0s[j][d] = QKV[(size_t)(sbase + j) * 384 + 128 + d];
  }
  for (int idx = t; idx < 512; idx += 256) {
    int ii = idx >> 7, d = idx & 127;
    Qi[ii][d] = QKV[(size_t)(sbase + i0 + ii) * 384 + d];
  }
  if (t < 64) posS[t >> 1][t & 1] = obs[7 * 16384 + (sbase + (t >> 1)) * 2 + (t & 1)];
  if (t >= 64 && t < 72) {
    int q = t - 64;
    posI[q >> 1][q & 1] = obs[7 * 16384 + (sbase + i0 + (q >> 1)) * 2 + (q & 1)];
  }
  __syncthreads();
  for (int idx = t; idx < 1024; idx += 256) {
    int ii = idx >> 8, h = (idx >> 6) & 3, e = idx & 63;
    float s = 0.f;
    for (int d = 0; d < 32; ++d) s += Qi[ii][h * 32 + d] * wk2[(h * 32 + d) * 64 + e];
    QW[ii][h][e] = s;
  }
  for (int idx = t; idx < 8192; idx += 256) {
    int ii = idx >> 11, j = (idx >> 6) & 31, e = idx & 63;
    float rx = posS[j][0] - posI[ii][0], ry = posS[j][1] - posI[ii][1];
    renc[ii][j][e] = fmaxf(rpw1[e * 2] * rx + rpw1[e * 2 + 1] * ry + rpb1[e], 0.f);
  }
  __syncthreads();
  for (int idx = t; idx < 512; idx += 256) {
    int ii = idx >> 7, h = (idx >> 5) & 3, j = idx & 31;
    float s = 0.f;
    for (int d = 0; d < 32; ++d) s += Qi[ii][h * 32 + d] * K0s[j][h * 32 + d];
    for (int e = 0; e < 64; ++e) s += QW[ii][h][e] * renc[ii][j][e];
    att[ii][h][j] = s * 0.1767766952966369f;   // 1/sqrt(32)
  }
  __syncthreads();
  {
    int r = t >> 4, l = t & 15;
    float v0 = att[r >> 2][r & 3][l], v1 = att[r >> 2][r & 3][l + 16];
    float mx = fmaxf(v0, v1);
    mx = fmaxf(mx, __shfl_xor(mx, 8, 16));
    mx = fmaxf(mx, __shfl_xor(mx, 4, 16));
    mx = fmaxf(mx, __shfl_xor(mx, 2, 16));
    mx = fmaxf(mx, __shfl_xor(mx, 1, 16));
    float e0 = expf(v0 - mx), e1 = expf(v1 - mx);
    float sm = e0 + e1;
    sm += __shfl_xor(sm, 8, 16);
    sm += __shfl_xor(sm, 4, 16);
    sm += __shfl_xor(sm, 2, 16);
    sm += __shfl_xor(sm, 1, 16);
    float inv = 1.f / sm;
    att[r >> 2][r & 3][l] = e0 * inv;
    att[r >> 2][r & 3][l + 16] = e1 * inv;
  }
  __syncthreads();
  for (int idx = t; idx < 1024; idx += 256) {
    int ii = idx >> 8, h = (idx >> 6) & 3, e = idx & 63;
    float s = 0.f;
    for (int j = 0; j < 32; ++j) s += att[ii][h][j] * renc[ii][j][e];
    AR[ii][h][e] = s;
  }
  __syncthreads();
  for (int idx = t; idx < 512; idx += 256) {
    int ii = idx >> 7, hd = idx & 127, h = hd >> 5;
    float s = 0.f;
    for (int j = 0; j < 32; ++j) s += att[ii][h][j] * QKV[(size_t)(sbase + j) * 384 + 256 + hd];
    for (int e = 0; e < 64; ++e) s += AR[ii][h][e] * wv2T[e * 128 + hd];
    QKV[(size_t)(sbase + i0 + ii) * 384 + hd] = s;   // ctx overwrites Q (safe: per-block rows)
  }
}

__global__ __launch_bounds__(256) void probs_kernel(
    const float* __restrict__ H1, const float* __restrict__ mpw2,
    const float* __restrict__ mpb2, float* __restrict__ out) {
  __shared__ float Hs[64][129];
  __shared__ float lg[64][5];
  int t = threadIdx.x, nb = blockIdx.x * 64;
  for (int idx = t; idx < 8192; idx += 256) Hs[idx >> 7][idx & 127] = H1[(size_t)nb * 128 + idx];
  __syncthreads();
  for (int idx = t; idx < 320; idx += 256) {
    int p = idx / 5, m = idx % 5;
    float s = mpb2[m];
    for (int k = 0; k < 128; ++k) s += Hs[p][k] * mpw2[m * 128 + k];
    lg[p][m] = s;
  }
  __syncthreads();
  if (t < 64) {
    float m0 = lg[t][0];
#pragma unroll
    for (int j = 1; j < 5; ++j) m0 = fmaxf(m0, lg[t][j]);
    float e[5], s = 0.f;
#pragma unroll
    for (int j = 0; j < 5; ++j) { e[j] = expf(lg[t][j] - m0); s += e[j]; }
    float inv = 1.f / s;
#pragma unroll
    for (int j = 0; j < 5; ++j) out[983040 + (size_t)(nb + t) * 5 + j] = e[j] * inv;
  }
}

__global__ __launch_bounds__(256) void traj_kernel(
    const float* __restrict__ TD2, const float* __restrict__ tdw3,
    const float* __restrict__ tdb3, const float* __restrict__ obs,
    float* __restrict__ out, int m) {
  __shared__ float Hs[64][129];
  __shared__ float tr[64][25];
  int t = threadIdx.x, nb = blockIdx.x * 64;
  for (int idx = t; idx < 8192; idx += 256) Hs[idx >> 7][idx & 127] = TD2[(size_t)nb * 128 + idx];
  __syncthreads();
  for (int idx = t; idx < 1536; idx += 256) {
    int p = idx / 24, o = idx % 24;
    float s = tdb3[m * 24 + o];
    for (int k = 0; k < 128; ++k) s += Hs[p][k] * tdw3[(m * 24 + o) * 128 + k];
    tr[p][o] = s;
  }
  __syncthreads();
  if (t < 128) {
    int p = t >> 1, c = t & 1, n = nb + p;
    float run = obs[7 * 16384 + n * 2 + c];
#pragma unroll
    for (int j = 0; j < 12; ++j) {
      run += tr[p][j * 2 + c];
      out[(size_t)n * 120 + m * 24 + j * 2 + c] = run;
    }
  }
}

extern "C" void kernel_launch(void* const* d_in, const int* in_sizes, int n_in,
                              void* d_out, int out_size, void* d_ws, size_t ws_size,
                              hipStream_t stream) {
  (void)in_sizes; (void)n_in; (void)out_size; (void)ws_size;
  const float* obs  = (const float*)d_in[0];
  const float* pew  = (const float*)d_in[1];
  const float* peb  = (const float*)d_in[2];
  const float* wih  = (const float*)d_in[3];
  const float* bih  = (const float*)d_in[4];
  const float* whh  = (const float*)d_in[5];
  const float* bhh  = (const float*)d_in[6];
  const float* rpw1 = (const float*)d_in[7];
  const float* rpb1 = (const float*)d_in[8];
  const float* rpw2 = (const float*)d_in[9];
  const float* rpb2 = (const float*)d_in[10];
  const float* wq   = (const float*)d_in[11];
  const float* bq   = (const float*)d_in[12];
  const float* wk   = (const float*)d_in[13];
  const float* bk   = (const float*)d_in[14];
  const float* wv   = (const float*)d_in[15];
  const float* bv   = (const float*)d_in[16];
  const float* wo   = (const float*)d_in[17];
  const float* bo   = (const float*)d_in[18];
  const float* opw  = (const float*)d_in[19];
  const float* opb  = (const float*)d_in[20];
  const float* mpw1 = (const float*)d_in[21];
  const float* mpb1 = (const float*)d_in[22];
  const float* mpw2 = (const float*)d_in[23];
  const float* mpb2 = (const float*)d_in[24];
  const float* tdw1 = (const float*)d_in[25];
  const float* tdb1 = (const float*)d_in[26];
  const float* tdw2 = (const float*)d_in[27];
  const float* tdb2 = (const float*)d_in[28];
  const float* tdw3 = (const float*)d_in[29];
  const float* tdb3 = (const float*)d_in[30];
  float* ws  = (float*)d_ws;
  float* out = (float*)d_out;

  prep1<<<68, 256, 0, stream>>>(wih, bih, bhh, pew, peb, wk, wv, rpw2, rpb2, bq, bk, bv, ws);
  prep2<<<1472, 256, 0, stream>>>(wq, wk, wv, wo, opw, mpw1, tdw1, tdw2, ws);
  lstm_kernel<<<256, 512, 0, stream>>>(obs, whh, ws, ws + WS_FEAT);
  // QKV = feat @ [wq|wk|wv]^T + [bq|bk_eff|bv_eff]
  gemm_kernel<<<dim3(256, 3), 256, 0, stream>>>(ws + WS_FEAT, nullptr, 128, 128, 128, 0,
      ws + WS_WQKVT, 384, ws + WS_BQKV, ws + WS_QKV, 384, 0, 0);
  attn_kernel<<<2048, 256, 0, stream>>>(obs, ws + WS_QKV, ws, rpw1, rpb1);
  // AO = ctx @ wo^T + bo  (into K0 slot)
  gemm_kernel<<<dim3(256, 1), 256, 0, stream>>>(ws + WS_QKV, nullptr, 128, 128, 384, 0,
      ws + WS_WOT, 128, bo, ws + WS_QKV, 384, 128, 0);
  // EDGE = [feat|AO] @ op_w^T + op_b (into V0 slot)
  gemm_kernel<<<dim3(256, 1), 256, 0, stream>>>(ws + WS_FEAT, ws + WS_QKV + 128, 128, 256, 128, 384,
      ws + WS_OPWT, 128, opb, ws + WS_QKV, 384, 256, 0);
  // H1 = relu([feat|EDGE] @ mp_w1^T + mp_b1)
  gemm_kernel<<<dim3(256, 1), 256, 0, stream>>>(ws + WS_FEAT, ws + WS_QKV + 256, 128, 256, 128, 384,
      ws + WS_MPW1T, 128, mpb1, ws + WS_H1, 128, 0, 1);
  probs_kernel<<<128, 256, 0, stream>>>(ws + WS_H1, mpw2, mpb2, out);
  for (int m = 0; m < 5; ++m) {
    gemm_kernel<<<dim3(256, 1), 256, 0, stream>>>(ws + WS_FEAT, ws + WS_QKV + 256, 128, 256, 128, 384,
        ws + WS_TDW1T + m * 32768, 128, tdb1 + m * 128, ws + WS_H1, 128, 0, 1);
    gemm_kernel<<<dim3(256, 1), 256, 0, stream>>>(ws + WS_H1, nullptr, 128, 128, 128, 0,
        ws + WS_TDW2T + m * 16384, 128, tdb2 + m * 128, ws + WS_TD2, 128, 0, 1);
    traj_kernel<<<128, 256, 0, stream>>>(ws + WS_TD2, tdw3, tdb3, obs, out, m);
  }
}

// Round 2
// 370.605 us; speedup vs baseline: 2.3709x; 2.3709x over previous
//
#include <hip/hip_runtime.h>
#include <math.h>

typedef __attribute__((ext_vector_type(8))) short short8;
typedef __attribute__((ext_vector_type(4))) float f32x4;

#define NPED 8192

// ---- workspace layout (BYTE offsets) ----
#define B_WHH    0          // [512][128] bf16
#define B_WQKV   131072     // [384][128] bf16  (wq|wk|wv)
#define B_WO     229376     // [128][128] bf16
#define B_OPW    262144     // [128][256] bf16
#define B_MPW1   327680     // [128][256] bf16
#define B_TDW1   393216     // [5][128][256] bf16
#define B_TDW2   720896     // [5][128][128] bf16
#define F_WIHE   884736     // [512][2] f32  Wih@pe_w
#define F_BEFF   888832     // [512]   f32  bih+bhh+Wih@pe_b
#define F_WK2    890880     // [128][64] f32 wk@rp_w2
#define F_WV2T   923648     // [64][128] f32 (wv@rp_w2)^T
#define F_BQKV   956416     // [384] f32  bq | bk_eff | bv_eff
#define A_FEAT   957952     // [8192][128] bf16
#define A_QKV    3055104    // [8192][384] bf16: ctx<-Q | AO<-K0 | EDGE<-V0
#define A_H1MP   9346560    // [8192][128] bf16
#define A_H1TD   11443712   // [5][8192][128] bf16 (TD2 in-place)
// end ~21.9 MB

__device__ __forceinline__ float bf2f(ushort u) {
  union { unsigned i; float f; } v; v.i = ((unsigned)u) << 16; return v.f;
}
__device__ __forceinline__ ushort f2bf(float f) {
  union { float f; unsigned i; } v; v.f = f;
  unsigned r = v.i + 0x7fffu + ((v.i >> 16) & 1u);
  return (ushort)(r >> 16);
}

__global__ __launch_bounds__(256) void prep(
    const float* __restrict__ wih, const float* __restrict__ bih, const float* __restrict__ bhh,
    const float* __restrict__ pew, const float* __restrict__ peb,
    const float* __restrict__ wk, const float* __restrict__ wv,
    const float* __restrict__ rpw2, const float* __restrict__ rpb2,
    const float* __restrict__ bq, const float* __restrict__ bk, const float* __restrict__ bv,
    const float* __restrict__ whh, const float* __restrict__ wq, const float* __restrict__ wo,
    const float* __restrict__ opw, const float* __restrict__ mpw1,
    const float* __restrict__ tdw1, const float* __restrict__ tdw2,
    char* __restrict__ wsb) {
  int tid = blockIdx.x * 256 + threadIdx.x;
  float* wihe = (float*)(wsb + F_WIHE);
  float* beff = (float*)(wsb + F_BEFF);
  float* wk2  = (float*)(wsb + F_WK2);
  float* wv2T = (float*)(wsb + F_WV2T);
  float* bqkv = (float*)(wsb + F_BQKV);
  if (tid < 512) {
    int d = tid;
    float s0 = 0.f, s1 = 0.f, sb = 0.f;
    for (int e = 0; e < 64; ++e) {
      float w = wih[d * 64 + e];
      s0 += w * pew[e * 2]; s1 += w * pew[e * 2 + 1]; sb += w * peb[e];
    }
    wihe[d * 2] = s0; wihe[d * 2 + 1] = s1;
    beff[d] = bih[d] + bhh[d] + sb;
  } else if (tid < 8704) {            // wk2 [128][64]
    int idx = tid - 512; int d = idx >> 6, e = idx & 63;
    float s = 0.f;
    for (int c = 0; c < 128; ++c) s += wk[d * 128 + c] * rpw2[c * 64 + e];
    wk2[idx] = s;
  } else if (tid < 16896) {           // wv2T [64][128]
    int idx = tid - 8704; int e = idx >> 7, hd = idx & 127;
    float s = 0.f;
    for (int c = 0; c < 128; ++c) s += wv[hd * 128 + c] * rpw2[c * 64 + e];
    wv2T[idx] = s;
  } else if (tid < 17024) {
    int d = tid - 16896;
    float s = bk[d];
    for (int c = 0; c < 128; ++c) s += wk[d * 128 + c] * rpb2[c];
    bqkv[128 + d] = s;
  } else if (tid < 17152) {
    int d = tid - 17024;
    float s = bv[d];
    for (int c = 0; c < 128; ++c) s += wv[d * 128 + c] * rpb2[c];
    bqkv[256 + d] = s;
  } else if (tid < 17280) {
    int d = tid - 17152;
    bqkv[d] = bq[d];
  } else if (tid >= 17408) {
    int i = tid - 17408;
    if (i < 65536) {
      ((ushort*)(wsb + B_WHH))[i] = f2bf(whh[i]);
    } else if (i < 114688) {          // wqkv [384][128]
      int j = i - 65536; int n = j >> 7, k = j & 127;
      float v = (n < 128) ? wq[n * 128 + k] : (n < 256) ? wk[(n - 128) * 128 + k] : wv[(n - 256) * 128 + k];
      ((ushort*)(wsb + B_WQKV))[j] = f2bf(v);
    } else if (i < 131072) {
      int j = i - 114688; ((ushort*)(wsb + B_WO))[j] = f2bf(wo[j]);
    } else if (i < 163840) {
      int j = i - 131072; ((ushort*)(wsb + B_OPW))[j] = f2bf(opw[j]);
    } else if (i < 196608) {
      int j = i - 163840; ((ushort*)(wsb + B_MPW1))[j] = f2bf(mpw1[j]);
    } else if (i < 360448) {
      int j = i - 196608; ((ushort*)(wsb + B_TDW1))[j] = f2bf(tdw1[j]);
    } else if (i < 442368) {
      int j = i - 360448; ((ushort*)(wsb + B_TDW2))[j] = f2bf(tdw2[j]);
    }
  }
}

// LSTM: 32 peds/block, 512 thr = 8 waves. Wave w owns gates {q*128 + w*16 + (lane&15)}.
// Whh fragments live in registers for all 8 timesteps. h tile in XOR-swizzled bf16 LDS.
__global__ __launch_bounds__(512) void lstm_mfma(
    const float* __restrict__ obs, const ushort* __restrict__ whhb,
    const float* __restrict__ wihe, const float* __restrict__ beff,
    ushort* __restrict__ feat) {
  __shared__ ushort Hs[32 * 128];
  __shared__ float obs_s[8][32][2];
  int tid = threadIdx.x;
  int w = tid >> 6, l = tid & 63;
  int lm = l & 15, lg = l >> 4;
  int nb = blockIdx.x * 32;
  {
    int ts = tid >> 6, p = (tid >> 1) & 31, c = tid & 1;
    obs_s[ts][p][c] = obs[ts * (NPED * 2) + (nb + p) * 2 + c];
  }
  for (int i = tid; i < 4096; i += 512) Hs[i] = 0;
  short8 bfr[4][4];
  float wx0[4], wx1[4], be[4];
#pragma unroll
  for (int q = 0; q < 4; ++q) {
    int g = q * 128 + w * 16 + lm;
    wx0[q] = wihe[g * 2]; wx1[q] = wihe[g * 2 + 1]; be[q] = beff[g];
#pragma unroll
    for (int ks = 0; ks < 4; ++ks)
      bfr[q][ks] = *(const short8*)(const void*)&whhb[g * 128 + ks * 32 + lg * 8];
  }
  float cst[2][4] = {};
  __syncthreads();
  for (int ts = 0; ts < 8; ++ts) {
    f32x4 acc[2][4];
#pragma unroll
    for (int mi = 0; mi < 2; ++mi)
#pragma unroll
      for (int r = 0; r < 4; ++r) {
        int p = mi * 16 + lg * 4 + r;
        float ox = obs_s[ts][p][0], oy = obs_s[ts][p][1];
#pragma unroll
        for (int q = 0; q < 4; ++q)
          acc[mi][q][r] = be[q] + wx0[q] * ox + wx1[q] * oy;
      }
#pragma unroll
    for (int ks = 0; ks < 4; ++ks) {
      int p0 = lm, p1 = 16 + lm;
      short8 a0 = *(const short8*)(const void*)&Hs[p0 * 128 + ((ks * 32 + lg * 8) ^ ((p0 & 7) << 3))];
      short8 a1 = *(const short8*)(const void*)&Hs[p1 * 128 + ((ks * 32 + lg * 8) ^ ((p1 & 7) << 3))];
#pragma unroll
      for (int q = 0; q < 4; ++q) {
        acc[0][q] = __builtin_amdgcn_mfma_f32_16x16x32_bf16(a0, bfr[q][ks], acc[0][q], 0, 0, 0);
        acc[1][q] = __builtin_amdgcn_mfma_f32_16x16x32_bf16(a1, bfr[q][ks], acc[1][q], 0, 0, 0);
      }
    }
    __syncthreads();
    int d = w * 16 + lm;
#pragma unroll
    for (int mi = 0; mi < 2; ++mi)
#pragma unroll
      for (int r = 0; r < 4; ++r) {
        int p = mi * 16 + lg * 4 + r;
        float xi = acc[mi][0][r], xf = acc[mi][1][r], xg = acc[mi][2][r], xo = acc[mi][3][r];
        float ig = 1.f / (1.f + __expf(-xi));
        float fg = 1.f / (1.f + __expf(-xf));
        xg = fminf(fmaxf(xg, -30.f), 30.f);
        float eg = __expf(-2.f * xg);
        float gg = (1.f - eg) / (1.f + eg);
        float og = 1.f / (1.f + __expf(-xo));
        float cv = fg * cst[mi][r] + ig * gg;
        cst[mi][r] = cv;
        float cvc = fminf(fmaxf(cv, -30.f), 30.f);
        float ec = __expf(-2.f * cvc);
        float th = (1.f - ec) / (1.f + ec);
        ushort hb = f2bf(og * th);
        Hs[p * 128 + (d ^ ((p & 7) << 3))] = hb;
        if (ts == 7) feat[(size_t)(nb + p) * 128 + d] = hb;
      }
    __syncthreads();
  }
}

// MFMA GEMM, direct-from-global. Block = 64 rows x (NF*16) cols, 4 waves stacked in M.
// A = [A1 | A2] concat along K (K1 boundary, 32-aligned). B is [N][K] bf16 (native w layout).
template<int NF>
__global__ __launch_bounds__(256) void mfma_gemm(
    const ushort* __restrict__ A1, int lda1, int K1,
    const ushort* __restrict__ A2, int lda2,
    const ushort* __restrict__ Bw, int K,
    const float* __restrict__ bias,
    ushort* __restrict__ out, int ldo, int ooff, int relu,
    int sB, int sBias, int sA1, int sOut) {
  int w = threadIdx.x >> 6, l = threadIdx.x & 63;
  int lm = l & 15, lg = l >> 4;
  int z = blockIdx.z;
  A1 += (size_t)z * sA1;
  Bw += (size_t)z * sB;
  bias += (size_t)z * sBias;
  out += (size_t)z * sOut;
  int row = blockIdx.x * 64 + w * 16 + lm;
  int col0 = blockIdx.y * (NF * 16);
  f32x4 acc[NF];
#pragma unroll
  for (int i = 0; i < NF; ++i) acc[i] = (f32x4){0.f, 0.f, 0.f, 0.f};
  const int nks = K >> 5;
  for (int ks = 0; ks < nks; ++ks) {
    int kb = ks * 32 + lg * 8;
    const ushort* ap = (ks * 32 < K1) ? (A1 + (size_t)row * lda1 + kb)
                                      : (A2 + (size_t)row * lda2 + (kb - K1));
    short8 af = *(const short8*)(const void*)ap;
#pragma unroll
    for (int ni = 0; ni < NF; ++ni) {
      short8 bf = *(const short8*)(const void*)(Bw + (size_t)(col0 + ni * 16 + lm) * K + kb);
      acc[ni] = __builtin_amdgcn_mfma_f32_16x16x32_bf16(af, bf, acc[ni], 0, 0, 0);
    }
  }
  int orow0 = blockIdx.x * 64 + w * 16 + lg * 4;
#pragma unroll
  for (int ni = 0; ni < NF; ++ni) {
    int c = col0 + ni * 16 + lm;
    float bv = bias[c];
#pragma unroll
    for (int r = 0; r < 4; ++r) {
      float v = acc[ni][r] + bv;
      if (relu) v = fmaxf(v, 0.f);
      out[(size_t)(orow0 + r) * ldo + ooff + c] = f2bf(v);
    }
  }
}

// attention over bf16 QKV; ctx overwrites Q slot.
__global__ __launch_bounds__(256) void attn_kernel(
    const float* __restrict__ obs, ushort* QKV,
    const float* __restrict__ wk2, const float* __restrict__ wv2T,
    const float* __restrict__ rpw1, const float* __restrict__ rpb1) {
  __shared__ float renc[4][32][65];
  __shared__ float K0s[32][129];
  __shared__ float Qi[4][128];
  __shared__ float QW[4][4][64];
  __shared__ float att[4][4][32];
  __shared__ float AR[4][4][64];
  __shared__ float posS[32][2];
  __shared__ float posI[4][2];
  int t = threadIdx.x;
  int scene = blockIdx.x >> 3, ic = blockIdx.x & 7;
  int i0 = ic * 4, sbase = scene * 32;

  for (int idx = t; idx < 4096; idx += 256) {
    int j = idx >> 7, d = idx & 127;
    K0s[j][d] = bf2f(QKV[(size_t)(sbase + j) * 384 + 128 + d]);
  }
  for (int idx = t; idx < 512; idx += 256) {
    int ii = idx >> 7, d = idx & 127;
    Qi[ii][d] = bf2f(QKV[(size_t)(sbase + i0 + ii) * 384 + d]);
  }
  if (t < 64) posS[t >> 1][t & 1] = obs[7 * (NPED * 2) + (sbase + (t >> 1)) * 2 + (t & 1)];
  if (t >= 64 && t < 72) {
    int q = t - 64;
    posI[q >> 1][q & 1] = obs[7 * (NPED * 2) + (sbase + i0 + (q >> 1)) * 2 + (q & 1)];
  }
  __syncthreads();
  for (int idx = t; idx < 1024; idx += 256) {
    int ii = idx >> 8, h = (idx >> 6) & 3, e = idx & 63;
    float s = 0.f;
    for (int d = 0; d < 32; ++d) s += Qi[ii][h * 32 + d] * wk2[(h * 32 + d) * 64 + e];
    QW[ii][h][e] = s;
  }
  for (int idx = t; idx < 8192; idx += 256) {
    int ii = idx >> 11, j = (idx >> 6) & 31, e = idx & 63;
    float rx = posS[j][0] - posI[ii][0], ry = posS[j][1] - posI[ii][1];
    renc[ii][j][e] = fmaxf(rpw1[e * 2] * rx + rpw1[e * 2 + 1] * ry + rpb1[e], 0.f);
  }
  __syncthreads();
  for (int idx = t; idx < 512; idx += 256) {
    int ii = idx >> 7, h = (idx >> 5) & 3, j = idx & 31;
    float s = 0.f;
    for (int d = 0; d < 32; ++d) s += Qi[ii][h * 32 + d] * K0s[j][h * 32 + d];
    for (int e = 0; e < 64; ++e) s += QW[ii][h][e] * renc[ii][j][e];
    att[ii][h][j] = s * 0.1767766952966369f;
  }
  __syncthreads();
  {
    int r = t >> 4, lj = t & 15;
    float v0 = att[r >> 2][r & 3][lj], v1 = att[r >> 2][r & 3][lj + 16];
    float mx = fmaxf(v0, v1);
    mx = fmaxf(mx, __shfl_xor(mx, 8, 16));
    mx = fmaxf(mx, __shfl_xor(mx, 4, 16));
    mx = fmaxf(mx, __shfl_xor(mx, 2, 16));
    mx = fmaxf(mx, __shfl_xor(mx, 1, 16));
    float e0 = expf(v0 - mx), e1 = expf(v1 - mx);
    float sm = e0 + e1;
    sm += __shfl_xor(sm, 8, 16);
    sm += __shfl_xor(sm, 4, 16);
    sm += __shfl_xor(sm, 2, 16);
    sm += __shfl_xor(sm, 1, 16);
    float inv = 1.f / sm;
    att[r >> 2][r & 3][lj] = e0 * inv;
    att[r >> 2][r & 3][lj + 16] = e1 * inv;
  }
  __syncthreads();
  for (int idx = t; idx < 1024; idx += 256) {
    int ii = idx >> 8, h = (idx >> 6) & 3, e = idx & 63;
    float s = 0.f;
    for (int j = 0; j < 32; ++j) s += att[ii][h][j] * renc[ii][j][e];
    AR[ii][h][e] = s;
  }
  __syncthreads();
  for (int idx = t; idx < 512; idx += 256) {
    int ii = idx >> 7, hd = idx & 127, h = hd >> 5;
    float s = 0.f;
    for (int j = 0; j < 32; ++j) s += att[ii][h][j] * bf2f(QKV[(size_t)(sbase + j) * 384 + 256 + hd]);
    for (int e = 0; e < 64; ++e) s += AR[ii][h][e] * wv2T[e * 128 + hd];
    QKV[(size_t)(sbase + i0 + ii) * 384 + hd] = f2bf(s);
  }
}

__global__ __launch_bounds__(256) void probs_kernel(
    const ushort* __restrict__ H1, const float* __restrict__ mpw2,
    const float* __restrict__ mpb2, float* __restrict__ out) {
  __shared__ float Hsm[64][129];
  __shared__ float lgt[64][5];
  int t = threadIdx.x, nb = blockIdx.x * 64;
  for (int idx = t; idx < 8192; idx += 256) Hsm[idx >> 7][idx & 127] = bf2f(H1[(size_t)nb * 128 + idx]);
  __syncthreads();
  for (int idx = t; idx < 320; idx += 256) {
    int p = idx / 5, m = idx % 5;
    float s = mpb2[m];
    for (int k = 0; k < 128; ++k) s += Hsm[p][k] * mpw2[m * 128 + k];
    lgt[p][m] = s;
  }
  __syncthreads();
  if (t < 64) {
    float m0 = lgt[t][0];
#pragma unroll
    for (int j = 1; j < 5; ++j) m0 = fmaxf(m0, lgt[t][j]);
    float e[5], s = 0.f;
#pragma unroll
    for (int j = 0; j < 5; ++j) { e[j] = expf(lgt[t][j] - m0); s += e[j]; }
    float inv = 1.f / s;
#pragma unroll
    for (int j = 0; j < 5; ++j) out[983040 + (size_t)(nb + t) * 5 + j] = e[j] * inv;
  }
}

__global__ __launch_bounds__(256) void traj_kernel(
    const ushort* __restrict__ TD2, const float* __restrict__ tdw3,
    const float* __restrict__ tdb3, const float* __restrict__ obs,
    float* __restrict__ out) {
  __shared__ float Hsm[64][129];
  __shared__ float tr[64][25];
  int t = threadIdx.x, nb = blockIdx.x * 64;
  int m = blockIdx.y;
  const ushort* T = TD2 + (size_t)m * 1048576;
  for (int idx = t; idx < 8192; idx += 256) Hsm[idx >> 7][idx & 127] = bf2f(T[(size_t)nb * 128 + idx]);
  __syncthreads();
  for (int idx = t; idx < 1536; idx += 256) {
    int p = idx / 24, o = idx % 24;
    float s = tdb3[m * 24 + o];
    for (int k = 0; k < 128; ++k) s += Hsm[p][k] * tdw3[(m * 24 + o) * 128 + k];
    tr[p][o] = s;
  }
  __syncthreads();
  if (t < 128) {
    int p = t >> 1, c = t & 1, n = nb + p;
    float run = obs[7 * (NPED * 2) + n * 2 + c];
#pragma unroll
    for (int j = 0; j < 12; ++j) {
      run += tr[p][j * 2 + c];
      out[(size_t)n * 120 + m * 24 + j * 2 + c] = run;
    }
  }
}

extern "C" void kernel_launch(void* const* d_in, const int* in_sizes, int n_in,
                              void* d_out, int out_size, void* d_ws, size_t ws_size,
                              hipStream_t stream) {
  (void)in_sizes; (void)n_in; (void)out_size; (void)ws_size;
  const float* obs  = (const float*)d_in[0];
  const float* pew  = (const float*)d_in[1];
  const float* peb  = (const float*)d_in[2];
  const float* wih  = (const float*)d_in[3];
  const float* bih  = (const float*)d_in[4];
  const float* whh  = (const float*)d_in[5];
  const float* bhh  = (const float*)d_in[6];
  const float* rpw1 = (const float*)d_in[7];
  const float* rpb1 = (const float*)d_in[8];
  const float* rpw2 = (const float*)d_in[9];
  const float* rpb2 = (const float*)d_in[10];
  const float* wq   = (const float*)d_in[11];
  const float* bq   = (const float*)d_in[12];
  const float* wk   = (const float*)d_in[13];
  const float* bk   = (const float*)d_in[14];
  const float* wv   = (const float*)d_in[15];
  const float* bv   = (const float*)d_in[16];
  const float* wo   = (const float*)d_in[17];
  const float* bo   = (const float*)d_in[18];
  const float* opw  = (const float*)d_in[19];
  const float* opb  = (const float*)d_in[20];
  const float* mpw1 = (const float*)d_in[21];
  const float* mpb1 = (const float*)d_in[22];
  const float* mpw2 = (const float*)d_in[23];
  const float* mpb2 = (const float*)d_in[24];
  const float* tdw1 = (const float*)d_in[25];
  const float* tdb1 = (const float*)d_in[26];
  const float* tdw2 = (const float*)d_in[27];
  const float* tdb2 = (const float*)d_in[28];
  const float* tdw3 = (const float*)d_in[29];
  const float* tdb3 = (const float*)d_in[30];
  char* wsb = (char*)d_ws;
  float* out = (float*)d_out;

  ushort* whhb  = (ushort*)(wsb + B_WHH);
  ushort* wqkvb = (ushort*)(wsb + B_WQKV);
  ushort* wob   = (ushort*)(wsb + B_WO);
  ushort* opwb  = (ushort*)(wsb + B_OPW);
  ushort* mpw1b = (ushort*)(wsb + B_MPW1);
  ushort* tdw1b = (ushort*)(wsb + B_TDW1);
  ushort* tdw2b = (ushort*)(wsb + B_TDW2);
  ushort* featb = (ushort*)(wsb + A_FEAT);
  ushort* qkvb  = (ushort*)(wsb + A_QKV);
  ushort* h1mpb = (ushort*)(wsb + A_H1MP);
  ushort* h1tdb = (ushort*)(wsb + A_H1TD);

  prep<<<1796, 256, 0, stream>>>(wih, bih, bhh, pew, peb, wk, wv, rpw2, rpb2,
                                 bq, bk, bv, whh, wq, wo, opw, mpw1, tdw1, tdw2, wsb);
  lstm_mfma<<<256, 512, 0, stream>>>(obs, whhb, (float*)(wsb + F_WIHE),
                                     (float*)(wsb + F_BEFF), featb);
  // QKV = feat @ [wq|wk|wv]^T + [bq|bk_eff|bv_eff]
  mfma_gemm<4><<<dim3(128, 6, 1), 256, 0, stream>>>(
      featb, 128, 128, featb, 128, wqkvb, 128, (float*)(wsb + F_BQKV),
      qkvb, 384, 0, 0, 0, 0, 0, 0);
  attn_kernel<<<2048, 256, 0, stream>>>(obs, qkvb, (float*)(wsb + F_WK2),
                                        (float*)(wsb + F_WV2T), rpw1, rpb1);
  // AO = ctx @ wo^T + bo  (slot1)
  mfma_gemm<4><<<dim3(128, 2, 1), 256, 0, stream>>>(
      qkvb, 384, 128, qkvb, 384, wob, 128, bo, qkvb, 384, 128, 0, 0, 0, 0, 0);
  // EDGE = [feat|AO] @ op_w^T + op_b  (slot2)
  mfma_gemm<4><<<dim3(128, 2, 1), 256, 0, stream>>>(
      featb, 128, 128, qkvb + 128, 384, opwb, 256, opb, qkvb, 384, 256, 0, 0, 0, 0, 0);
  // H1MP = relu([feat|EDGE] @ mp_w1^T + mp_b1)
  mfma_gemm<4><<<dim3(128, 2, 1), 256, 0, stream>>>(
      featb, 128, 128, qkvb + 256, 384, mpw1b, 256, mpb1, h1mpb, 128, 0, 1, 0, 0, 0, 0);
  probs_kernel<<<128, 256, 0, stream>>>(h1mpb, mpw2, mpb2, out);
  // TD1 (batched over 5 modes)
  mfma_gemm<4><<<dim3(128, 2, 5), 256, 0, stream>>>(
      featb, 128, 128, qkvb + 256, 384, tdw1b, 256, tdb1, h1tdb, 128, 0, 1,
      32768, 128, 0, 1048576);
  // TD2 in-place over H1TD (full-N blocks, per-wave rows: safe)
  mfma_gemm<8><<<dim3(128, 1, 5), 256, 0, stream>>>(
      h1tdb, 128, 128, h1tdb, 128, tdw2b, 128, tdb2, h1tdb, 128, 0, 1,
      16384, 128, 1048576, 1048576);
  traj_kernel<<<dim3(128, 5), 256, 0, stream>>>(h1tdb, tdw3, tdb3, obs, out);
}

// Round 3
// 315.689 us; speedup vs baseline: 2.7834x; 1.1740x over previous
//
#include <hip/hip_runtime.h>
#include <math.h>

typedef __attribute__((ext_vector_type(8))) short short8;
typedef __attribute__((ext_vector_type(4))) float f32x4;

#define NPED 8192

// ---- workspace layout (BYTE offsets) ----
#define B_WHH    0          // [512][128] bf16
#define B_WQKV   131072     // [384][128] bf16  (wq|wk|wv)
#define B_WO     229376     // [128][128] bf16
#define B_OPW    262144     // [128][256] bf16
#define B_MPW1   327680     // [128][256] bf16
#define B_TDW1   393216     // [5][128][256] bf16
#define B_TDW2   720896     // [5][128][128] bf16
#define F_WIHE   884736     // [512][2] f32  Wih@pe_w
#define F_BEFF   888832     // [512]   f32  bih+bhh+Wih@pe_b
#define F_WK2    890880     // [128][64] f32 wk@rp_w2
#define F_WV2T   923648     // [64][128] f32 (wv@rp_w2)^T
#define F_BQKV   956416     // [384] f32  bq | bk_eff | bv_eff
#define A_FEAT   957952     // [8192][128] bf16
#define A_QKV    3055104    // [8192][384] bf16: ctx<-Q | AO<-K0 | EDGE<-V0
#define A_H1MP   9346560    // [8192][128] bf16
#define A_H1TD   11443712   // [5][8192][128] bf16 (TD2 in-place)
#define B_TDW3C  21929472   // [5][32][128] bf16  prefix-summed tdw3 (cols 24..31 zero)
#define F_TDB3C  21970432   // [5][24] f32 prefix-summed tdb3
// end ~22.0 MB

__device__ __forceinline__ float bf2f(ushort u) {
  union { unsigned i; float f; } v; v.i = ((unsigned)u) << 16; return v.f;
}
__device__ __forceinline__ ushort f2bf(float f) {
  union { float f; unsigned i; } v; v.f = f;
  unsigned r = v.i + 0x7fffu + ((v.i >> 16) & 1u);
  return (ushort)(r >> 16);
}

__global__ __launch_bounds__(256) void prep(
    const float* __restrict__ wih, const float* __restrict__ bih, const float* __restrict__ bhh,
    const float* __restrict__ pew, const float* __restrict__ peb,
    const float* __restrict__ wk, const float* __restrict__ wv,
    const float* __restrict__ rpw2, const float* __restrict__ rpb2,
    const float* __restrict__ bq, const float* __restrict__ bk, const float* __restrict__ bv,
    const float* __restrict__ whh, const float* __restrict__ wq, const float* __restrict__ wo,
    const float* __restrict__ opw, const float* __restrict__ mpw1,
    const float* __restrict__ tdw1, const float* __restrict__ tdw2,
    const float* __restrict__ tdw3, const float* __restrict__ tdb3,
    char* __restrict__ wsb) {
  int tid = blockIdx.x * 256 + threadIdx.x;
  float* wihe = (float*)(wsb + F_WIHE);
  float* beff = (float*)(wsb + F_BEFF);
  float* wk2  = (float*)(wsb + F_WK2);
  float* wv2T = (float*)(wsb + F_WV2T);
  float* bqkv = (float*)(wsb + F_BQKV);
  if (tid < 512) {
    int d = tid;
    float s0 = 0.f, s1 = 0.f, sb = 0.f;
    for (int e = 0; e < 64; ++e) {
      float w = wih[d * 64 + e];
      s0 += w * pew[e * 2]; s1 += w * pew[e * 2 + 1]; sb += w * peb[e];
    }
    wihe[d * 2] = s0; wihe[d * 2 + 1] = s1;
    beff[d] = bih[d] + bhh[d] + sb;
  } else if (tid < 8704) {            // wk2 [128][64]
    int idx = tid - 512; int d = idx >> 6, e = idx & 63;
    float s = 0.f;
    for (int c = 0; c < 128; ++c) s += wk[d * 128 + c] * rpw2[c * 64 + e];
    wk2[idx] = s;
  } else if (tid < 16896) {           // wv2T [64][128]
    int idx = tid - 8704; int e = idx >> 7, hd = idx & 127;
    float s = 0.f;
    for (int c = 0; c < 128; ++c) s += wv[hd * 128 + c] * rpw2[c * 64 + e];
    wv2T[idx] = s;
  } else if (tid < 17024) {
    int d = tid - 16896;
    float s = bk[d];
    for (int c = 0; c < 128; ++c) s += wk[d * 128 + c] * rpb2[c];
    bqkv[128 + d] = s;
  } else if (tid < 17152) {
    int d = tid - 17024;
    float s = bv[d];
    for (int c = 0; c < 128; ++c) s += wv[d * 128 + c] * rpb2[c];
    bqkv[256 + d] = s;
  } else if (tid < 17280) {
    int d = tid - 17152;
    bqkv[d] = bq[d];
  } else if (tid >= 17408) {
    int i = tid - 17408;
    if (i < 65536) {
      ((ushort*)(wsb + B_WHH))[i] = f2bf(whh[i]);
    } else if (i < 114688) {          // wqkv [384][128]
      int j = i - 65536; int n = j >> 7, k = j & 127;
      float v = (n < 128) ? wq[n * 128 + k] : (n < 256) ? wk[(n - 128) * 128 + k] : wv[(n - 256) * 128 + k];
      ((ushort*)(wsb + B_WQKV))[j] = f2bf(v);
    } else if (i < 131072) {
      int j = i - 114688; ((ushort*)(wsb + B_WO))[j] = f2bf(wo[j]);
    } else if (i < 163840) {
      int j = i - 131072; ((ushort*)(wsb + B_OPW))[j] = f2bf(opw[j]);
    } else if (i < 196608) {
      int j = i - 163840; ((ushort*)(wsb + B_MPW1))[j] = f2bf(mpw1[j]);
    } else if (i < 360448) {
      int j = i - 196608; ((ushort*)(wsb + B_TDW1))[j] = f2bf(tdw1[j]);
    } else if (i < 442368) {
      int j = i - 360448; ((ushort*)(wsb + B_TDW2))[j] = f2bf(tdw2[j]);
    } else if (i < 462848) {          // tdw3c [5][32][128] prefix-summed
      int j = i - 442368; int m = j >> 12, r = j & 4095, o = r >> 7, k = r & 127;
      float s = 0.f;
      if (o < 24) {
        int c = o & 1, jj = o >> 1;
        for (int jp = 0; jp <= jj; ++jp) s += tdw3[(m * 24 + jp * 2 + c) * 128 + k];
      }
      ((ushort*)(wsb + B_TDW3C))[j] = f2bf(s);
    } else if (i < 462968) {          // tdb3c [5][24]
      int j = i - 462848; int m = j / 24, o = j % 24;
      int c = o & 1, jj = o >> 1;
      float s = 0.f;
      for (int jp = 0; jp <= jj; ++jp) s += tdb3[m * 24 + jp * 2 + c];
      ((float*)(wsb + F_TDB3C))[j] = s;
    }
  }
}

// LSTM: 32 peds/block, 512 thr = 8 waves. Wave w owns gates {q*128 + w*16 + (lane&15)}.
// Whh fragments live in registers for all 8 timesteps. h tile in XOR-swizzled bf16 LDS.
__global__ __launch_bounds__(512) void lstm_mfma(
    const float* __restrict__ obs, const ushort* __restrict__ whhb,
    const float* __restrict__ wihe, const float* __restrict__ beff,
    ushort* __restrict__ feat) {
  __shared__ ushort Hs[32 * 128];
  __shared__ float obs_s[8][32][2];
  int tid = threadIdx.x;
  int w = tid >> 6, l = tid & 63;
  int lm = l & 15, lg = l >> 4;
  int nb = blockIdx.x * 32;
  {
    int ts = tid >> 6, p = (tid >> 1) & 31, c = tid & 1;
    obs_s[ts][p][c] = obs[ts * (NPED * 2) + (nb + p) * 2 + c];
  }
  for (int i = tid; i < 4096; i += 512) Hs[i] = 0;
  short8 bfr[4][4];
  float wx0[4], wx1[4], be[4];
#pragma unroll
  for (int q = 0; q < 4; ++q) {
    int g = q * 128 + w * 16 + lm;
    wx0[q] = wihe[g * 2]; wx1[q] = wihe[g * 2 + 1]; be[q] = beff[g];
#pragma unroll
    for (int ks = 0; ks < 4; ++ks)
      bfr[q][ks] = *(const short8*)(const void*)&whhb[g * 128 + ks * 32 + lg * 8];
  }
  float cst[2][4] = {};
  __syncthreads();
  for (int ts = 0; ts < 8; ++ts) {
    f32x4 acc[2][4];
#pragma unroll
    for (int mi = 0; mi < 2; ++mi)
#pragma unroll
      for (int r = 0; r < 4; ++r) {
        int p = mi * 16 + lg * 4 + r;
        float ox = obs_s[ts][p][0], oy = obs_s[ts][p][1];
#pragma unroll
        for (int q = 0; q < 4; ++q)
          acc[mi][q][r] = be[q] + wx0[q] * ox + wx1[q] * oy;
      }
#pragma unroll
    for (int ks = 0; ks < 4; ++ks) {
      int p0 = lm, p1 = 16 + lm;
      short8 a0 = *(const short8*)(const void*)&Hs[p0 * 128 + ((ks * 32 + lg * 8) ^ ((p0 & 7) << 3))];
      short8 a1 = *(const short8*)(const void*)&Hs[p1 * 128 + ((ks * 32 + lg * 8) ^ ((p1 & 7) << 3))];
#pragma unroll
      for (int q = 0; q < 4; ++q) {
        acc[0][q] = __builtin_amdgcn_mfma_f32_16x16x32_bf16(a0, bfr[q][ks], acc[0][q], 0, 0, 0);
        acc[1][q] = __builtin_amdgcn_mfma_f32_16x16x32_bf16(a1, bfr[q][ks], acc[1][q], 0, 0, 0);
      }
    }
    __syncthreads();
    int d = w * 16 + lm;
#pragma unroll
    for (int mi = 0; mi < 2; ++mi)
#pragma unroll
      for (int r = 0; r < 4; ++r) {
        int p = mi * 16 + lg * 4 + r;
        float xi = acc[mi][0][r], xf = acc[mi][1][r], xg = acc[mi][2][r], xo = acc[mi][3][r];
        float ig = 1.f / (1.f + __expf(-xi));
        float fg = 1.f / (1.f + __expf(-xf));
        xg = fminf(fmaxf(xg, -30.f), 30.f);
        float eg = __expf(-2.f * xg);
        float gg = (1.f - eg) / (1.f + eg);
        float og = 1.f / (1.f + __expf(-xo));
        float cv = fg * cst[mi][r] + ig * gg;
        cst[mi][r] = cv;
        float cvc = fminf(fmaxf(cv, -30.f), 30.f);
        float ec = __expf(-2.f * cvc);
        float th = (1.f - ec) / (1.f + ec);
        ushort hb = f2bf(og * th);
        Hs[p * 128 + (d ^ ((p & 7) << 3))] = hb;
        if (ts == 7) feat[(size_t)(nb + p) * 128 + d] = hb;
      }
    __syncthreads();
  }
}

// MFMA GEMM, direct-from-global. Block = 64 rows x (NF*16) cols, 4 waves stacked in M.
// A = [A1 | A2] concat along K (K1 boundary, 32-aligned). B is [N][K] bf16 (native w layout).
template<int NF>
__global__ __launch_bounds__(256) void mfma_gemm(
    const ushort* __restrict__ A1, int lda1, int K1,
    const ushort* __restrict__ A2, int lda2,
    const ushort* __restrict__ Bw, int K,
    const float* __restrict__ bias,
    ushort* __restrict__ out, int ldo, int ooff, int relu,
    int sB, int sBias, int sA1, int sOut) {
  int w = threadIdx.x >> 6, l = threadIdx.x & 63;
  int lm = l & 15, lg = l >> 4;
  int z = blockIdx.z;
  A1 += (size_t)z * sA1;
  Bw += (size_t)z * sB;
  bias += (size_t)z * sBias;
  out += (size_t)z * sOut;
  int row = blockIdx.x * 64 + w * 16 + lm;
  int col0 = blockIdx.y * (NF * 16);
  f32x4 acc[NF];
#pragma unroll
  for (int i = 0; i < NF; ++i) acc[i] = (f32x4){0.f, 0.f, 0.f, 0.f};
  const int nks = K >> 5;
  for (int ks = 0; ks < nks; ++ks) {
    int kb = ks * 32 + lg * 8;
    const ushort* ap = (ks * 32 < K1) ? (A1 + (size_t)row * lda1 + kb)
                                      : (A2 + (size_t)row * lda2 + (kb - K1));
    short8 af = *(const short8*)(const void*)ap;
#pragma unroll
    for (int ni = 0; ni < NF; ++ni) {
      short8 bf = *(const short8*)(const void*)(Bw + (size_t)(col0 + ni * 16 + lm) * K + kb);
      acc[ni] = __builtin_amdgcn_mfma_f32_16x16x32_bf16(af, bf, acc[ni], 0, 0, 0);
    }
  }
  int orow0 = blockIdx.x * 64 + w * 16 + lg * 4;
#pragma unroll
  for (int ni = 0; ni < NF; ++ni) {
    int c = col0 + ni * 16 + lm;
    float bv = bias[c];
#pragma unroll
    for (int r = 0; r < 4; ++r) {
      float v = acc[ni][r] + bv;
      if (relu) v = fmaxf(v, 0.f);
      out[(size_t)(orow0 + r) * ldo + ooff + c] = f2bf(v);
    }
  }
}

// traj: predictions = TD2 @ tdw3c^T + tdb3c + last_pos   (cumsum folded into weights)
// one dispatch, grid (128, 5). 64 rows/block, N=24 (padded 32), K=128. fp32 out.
__global__ __launch_bounds__(256) void traj_mfma(
    const ushort* __restrict__ TD2, const ushort* __restrict__ w3c,
    const float* __restrict__ b3c, const float* __restrict__ obs,
    float* __restrict__ out) {
  int w = threadIdx.x >> 6, l = threadIdx.x & 63;
  int lm = l & 15, lg = l >> 4;
  int m = blockIdx.y;
  const ushort* A = TD2 + (size_t)m * (NPED * 128);
  const ushort* B = w3c + (size_t)m * 4096;
  int row = blockIdx.x * 64 + w * 16 + lm;
  f32x4 acc[2];
  acc[0] = (f32x4){0.f,0.f,0.f,0.f}; acc[1] = (f32x4){0.f,0.f,0.f,0.f};
#pragma unroll
  for (int ks = 0; ks < 4; ++ks) {
    int kb = ks * 32 + lg * 8;
    short8 af = *(const short8*)(const void*)(A + (size_t)row * 128 + kb);
#pragma unroll
    for (int ni = 0; ni < 2; ++ni) {
      short8 bf = *(const short8*)(const void*)(B + (ni * 16 + lm) * 128 + kb);
      acc[ni] = __builtin_amdgcn_mfma_f32_16x16x32_bf16(af, bf, acc[ni], 0, 0, 0);
    }
  }
  int orow0 = blockIdx.x * 64 + w * 16 + lg * 4;
#pragma unroll
  for (int ni = 0; ni < 2; ++ni) {
    int o = ni * 16 + lm;
    if (o < 24) {
      float bb = b3c[m * 24 + o];
      int c = o & 1;
#pragma unroll
      for (int r = 0; r < 4; ++r) {
        int n = orow0 + r;
        out[(size_t)n * 120 + m * 24 + o] = acc[ni][r] + bb + obs[7 * (NPED * 2) + n * 2 + c];
      }
    }
  }
}

// attention over bf16 QKV; ctx overwrites Q slot.
__global__ __launch_bounds__(256) void attn_kernel(
    const float* __restrict__ obs, ushort* QKV,
    const float* __restrict__ wk2, const float* __restrict__ wv2T,
    const float* __restrict__ rpw1, const float* __restrict__ rpb1) {
  __shared__ float renc[4][32][65];
  __shared__ float K0s[32][129];
  __shared__ float Qi[4][128];
  __shared__ float QW[4][4][64];
  __shared__ float att[4][4][32];
  __shared__ float AR[4][4][64];
  __shared__ float posS[32][2];
  __shared__ float posI[4][2];
  int t = threadIdx.x;
  int scene = blockIdx.x >> 3, ic = blockIdx.x & 7;
  int i0 = ic * 4, sbase = scene * 32;

  for (int idx = t; idx < 4096; idx += 256) {
    int j = idx >> 7, d = idx & 127;
    K0s[j][d] = bf2f(QKV[(size_t)(sbase + j) * 384 + 128 + d]);
  }
  for (int idx = t; idx < 512; idx += 256) {
    int ii = idx >> 7, d = idx & 127;
    Qi[ii][d] = bf2f(QKV[(size_t)(sbase + i0 + ii) * 384 + d]);
  }
  if (t < 64) posS[t >> 1][t & 1] = obs[7 * (NPED * 2) + (sbase + (t >> 1)) * 2 + (t & 1)];
  if (t >= 64 && t < 72) {
    int q = t - 64;
    posI[q >> 1][q & 1] = obs[7 * (NPED * 2) + (sbase + i0 + (q >> 1)) * 2 + (q & 1)];
  }
  __syncthreads();
  for (int idx = t; idx < 1024; idx += 256) {
    int ii = idx >> 8, h = (idx >> 6) & 3, e = idx & 63;
    float s = 0.f;
    for (int d = 0; d < 32; ++d) s += Qi[ii][h * 32 + d] * wk2[(h * 32 + d) * 64 + e];
    QW[ii][h][e] = s;
  }
  for (int idx = t; idx < 8192; idx += 256) {
    int ii = idx >> 11, j = (idx >> 6) & 31, e = idx & 63;
    float rx = posS[j][0] - posI[ii][0], ry = posS[j][1] - posI[ii][1];
    renc[ii][j][e] = fmaxf(rpw1[e * 2] * rx + rpw1[e * 2 + 1] * ry + rpb1[e], 0.f);
  }
  __syncthreads();
  for (int idx = t; idx < 512; idx += 256) {
    int ii = idx >> 7, h = (idx >> 5) & 3, j = idx & 31;
    float s = 0.f;
    for (int d = 0; d < 32; ++d) s += Qi[ii][h * 32 + d] * K0s[j][h * 32 + d];
    for (int e = 0; e < 64; ++e) s += QW[ii][h][e] * renc[ii][j][e];
    att[ii][h][j] = s * 0.1767766952966369f;
  }
  __syncthreads();
  {
    int r = t >> 4, lj = t & 15;
    float v0 = att[r >> 2][r & 3][lj], v1 = att[r >> 2][r & 3][lj + 16];
    float mx = fmaxf(v0, v1);
    mx = fmaxf(mx, __shfl_xor(mx, 8, 16));
    mx = fmaxf(mx, __shfl_xor(mx, 4, 16));
    mx = fmaxf(mx, __shfl_xor(mx, 2, 16));
    mx = fmaxf(mx, __shfl_xor(mx, 1, 16));
    float e0 = expf(v0 - mx), e1 = expf(v1 - mx);
    float sm = e0 + e1;
    sm += __shfl_xor(sm, 8, 16);
    sm += __shfl_xor(sm, 4, 16);
    sm += __shfl_xor(sm, 2, 16);
    sm += __shfl_xor(sm, 1, 16);
    float inv = 1.f / sm;
    att[r >> 2][r & 3][lj] = e0 * inv;
    att[r >> 2][r & 3][lj + 16] = e1 * inv;
  }
  __syncthreads();
  for (int idx = t; idx < 1024; idx += 256) {
    int ii = idx >> 8, h = (idx >> 6) & 3, e = idx & 63;
    float s = 0.f;
    for (int j = 0; j < 32; ++j) s += att[ii][h][j] * renc[ii][j][e];
    AR[ii][h][e] = s;
  }
  __syncthreads();
  for (int idx = t; idx < 512; idx += 256) {
    int ii = idx >> 7, hd = idx & 127, h = hd >> 5;
    float s = 0.f;
    for (int j = 0; j < 32; ++j) s += att[ii][h][j] * bf2f(QKV[(size_t)(sbase + j) * 384 + 256 + hd]);
    for (int e = 0; e < 64; ++e) s += AR[ii][h][e] * wv2T[e * 128 + hd];
    QKV[(size_t)(sbase + i0 + ii) * 384 + hd] = f2bf(s);
  }
}

__global__ __launch_bounds__(256) void probs_kernel(
    const ushort* __restrict__ H1, const float* __restrict__ mpw2,
    const float* __restrict__ mpb2, float* __restrict__ out) {
  __shared__ float Hsm[64][129];
  __shared__ float lgt[64][5];
  int t = threadIdx.x, nb = blockIdx.x * 64;
  for (int idx = t; idx < 8192; idx += 256) Hsm[idx >> 7][idx & 127] = bf2f(H1[(size_t)nb * 128 + idx]);
  __syncthreads();
  for (int idx = t; idx < 320; idx += 256) {
    int p = idx / 5, m = idx % 5;
    float s = mpb2[m];
    for (int k = 0; k < 128; ++k) s += Hsm[p][k] * mpw2[m * 128 + k];
    lgt[p][m] = s;
  }
  __syncthreads();
  if (t < 64) {
    float m0 = lgt[t][0];
#pragma unroll
    for (int j = 1; j < 5; ++j) m0 = fmaxf(m0, lgt[t][j]);
    float e[5], s = 0.f;
#pragma unroll
    for (int j = 0; j < 5; ++j) { e[j] = expf(lgt[t][j] - m0); s += e[j]; }
    float inv = 1.f / s;
#pragma unroll
    for (int j = 0; j < 5; ++j) out[983040 + (size_t)(nb + t) * 5 + j] = e[j] * inv;
  }
}

extern "C" void kernel_launch(void* const* d_in, const int* in_sizes, int n_in,
                              void* d_out, int out_size, void* d_ws, size_t ws_size,
                              hipStream_t stream) {
  (void)in_sizes; (void)n_in; (void)out_size; (void)ws_size;
  const float* obs  = (const float*)d_in[0];
  const float* pew  = (const float*)d_in[1];
  const float* peb  = (const float*)d_in[2];
  const float* wih  = (const float*)d_in[3];
  const float* bih  = (const float*)d_in[4];
  const float* whh  = (const float*)d_in[5];
  const float* bhh  = (const float*)d_in[6];
  const float* rpw1 = (const float*)d_in[7];
  const float* rpb1 = (const float*)d_in[8];
  const float* rpw2 = (const float*)d_in[9];
  const float* rpb2 = (const float*)d_in[10];
  const float* wq   = (const float*)d_in[11];
  const float* bq   = (const float*)d_in[12];
  const float* wk   = (const float*)d_in[13];
  const float* bk   = (const float*)d_in[14];
  const float* wv   = (const float*)d_in[15];
  const float* bv   = (const float*)d_in[16];
  const float* wo   = (const float*)d_in[17];
  const float* bo   = (const float*)d_in[18];
  const float* opw  = (const float*)d_in[19];
  const float* opb  = (const float*)d_in[20];
  const float* mpw1 = (const float*)d_in[21];
  const float* mpb1 = (const float*)d_in[22];
  const float* mpw2 = (const float*)d_in[23];
  const float* mpb2 = (const float*)d_in[24];
  const float* tdw1 = (const float*)d_in[25];
  const float* tdb1 = (const float*)d_in[26];
  const float* tdw2 = (const float*)d_in[27];
  const float* tdb2 = (const float*)d_in[28];
  const float* tdw3 = (const float*)d_in[29];
  const float* tdb3 = (const float*)d_in[30];
  char* wsb = (char*)d_ws;
  float* out = (float*)d_out;

  ushort* whhb  = (ushort*)(wsb + B_WHH);
  ushort* wqkvb = (ushort*)(wsb + B_WQKV);
  ushort* wob   = (ushort*)(wsb + B_WO);
  ushort* opwb  = (ushort*)(wsb + B_OPW);
  ushort* mpw1b = (ushort*)(wsb + B_MPW1);
  ushort* tdw1b = (ushort*)(wsb + B_TDW1);
  ushort* tdw2b = (ushort*)(wsb + B_TDW2);
  ushort* tdw3cb= (ushort*)(wsb + B_TDW3C);
  ushort* featb = (ushort*)(wsb + A_FEAT);
  ushort* qkvb  = (ushort*)(wsb + A_QKV);
  ushort* h1mpb = (ushort*)(wsb + A_H1MP);
  ushort* h1tdb = (ushort*)(wsb + A_H1TD);

  prep<<<1877, 256, 0, stream>>>(wih, bih, bhh, pew, peb, wk, wv, rpw2, rpb2,
                                 bq, bk, bv, whh, wq, wo, opw, mpw1, tdw1, tdw2,
                                 tdw3, tdb3, wsb);
  lstm_mfma<<<256, 512, 0, stream>>>(obs, whhb, (float*)(wsb + F_WIHE),
                                     (float*)(wsb + F_BEFF), featb);
  // QKV = feat @ [wq|wk|wv]^T + [bq|bk_eff|bv_eff]
  mfma_gemm<4><<<dim3(128, 6, 1), 256, 0, stream>>>(
      featb, 128, 128, featb, 128, wqkvb, 128, (float*)(wsb + F_BQKV),
      qkvb, 384, 0, 0, 0, 0, 0, 0);
  attn_kernel<<<2048, 256, 0, stream>>>(obs, qkvb, (float*)(wsb + F_WK2),
                                        (float*)(wsb + F_WV2T), rpw1, rpb1);
  // AO = ctx @ wo^T + bo  (slot1)
  mfma_gemm<4><<<dim3(128, 2, 1), 256, 0, stream>>>(
      qkvb, 384, 128, qkvb, 384, wob, 128, bo, qkvb, 384, 128, 0, 0, 0, 0, 0);
  // EDGE = [feat|AO] @ op_w^T + op_b  (slot2)
  mfma_gemm<4><<<dim3(128, 2, 1), 256, 0, stream>>>(
      featb, 128, 128, qkvb + 128, 384, opwb, 256, opb, qkvb, 384, 256, 0, 0, 0, 0, 0);
  // H1MP = relu([feat|EDGE] @ mp_w1^T + mp_b1)
  mfma_gemm<4><<<dim3(128, 2, 1), 256, 0, stream>>>(
      featb, 128, 128, qkvb + 256, 384, mpw1b, 256, mpb1, h1mpb, 128, 0, 1, 0, 0, 0, 0);
  probs_kernel<<<128, 256, 0, stream>>>(h1mpb, mpw2, mpb2, out);
  // TD1 (batched over 5 modes)
  mfma_gemm<4><<<dim3(128, 2, 5), 256, 0, stream>>>(
      featb, 128, 128, qkvb + 256, 384, tdw1b, 256, tdb1, h1tdb, 128, 0, 1,
      32768, 128, 0, 1048576);
  // TD2 in-place over H1TD (full-N blocks, per-wave rows: safe)
  mfma_gemm<8><<<dim3(128, 1, 5), 256, 0, stream>>>(
      h1tdb, 128, 128, h1tdb, 128, tdw2b, 128, tdb2, h1tdb, 128, 0, 1,
      16384, 128, 1048576, 1048576);
  // predictions = TD2 @ tdw3c^T + tdb3c + last_pos   (cumsum pre-folded)
  traj_mfma<<<dim3(128, 5), 256, 0, stream>>>(h1tdb, tdw3cb, (float*)(wsb + F_TDB3C), obs, out);
}

// Round 4
// 297.314 us; speedup vs baseline: 2.9554x; 1.0618x over previous
//
#include <hip/hip_runtime.h>
#include <math.h>

typedef __attribute__((ext_vector_type(8))) short short8;
typedef __attribute__((ext_vector_type(4))) float f32x4;

#define NPED 8192
#define INVS 0.1767766952966369f   // 1/sqrt(32)

// ---- workspace layout (BYTE offsets) ----
#define B_WHH    0          // [512][128] bf16
#define B_WQKV   131072     // [384][128] bf16  (wq_s|wk|wv), wq rows scaled by INVS
#define B_WO     229376     // [128][128] bf16
#define B_OPW    262144     // [128][256] bf16
#define B_MPW1   327680     // [128][256] bf16
#define B_TDW1   393216     // [5][128][256] bf16
#define B_TDW2   720896     // [5][128][128] bf16
#define B_WK2PAD 884736     // [256][128] bf16  wk2pad[(h*64+e)][d] = (d>>5==h)?wk2[d][e]:0
#define F_WIHE   950272     // [512][2] f32
#define F_BEFF   954368     // [512] f32
#define F_WV2T   956416     // [64][128] f32 (wv@rp_w2)^T
#define F_BQKV   989184     // [384] f32: bq*INVS | bk_eff | bv_eff
#define F_ZERO   990720     // [256] f32 zeros
#define A_FEAT   991744     // [8192][128] bf16
#define A_QKV    3088896    // [8192][384] bf16: ctx<-Q | AO<-K0 | EDGE<-V0
#define A_H1MP   9380352    // [8192][128] bf16
#define A_H1TD   11477504   // [5][8192][128] bf16 (TD2 in-place)
#define A_QW     11477504   // [8192][256] bf16 (aliases H1TD head; dead before TD1 writes)
#define B_TDW3C  21963264   // [5][32][128] bf16 prefix-summed tdw3
#define F_TDB3C  22004224   // [5][24] f32
// end ~22.0 MB

__device__ __forceinline__ float bf2f(ushort u) {
  union { unsigned i; float f; } v; v.i = ((unsigned)u) << 16; return v.f;
}
__device__ __forceinline__ float blo(unsigned u) {
  union { unsigned i; float f; } v; v.i = u << 16; return v.f;
}
__device__ __forceinline__ float bhi(unsigned u) {
  union { unsigned i; float f; } v; v.i = u & 0xffff0000u; return v.f;
}
__device__ __forceinline__ ushort f2bf(float f) {
  union { float f; unsigned i; } v; v.f = f;
  unsigned r = v.i + 0x7fffu + ((v.i >> 16) & 1u);
  return (ushort)(r >> 16);
}

__global__ __launch_bounds__(256) void prep(
    const float* __restrict__ wih, const float* __restrict__ bih, const float* __restrict__ bhh,
    const float* __restrict__ pew, const float* __restrict__ peb,
    const float* __restrict__ wk, const float* __restrict__ wv,
    const float* __restrict__ rpw2, const float* __restrict__ rpb2,
    const float* __restrict__ bq, const float* __restrict__ bk, const float* __restrict__ bv,
    const float* __restrict__ whh, const float* __restrict__ wq, const float* __restrict__ wo,
    const float* __restrict__ opw, const float* __restrict__ mpw1,
    const float* __restrict__ tdw1, const float* __restrict__ tdw2,
    const float* __restrict__ tdw3, const float* __restrict__ tdb3,
    char* __restrict__ wsb) {
  int tid = blockIdx.x * 256 + threadIdx.x;
  float* wihe = (float*)(wsb + F_WIHE);
  float* beff = (float*)(wsb + F_BEFF);
  float* wv2T = (float*)(wsb + F_WV2T);
  float* bqkv = (float*)(wsb + F_BQKV);
  if (tid < 512) {
    int d = tid;
    float s0 = 0.f, s1 = 0.f, sb = 0.f;
    for (int e = 0; e < 64; ++e) {
      float w = wih[d * 64 + e];
      s0 += w * pew[e * 2]; s1 += w * pew[e * 2 + 1]; sb += w * peb[e];
    }
    wihe[d * 2] = s0; wihe[d * 2 + 1] = s1;
    beff[d] = bih[d] + bhh[d] + sb;
  } else if (tid < 33280) {           // wk2pad [256][128] bf16
    int idx = tid - 512; int r = idx >> 7, d = idx & 127;
    int h = r >> 6, e = r & 63;
    float s = 0.f;
    if ((d >> 5) == h)
      for (int c = 0; c < 128; ++c) s += wk[d * 128 + c] * rpw2[c * 64 + e];
    ((ushort*)(wsb + B_WK2PAD))[idx] = f2bf(s);
  } else if (tid < 41472) {           // wv2T [64][128] f32
    int idx = tid - 33280; int e = idx >> 7, hd = idx & 127;
    float s = 0.f;
    for (int c = 0; c < 128; ++c) s += wv[hd * 128 + c] * rpw2[c * 64 + e];
    wv2T[idx] = s;
  } else if (tid < 41600) {
    int d = tid - 41472;
    float s = bk[d];
    for (int c = 0; c < 128; ++c) s += wk[d * 128 + c] * rpb2[c];
    bqkv[128 + d] = s;
  } else if (tid < 41728) {
    int d = tid - 41600;
    float s = bv[d];
    for (int c = 0; c < 128; ++c) s += wv[d * 128 + c] * rpb2[c];
    bqkv[256 + d] = s;
  } else if (tid < 41856) {
    int d = tid - 41728;
    bqkv[d] = bq[d] * INVS;
  } else if (tid < 42112) {
    ((float*)(wsb + F_ZERO))[tid - 41856] = 0.f;
  } else {
    int i = tid - 42112;
    if (i < 65536) {
      ((ushort*)(wsb + B_WHH))[i] = f2bf(whh[i]);
    } else if (i < 114688) {          // wqkv [384][128]; wq rows scaled
      int j = i - 65536; int n = j >> 7, k = j & 127;
      float v = (n < 128) ? wq[n * 128 + k] * INVS
                          : (n < 256) ? wk[(n - 128) * 128 + k] : wv[(n - 256) * 128 + k];
      ((ushort*)(wsb + B_WQKV))[j] = f2bf(v);
    } else if (i < 131072) {
      int j = i - 114688; ((ushort*)(wsb + B_WO))[j] = f2bf(wo[j]);
    } else if (i < 163840) {
      int j = i - 131072; ((ushort*)(wsb + B_OPW))[j] = f2bf(opw[j]);
    } else if (i < 196608) {
      int j = i - 163840; ((ushort*)(wsb + B_MPW1))[j] = f2bf(mpw1[j]);
    } else if (i < 360448) {
      int j = i - 196608; ((ushort*)(wsb + B_TDW1))[j] = f2bf(tdw1[j]);
    } else if (i < 442368) {
      int j = i - 360448; ((ushort*)(wsb + B_TDW2))[j] = f2bf(tdw2[j]);
    } else if (i < 462848) {          // tdw3c prefix-summed
      int j = i - 442368; int m = j >> 12, r = j & 4095, o = r >> 7, k = r & 127;
      float s = 0.f;
      if (o < 24) {
        int c = o & 1, jj = o >> 1;
        for (int jp = 0; jp <= jj; ++jp) s += tdw3[(m * 24 + jp * 2 + c) * 128 + k];
      }
      ((ushort*)(wsb + B_TDW3C))[j] = f2bf(s);
    } else if (i < 462968) {
      int j = i - 462848; int m = j / 24, o = j % 24;
      int c = o & 1, jj = o >> 1;
      float s = 0.f;
      for (int jp = 0; jp <= jj; ++jp) s += tdb3[m * 24 + jp * 2 + c];
      ((float*)(wsb + F_TDB3C))[j] = s;
    }
  }
}

// LSTM (unchanged from round 2/3)
__global__ __launch_bounds__(512) void lstm_mfma(
    const float* __restrict__ obs, const ushort* __restrict__ whhb,
    const float* __restrict__ wihe, const float* __restrict__ beff,
    ushort* __restrict__ feat) {
  __shared__ ushort Hs[32 * 128];
  __shared__ float obs_s[8][32][2];
  int tid = threadIdx.x;
  int w = tid >> 6, l = tid & 63;
  int lm = l & 15, lg = l >> 4;
  int nb = blockIdx.x * 32;
  {
    int ts = tid >> 6, p = (tid >> 1) & 31, c = tid & 1;
    obs_s[ts][p][c] = obs[ts * (NPED * 2) + (nb + p) * 2 + c];
  }
  for (int i = tid; i < 4096; i += 512) Hs[i] = 0;
  short8 bfr[4][4];
  float wx0[4], wx1[4], be[4];
#pragma unroll
  for (int q = 0; q < 4; ++q) {
    int g = q * 128 + w * 16 + lm;
    wx0[q] = wihe[g * 2]; wx1[q] = wihe[g * 2 + 1]; be[q] = beff[g];
#pragma unroll
    for (int ks = 0; ks < 4; ++ks)
      bfr[q][ks] = *(const short8*)(const void*)&whhb[g * 128 + ks * 32 + lg * 8];
  }
  float cst[2][4] = {};
  __syncthreads();
  for (int ts = 0; ts < 8; ++ts) {
    f32x4 acc[2][4];
#pragma unroll
    for (int mi = 0; mi < 2; ++mi)
#pragma unroll
      for (int r = 0; r < 4; ++r) {
        int p = mi * 16 + lg * 4 + r;
        float ox = obs_s[ts][p][0], oy = obs_s[ts][p][1];
#pragma unroll
        for (int q = 0; q < 4; ++q)
          acc[mi][q][r] = be[q] + wx0[q] * ox + wx1[q] * oy;
      }
#pragma unroll
    for (int ks = 0; ks < 4; ++ks) {
      int p0 = lm, p1 = 16 + lm;
      short8 a0 = *(const short8*)(const void*)&Hs[p0 * 128 + ((ks * 32 + lg * 8) ^ ((p0 & 7) << 3))];
      short8 a1 = *(const short8*)(const void*)&Hs[p1 * 128 + ((ks * 32 + lg * 8) ^ ((p1 & 7) << 3))];
#pragma unroll
      for (int q = 0; q < 4; ++q) {
        acc[0][q] = __builtin_amdgcn_mfma_f32_16x16x32_bf16(a0, bfr[q][ks], acc[0][q], 0, 0, 0);
        acc[1][q] = __builtin_amdgcn_mfma_f32_16x16x32_bf16(a1, bfr[q][ks], acc[1][q], 0, 0, 0);
      }
    }
    __syncthreads();
    int d = w * 16 + lm;
#pragma unroll
    for (int mi = 0; mi < 2; ++mi)
#pragma unroll
      for (int r = 0; r < 4; ++r) {
        int p = mi * 16 + lg * 4 + r;
        float xi = acc[mi][0][r], xf = acc[mi][1][r], xg = acc[mi][2][r], xo = acc[mi][3][r];
        float ig = 1.f / (1.f + __expf(-xi));
        float fg = 1.f / (1.f + __expf(-xf));
        xg = fminf(fmaxf(xg, -30.f), 30.f);
        float eg = __expf(-2.f * xg);
        float gg = (1.f - eg) / (1.f + eg);
        float og = 1.f / (1.f + __expf(-xo));
        float cv = fg * cst[mi][r] + ig * gg;
        cst[mi][r] = cv;
        float cvc = fminf(fmaxf(cv, -30.f), 30.f);
        float ec = __expf(-2.f * cvc);
        float th = (1.f - ec) / (1.f + ec);
        ushort hb = f2bf(og * th);
        Hs[p * 128 + (d ^ ((p & 7) << 3))] = hb;
        if (ts == 7) feat[(size_t)(nb + p) * 128 + d] = hb;
      }
    __syncthreads();
  }
}

template<int NF>
__global__ __launch_bounds__(256) void mfma_gemm(
    const ushort* __restrict__ A1, int lda1, int K1,
    const ushort* __restrict__ A2, int lda2,
    const ushort* __restrict__ Bw, int K,
    const float* __restrict__ bias,
    ushort* __restrict__ out, int ldo, int ooff, int relu,
    int sB, int sBias, int sA1, int sOut) {
  int w = threadIdx.x >> 6, l = threadIdx.x & 63;
  int lm = l & 15, lg = l >> 4;
  int z = blockIdx.z;
  A1 += (size_t)z * sA1;
  Bw += (size_t)z * sB;
  bias += (size_t)z * sBias;
  out += (size_t)z * sOut;
  int row = blockIdx.x * 64 + w * 16 + lm;
  int col0 = blockIdx.y * (NF * 16);
  f32x4 acc[NF];
#pragma unroll
  for (int i = 0; i < NF; ++i) acc[i] = (f32x4){0.f, 0.f, 0.f, 0.f};
  const int nks = K >> 5;
  for (int ks = 0; ks < nks; ++ks) {
    int kb = ks * 32 + lg * 8;
    const ushort* ap = (ks * 32 < K1) ? (A1 + (size_t)row * lda1 + kb)
                                      : (A2 + (size_t)row * lda2 + (kb - K1));
    short8 af = *(const short8*)(const void*)ap;
#pragma unroll
    for (int ni = 0; ni < NF; ++ni) {
      short8 bf = *(const short8*)(const void*)(Bw + (size_t)(col0 + ni * 16 + lm) * K + kb);
      acc[ni] = __builtin_amdgcn_mfma_f32_16x16x32_bf16(af, bf, acc[ni], 0, 0, 0);
    }
  }
  int orow0 = blockIdx.x * 64 + w * 16 + lg * 4;
#pragma unroll
  for (int ni = 0; ni < NF; ++ni) {
    int c = col0 + ni * 16 + lm;
    float bv = bias[c];
#pragma unroll
    for (int r = 0; r < 4; ++r) {
      float v = acc[ni][r] + bv;
      if (relu) v = fmaxf(v, 0.f);
      out[(size_t)(orow0 + r) * ldo + ooff + c] = f2bf(v);
    }
  }
}

__global__ __launch_bounds__(256) void traj_mfma(
    const ushort* __restrict__ TD2, const ushort* __restrict__ w3c,
    const float* __restrict__ b3c, const float* __restrict__ obs,
    float* __restrict__ out) {
  int w = threadIdx.x >> 6, l = threadIdx.x & 63;
  int lm = l & 15, lg = l >> 4;
  int m = blockIdx.y;
  const ushort* A = TD2 + (size_t)m * (NPED * 128);
  const ushort* B = w3c + (size_t)m * 4096;
  int row = blockIdx.x * 64 + w * 16 + lm;
  f32x4 acc[2];
  acc[0] = (f32x4){0.f,0.f,0.f,0.f}; acc[1] = (f32x4){0.f,0.f,0.f,0.f};
#pragma unroll
  for (int ks = 0; ks < 4; ++ks) {
    int kb = ks * 32 + lg * 8;
    short8 af = *(const short8*)(const void*)(A + (size_t)row * 128 + kb);
#pragma unroll
    for (int ni = 0; ni < 2; ++ni) {
      short8 bf = *(const short8*)(const void*)(B + (ni * 16 + lm) * 128 + kb);
      acc[ni] = __builtin_amdgcn_mfma_f32_16x16x32_bf16(af, bf, acc[ni], 0, 0, 0);
    }
  }
  int orow0 = blockIdx.x * 64 + w * 16 + lg * 4;
#pragma unroll
  for (int ni = 0; ni < 2; ++ni) {
    int o = ni * 16 + lm;
    if (o < 24) {
      float bb = b3c[m * 24 + o];
      int c = o & 1;
#pragma unroll
      for (int r = 0; r < 4; ++r) {
        int n = orow0 + r;
        out[(size_t)n * 120 + m * 24 + o] = acc[ni][r] + bb + obs[7 * (NPED * 2) + n * 2 + c];
      }
    }
  }
}

// attention v2: vectorized LDS, bf16 tiles w/ XOR chunk swizzle, XCD-grouped scenes.
// grid 2048: scene = bid & 255, ichunk = bid >> 8 (same-scene blocks share an XCD).
__global__ __launch_bounds__(256) void attn_kernel(
    const float* __restrict__ obs, ushort* QKV, const ushort* __restrict__ QW,
    const float* __restrict__ wv2T,
    const float* __restrict__ rpw1, const float* __restrict__ rpb1) {
  __shared__ ushort K0s[32 * 128];   // [j][d] bf16, chunk c(=d>>3) stored at c^(j&7)
  __shared__ ushort V0s[32 * 128];
  __shared__ ushort renc[4 * 32 * 64]; // [ii][j][e] bf16, chunk c(=e>>3) at c^(j&7)
  __shared__ float Qi[4][128];
  __shared__ float QWs[4][256];
  __shared__ float att[4][4][32];
  __shared__ float AR[4][4][64];
  __shared__ float rpx[64], rpy[64], rpb[64];
  __shared__ float posS[32][2];
  __shared__ float posI[4][2];
  int t = threadIdx.x;
  int scene = blockIdx.x & 255, ic = blockIdx.x >> 8;
  int i0 = ic * 4, sbase = scene * 32;

  // ---- stage ----
  for (int idx = t; idx < 1024; idx += 256) {      // K0+V0 short8 copies
    int arr = idx >> 9, j = (idx >> 4) & 31, c = idx & 15;
    short8 v = *(const short8*)(const void*)&QKV[(size_t)(sbase + j) * 384 + 128 + arr * 128 + c * 8];
    ushort* dst = arr ? V0s : K0s;
    *(short8*)(void*)&dst[j * 128 + (c ^ (j & 7)) * 8] = v;
  }
  for (int idx = t; idx < 512; idx += 256) {       // Qi f32
    int ii = idx >> 7, d = idx & 127;
    Qi[ii][d] = bf2f(QKV[(size_t)(sbase + i0 + ii) * 384 + d]);
  }
  for (int idx = t; idx < 1024; idx += 256) {      // QW f32
    int ii = idx >> 8, e = idx & 255;
    QWs[ii][e] = bf2f(QW[(size_t)(sbase + i0 + ii) * 256 + e]);
  }
  if (t < 64) posS[t >> 1][t & 1] = obs[7 * (NPED * 2) + (sbase + (t >> 1)) * 2 + (t & 1)];
  else if (t < 72) {
    int q = t - 64;
    posI[q >> 1][q & 1] = obs[7 * (NPED * 2) + (sbase + i0 + (q >> 1)) * 2 + (q & 1)];
  } else if (t >= 128 && t < 192) {
    int e = t - 128;
    rpx[e] = rpw1[e * 2]; rpy[e] = rpw1[e * 2 + 1]; rpb[e] = rpb1[e];
  }
  __syncthreads();

  // ---- renc ----
  for (int idx = t; idx < 1024; idx += 256) {      // (ii,j,c) chunks of 8 e
    int ii = idx >> 8, j = (idx >> 3) & 31, c = idx & 7;
    float dx = posS[j][0] - posI[ii][0], dy = posS[j][1] - posI[ii][1];
    short8 pk;
#pragma unroll
    for (int r = 0; r < 8; ++r) {
      int e = c * 8 + r;
      pk[r] = (short)f2bf(fmaxf(rpx[e] * dx + rpy[e] * dy + rpb[e], 0.f));
    }
    *(short8*)(void*)&renc[(ii * 32 + j) * 64 + (c ^ (j & 7)) * 8] = pk;
  }
  __syncthreads();

  // ---- scores (scale prefolded into Q/QW) ----
  for (int idx = t; idx < 512; idx += 256) {
    int ii = idx >> 7, h = (idx >> 5) & 3, j = idx & 31;
    float s = 0.f;
#pragma unroll
    for (int cc = 0; cc < 4; ++cc) {
      uint4 kv = *(const uint4*)(const void*)&K0s[j * 128 + (((h * 4 + cc) ^ (j & 7)) * 8)];
      const float4 qa = *(const float4*)&Qi[ii][h * 32 + cc * 8];
      const float4 qb = *(const float4*)&Qi[ii][h * 32 + cc * 8 + 4];
      s += blo(kv.x) * qa.x + bhi(kv.x) * qa.y + blo(kv.y) * qa.z + bhi(kv.y) * qa.w;
      s += blo(kv.z) * qb.x + bhi(kv.z) * qb.y + blo(kv.w) * qb.z + bhi(kv.w) * qb.w;
    }
#pragma unroll
    for (int c = 0; c < 8; ++c) {
      uint4 rv = *(const uint4*)(const void*)&renc[(ii * 32 + j) * 64 + ((c ^ (j & 7)) * 8)];
      const float4 wa = *(const float4*)&QWs[ii][c * 8];
      const float4 wb = *(const float4*)&QWs[ii][c * 8 + 4];
      // note: QWs row offset by h handled below — must index h*64
      (void)wa; (void)wb;
      const float4 ua = *(const float4*)&QWs[ii][h * 64 + c * 8];
      const float4 ub = *(const float4*)&QWs[ii][h * 64 + c * 8 + 4];
      s += blo(rv.x) * ua.x + bhi(rv.x) * ua.y + blo(rv.y) * ua.z + bhi(rv.y) * ua.w;
      s += blo(rv.z) * ub.x + bhi(rv.z) * ub.y + blo(rv.w) * ub.z + bhi(rv.w) * ub.w;
    }
    att[ii][h][j] = s;
  }
  __syncthreads();

  // ---- softmax over j (rows = (ii,h)) ----
  {
    int r = t >> 4, lj = t & 15;
    float v0 = att[r >> 2][r & 3][lj], v1 = att[r >> 2][r & 3][lj + 16];
    float mx = fmaxf(v0, v1);
    mx = fmaxf(mx, __shfl_xor(mx, 8, 16));
    mx = fmaxf(mx, __shfl_xor(mx, 4, 16));
    mx = fmaxf(mx, __shfl_xor(mx, 2, 16));
    mx = fmaxf(mx, __shfl_xor(mx, 1, 16));
    float e0 = expf(v0 - mx), e1 = expf(v1 - mx);
    float sm = e0 + e1;
    sm += __shfl_xor(sm, 8, 16);
    sm += __shfl_xor(sm, 4, 16);
    sm += __shfl_xor(sm, 2, 16);
    sm += __shfl_xor(sm, 1, 16);
    float inv = 1.f / sm;
    att[r >> 2][r & 3][lj] = e0 * inv;
    att[r >> 2][r & 3][lj + 16] = e1 * inv;
  }
  __syncthreads();

  // ---- AR[ii][h][e] = sum_j att * renc ----
  {
    int ii = t >> 6, h = (t >> 4) & 3, e4 = t & 15;
    int c = e4 >> 1, off = (e4 & 1) * 4;
    float a0 = 0.f, a1 = 0.f, a2 = 0.f, a3 = 0.f;
    for (int j = 0; j < 32; ++j) {
      float av = att[ii][h][j];
      uint2 rv = *(const uint2*)(const void*)&renc[(ii * 32 + j) * 64 + ((c ^ (j & 7)) * 8) + off];
      a0 += av * blo(rv.x); a1 += av * bhi(rv.x);
      a2 += av * blo(rv.y); a3 += av * bhi(rv.y);
    }
    *(float4*)&AR[ii][h][e4 * 4] = make_float4(a0, a1, a2, a3);
  }
  __syncthreads();

  // ---- ctx: lane halves split (j-half / e-half), shfl_xor(32) combine ----
  {
    int ii = t >> 6, l = t & 63;
    int h5 = l >> 5, hd4 = l & 31;
    int hd = hd4 * 4, h = hd >> 5;
    float c0 = 0.f, c1 = 0.f, c2 = 0.f, c3 = 0.f;
    int cch = hd >> 3, offh = hd & 7;   // V0 chunk/offset for 4 bf16 at hd
    for (int j = h5 * 16; j < h5 * 16 + 16; ++j) {
      float av = att[ii][h][j];
      uint2 vv = *(const uint2*)(const void*)&V0s[j * 128 + ((cch ^ (j & 7)) * 8) + offh];
      c0 += av * blo(vv.x); c1 += av * bhi(vv.x);
      c2 += av * blo(vv.y); c3 += av * bhi(vv.y);
    }
    for (int e4 = h5 * 8; e4 < h5 * 8 + 8; ++e4) {
      const float4 ar = *(const float4*)&AR[ii][h][e4 * 4];
#pragma unroll
      for (int r = 0; r < 4; ++r) {
        const float4 wv = *(const float4*)&wv2T[(e4 * 4 + r) * 128 + hd];
        float a = (r == 0) ? ar.x : (r == 1) ? ar.y : (r == 2) ? ar.z : ar.w;
        c0 += a * wv.x; c1 += a * wv.y; c2 += a * wv.z; c3 += a * wv.w;
      }
    }
    c0 += __shfl_xor(c0, 32); c1 += __shfl_xor(c1, 32);
    c2 += __shfl_xor(c2, 32); c3 += __shfl_xor(c3, 32);
    if (h5 == 0) {
      ushort4 o;
      o.x = f2bf(c0); o.y = f2bf(c1); o.z = f2bf(c2); o.w = f2bf(c3);
      *(ushort4*)(void*)&QKV[(size_t)(sbase + i0 + ii) * 384 + hd] = o;
    }
  }
}

__global__ __launch_bounds__(256) void probs_kernel(
    const ushort* __restrict__ H1, const float* __restrict__ mpw2,
    const float* __restrict__ mpb2, float* __restrict__ out) {
  __shared__ float Hsm[64][129];
  __shared__ float lgt[64][5];
  int t = threadIdx.x, nb = blockIdx.x * 64;
  for (int idx = t; idx < 8192; idx += 256) Hsm[idx >> 7][idx & 127] = bf2f(H1[(size_t)nb * 128 + idx]);
  __syncthreads();
  for (int idx = t; idx < 320; idx += 256) {
    int p = idx / 5, m = idx % 5;
    float s = mpb2[m];
    for (int k = 0; k < 128; ++k) s += Hsm[p][k] * mpw2[m * 128 + k];
    lgt[p][m] = s;
  }
  __syncthreads();
  if (t < 64) {
    float m0 = lgt[t][0];
#pragma unroll
    for (int j = 1; j < 5; ++j) m0 = fmaxf(m0, lgt[t][j]);
    float e[5], s = 0.f;
#pragma unroll
    for (int j = 0; j < 5; ++j) { e[j] = expf(lgt[t][j] - m0); s += e[j]; }
    float inv = 1.f / s;
#pragma unroll
    for (int j = 0; j < 5; ++j) out[983040 + (size_t)(nb + t) * 5 + j] = e[j] * inv;
  }
}

extern "C" void kernel_launch(void* const* d_in, const int* in_sizes, int n_in,
                              void* d_out, int out_size, void* d_ws, size_t ws_size,
                              hipStream_t stream) {
  (void)in_sizes; (void)n_in; (void)out_size; (void)ws_size;
  const float* obs  = (const float*)d_in[0];
  const float* pew  = (const float*)d_in[1];
  const float* peb  = (const float*)d_in[2];
  const float* wih  = (const float*)d_in[3];
  const float* bih  = (const float*)d_in[4];
  const float* whh  = (const float*)d_in[5];
  const float* bhh  = (const float*)d_in[6];
  const float* rpw1 = (const float*)d_in[7];
  const float* rpb1 = (const float*)d_in[8];
  const float* rpw2 = (const float*)d_in[9];
  const float* rpb2 = (const float*)d_in[10];
  const float* wq   = (const float*)d_in[11];
  const float* bq   = (const float*)d_in[12];
  const float* wk   = (const float*)d_in[13];
  const float* bk   = (const float*)d_in[14];
  const float* wv   = (const float*)d_in[15];
  const float* bv   = (const float*)d_in[16];
  const float* wo   = (const float*)d_in[17];
  const float* bo   = (const float*)d_in[18];
  const float* opw  = (const float*)d_in[19];
  const float* opb  = (const float*)d_in[20];
  const float* mpw1 = (const float*)d_in[21];
  const float* mpb1 = (const float*)d_in[22];
  const float* mpw2 = (const float*)d_in[23];
  const float* mpb2 = (const float*)d_in[24];
  const float* tdw1 = (const float*)d_in[25];
  const float* tdb1 = (const float*)d_in[26];
  const float* tdw2 = (const float*)d_in[27];
  const float* tdb2 = (const float*)d_in[28];
  const float* tdw3 = (const float*)d_in[29];
  const float* tdb3 = (const float*)d_in[30];
  char* wsb = (char*)d_ws;
  float* out = (float*)d_out;

  ushort* whhb   = (ushort*)(wsb + B_WHH);
  ushort* wqkvb  = (ushort*)(wsb + B_WQKV);
  ushort* wob    = (ushort*)(wsb + B_WO);
  ushort* opwb   = (ushort*)(wsb + B_OPW);
  ushort* mpw1b  = (ushort*)(wsb + B_MPW1);
  ushort* tdw1b  = (ushort*)(wsb + B_TDW1);
  ushort* tdw2b  = (ushort*)(wsb + B_TDW2);
  ushort* wk2pb  = (ushort*)(wsb + B_WK2PAD);
  ushort* tdw3cb = (ushort*)(wsb + B_TDW3C);
  ushort* featb  = (ushort*)(wsb + A_FEAT);
  ushort* qkvb   = (ushort*)(wsb + A_QKV);
  ushort* qwb    = (ushort*)(wsb + A_QW);
  ushort* h1mpb  = (ushort*)(wsb + A_H1MP);
  ushort* h1tdb  = (ushort*)(wsb + A_H1TD);

  prep<<<1973, 256, 0, stream>>>(wih, bih, bhh, pew, peb, wk, wv, rpw2, rpb2,
                                 bq, bk, bv, whh, wq, wo, opw, mpw1, tdw1, tdw2,
                                 tdw3, tdb3, wsb);
  lstm_mfma<<<256, 512, 0, stream>>>(obs, whhb, (float*)(wsb + F_WIHE),
                                     (float*)(wsb + F_BEFF), featb);
  // QKV = feat @ [wq_s|wk|wv]^T + [bq_s|bk_eff|bv_eff]
  mfma_gemm<4><<<dim3(128, 6, 1), 256, 0, stream>>>(
      featb, 128, 128, featb, 128, wqkvb, 128, (float*)(wsb + F_BQKV),
      qkvb, 384, 0, 0, 0, 0, 0, 0);
  // QW = Q @ wk2pad^T  (scaled via Q)
  mfma_gemm<4><<<dim3(128, 4, 1), 256, 0, stream>>>(
      qkvb, 384, 128, qkvb, 384, wk2pb, 128, (float*)(wsb + F_ZERO),
      qwb, 256, 0, 0, 0, 0, 0, 0);
  attn_kernel<<<2048, 256, 0, stream>>>(obs, qkvb, qwb, (float*)(wsb + F_WV2T), rpw1, rpb1);
  // AO = ctx @ wo^T + bo (slot1)
  mfma_gemm<4><<<dim3(128, 2, 1), 256, 0, stream>>>(
      qkvb, 384, 128, qkvb, 384, wob, 128, bo, qkvb, 384, 128, 0, 0, 0, 0, 0);
  // EDGE = [feat|AO] @ op_w^T + op_b (slot2)
  mfma_gemm<4><<<dim3(128, 2, 1), 256, 0, stream>>>(
      featb, 128, 128, qkvb + 128, 384, opwb, 256, opb, qkvb, 384, 256, 0, 0, 0, 0, 0);
  // H1MP = relu([feat|EDGE] @ mp_w1^T + mp_b1)
  mfma_gemm<4><<<dim3(128, 2, 1), 256, 0, stream>>>(
      featb, 128, 128, qkvb + 256, 384, mpw1b, 256, mpb1, h1mpb, 128, 0, 1, 0, 0, 0, 0);
  probs_kernel<<<128, 256, 0, stream>>>(h1mpb, mpw2, mpb2, out);
  // TD1 (batched over 5 modes) — overwrites QW region (dead after attn)
  mfma_gemm<4><<<dim3(128, 2, 5), 256, 0, stream>>>(
      featb, 128, 128, qkvb + 256, 384, tdw1b, 256, tdb1, h1tdb, 128, 0, 1,
      32768, 128, 0, 1048576);
  // TD2 in-place
  mfma_gemm<8><<<dim3(128, 1, 5), 256, 0, stream>>>(
      h1tdb, 128, 128, h1tdb, 128, tdw2b, 128, tdb2, h1tdb, 128, 0, 1,
      16384, 128, 1048576, 1048576);
  traj_mfma<<<dim3(128, 5), 256, 0, stream>>>(h1tdb, tdw3cb, (float*)(wsb + F_TDB3C), obs, out);
}

// Round 7
// 276.436 us; speedup vs baseline: 3.1786x; 1.0755x over previous
//
#include <hip/hip_runtime.h>
#include <math.h>

typedef __attribute__((ext_vector_type(8))) short short8;
typedef __attribute__((ext_vector_type(4))) float f32x4;

#define NPED 8192
#define INVS 0.1767766952966369f   // 1/sqrt(32)

// ---- workspace layout (BYTE offsets) ----
#define B_WHH    0          // [512][128] bf16
#define B_WQKV   131072     // [384][128] bf16 (wq_s|wk|wv), wq rows scaled by INVS
#define B_WK2PAD 229376     // [256][128] bf16
#define B_OPWE   294912     // [128][256] bf16  [opw1 | opw2@wo]
#define B_MPW1   360448     // [128][256] bf16
#define B_TDW1   425984     // [5][128][256] bf16
#define B_TDW2   753664     // [5][128][128] bf16
#define B_TDW3C  917504     // [5][32][128] bf16 prefix-summed tdw3
#define F_WIHE   958464     // [512][2] f32
#define F_BEFF   962560     // [512] f32
#define F_WV2T   964608     // [64][128] f32
#define F_BQKV   997376     // [384] f32: bq*INVS | bk_eff | bv_eff
#define F_BEDGE  998912     // [128] f32: opb + opw2@bo
#define F_TDB3C  999424     // [5][24] f32
#define F_ZERO   999936     // [256] f32 zeros
#define A_FEAT   1000960    // [8192][128] bf16
#define A_QKV    3098112    // [8192][640] bf16: ctx<-Q | K0 | V0 | EDGE | QW
// end ~13.6 MB

__device__ __forceinline__ float bf2f(ushort u) {
  union { unsigned i; float f; } v; v.i = ((unsigned)u) << 16; return v.f;
}
__device__ __forceinline__ float blo(unsigned u) {
  union { unsigned i; float f; } v; v.i = u << 16; return v.f;
}
__device__ __forceinline__ float bhi(unsigned u) {
  union { unsigned i; float f; } v; v.i = u & 0xffff0000u; return v.f;
}
__device__ __forceinline__ ushort f2bf(float f) {
  union { float f; unsigned i; } v; v.f = f;
  unsigned r = v.i + 0x7fffu + ((v.i >> 16) & 1u);
  return (ushort)(r >> 16);
}

__global__ __launch_bounds__(256) void prep(
    const float* __restrict__ wih, const float* __restrict__ bih, const float* __restrict__ bhh,
    const float* __restrict__ pew, const float* __restrict__ peb,
    const float* __restrict__ wk, const float* __restrict__ wv,
    const float* __restrict__ rpw2, const float* __restrict__ rpb2,
    const float* __restrict__ bq, const float* __restrict__ bk, const float* __restrict__ bv,
    const float* __restrict__ whh, const float* __restrict__ wq, const float* __restrict__ wo,
    const float* __restrict__ opw, const float* __restrict__ opb, const float* __restrict__ bo,
    const float* __restrict__ mpw1,
    const float* __restrict__ tdw1, const float* __restrict__ tdw2,
    const float* __restrict__ tdw3, const float* __restrict__ tdb3,
    char* __restrict__ wsb) {
  int tid = blockIdx.x * 256 + threadIdx.x;
  if (tid < 512) {
    int d = tid;
    float s0 = 0.f, s1 = 0.f, sb = 0.f;
    for (int e = 0; e < 64; ++e) {
      float w = wih[d * 64 + e];
      s0 += w * pew[e * 2]; s1 += w * pew[e * 2 + 1]; sb += w * peb[e];
    }
    ((float*)(wsb + F_WIHE))[d * 2] = s0;
    ((float*)(wsb + F_WIHE))[d * 2 + 1] = s1;
    ((float*)(wsb + F_BEFF))[d] = bih[d] + bhh[d] + sb;
  } else if (tid < 49664) {           // wqkv [384][128]
    int j = tid - 512; int n = j >> 7, k = j & 127;
    float v = (n < 128) ? wq[n * 128 + k] * INVS
                        : (n < 256) ? wk[(n - 128) * 128 + k] : wv[(n - 256) * 128 + k];
    ((ushort*)(wsb + B_WQKV))[j] = f2bf(v);
  } else if (tid < 82432) {           // wk2pad [256][128]
    int idx = tid - 49664; int r = idx >> 7, d = idx & 127;
    int h = r >> 6, e = r & 63;
    float s = 0.f;
    if ((d >> 5) == h)
      for (int c = 0; c < 128; ++c) s += wk[d * 128 + c] * rpw2[c * 64 + e];
    ((ushort*)(wsb + B_WK2PAD))[idx] = f2bf(s);
  } else if (tid < 115200) {          // opwe [128][256]: [opw1 | opw2@wo]
    int idx = tid - 82432; int o = idx >> 8, k = idx & 255;
    float s;
    if (k < 128) s = opw[o * 256 + k];
    else {
      s = 0.f;
      for (int c = 0; c < 128; ++c) s += opw[o * 256 + 128 + c] * wo[c * 128 + (k - 128)];
    }
    ((ushort*)(wsb + B_OPWE))[idx] = f2bf(s);
  } else if (tid < 147968) {          // mpw1
    int j = tid - 115200; ((ushort*)(wsb + B_MPW1))[j] = f2bf(mpw1[j]);
  } else if (tid < 311808) {          // tdw1
    int j = tid - 147968; ((ushort*)(wsb + B_TDW1))[j] = f2bf(tdw1[j]);
  } else if (tid < 393728) {          // tdw2
    int j = tid - 311808; ((ushort*)(wsb + B_TDW2))[j] = f2bf(tdw2[j]);
  } else if (tid < 414208) {          // tdw3c prefix-summed (cols 24..31 zero)
    int j = tid - 393728; int m = j >> 12, r = j & 4095, o = r >> 7, k = r & 127;
    float s = 0.f;
    if (o < 24) {
      int c = o & 1, jj = o >> 1;
      for (int jp = 0; jp <= jj; ++jp) s += tdw3[(m * 24 + jp * 2 + c) * 128 + k];
    }
    ((ushort*)(wsb + B_TDW3C))[j] = f2bf(s);
  } else if (tid < 414328) {          // tdb3c
    int j = tid - 414208; int m = j / 24, o = j % 24;
    int c = o & 1, jj = o >> 1;
    float s = 0.f;
    for (int jp = 0; jp <= jj; ++jp) s += tdb3[m * 24 + jp * 2 + c];
    ((float*)(wsb + F_TDB3C))[j] = s;
  } else if (tid < 414712) {          // bqkv
    int d = tid - 414328;
    float s;
    if (d < 128) s = bq[d] * INVS;
    else if (d < 256) {
      int dd = d - 128; s = bk[dd];
      for (int c = 0; c < 128; ++c) s += wk[dd * 128 + c] * rpb2[c];
    } else {
      int dd = d - 256; s = bv[dd];
      for (int c = 0; c < 128; ++c) s += wv[dd * 128 + c] * rpb2[c];
    }
    ((float*)(wsb + F_BQKV))[d] = s;
  } else if (tid < 414840) {          // bedge = opb + opw2@bo
    int o = tid - 414712;
    float s = opb[o];
    for (int c = 0; c < 128; ++c) s += opw[o * 256 + 128 + c] * bo[c];
    ((float*)(wsb + F_BEDGE))[o] = s;
  } else if (tid < 415096) {
    ((float*)(wsb + F_ZERO))[tid - 414840] = 0.f;
  } else if (tid < 423288) {          // wv2T [64][128] f32
    int idx = tid - 415096; int e = idx >> 7, hd = idx & 127;
    float s = 0.f;
    for (int c = 0; c < 128; ++c) s += wv[hd * 128 + c] * rpw2[c * 64 + e];
    ((float*)(wsb + F_WV2T))[idx] = s;
  } else if (tid < 488824) {          // whh
    int i = tid - 423288;
    ((ushort*)(wsb + B_WHH))[i] = f2bf(whh[i]);
  }
}

// LSTM (unchanged, verified)
__global__ __launch_bounds__(512) void lstm_mfma(
    const float* __restrict__ obs, const ushort* __restrict__ whhb,
    const float* __restrict__ wihe, const float* __restrict__ beff,
    ushort* __restrict__ feat) {
  __shared__ ushort Hs[32 * 128];
  __shared__ float obs_s[8][32][2];
  int tid = threadIdx.x;
  int w = tid >> 6, l = tid & 63;
  int lm = l & 15, lg = l >> 4;
  int nb = blockIdx.x * 32;
  {
    int ts = tid >> 6, p = (tid >> 1) & 31, c = tid & 1;
    obs_s[ts][p][c] = obs[ts * (NPED * 2) + (nb + p) * 2 + c];
  }
  for (int i = tid; i < 4096; i += 512) Hs[i] = 0;
  short8 bfr[4][4];
  float wx0[4], wx1[4], be[4];
#pragma unroll
  for (int q = 0; q < 4; ++q) {
    int g = q * 128 + w * 16 + lm;
    wx0[q] = wihe[g * 2]; wx1[q] = wihe[g * 2 + 1]; be[q] = beff[g];
#pragma unroll
    for (int ks = 0; ks < 4; ++ks)
      bfr[q][ks] = *(const short8*)(const void*)&whhb[g * 128 + ks * 32 + lg * 8];
  }
  float cst[2][4] = {};
  __syncthreads();
  for (int ts = 0; ts < 8; ++ts) {
    f32x4 acc[2][4];
#pragma unroll
    for (int mi = 0; mi < 2; ++mi)
#pragma unroll
      for (int r = 0; r < 4; ++r) {
        int p = mi * 16 + lg * 4 + r;
        float ox = obs_s[ts][p][0], oy = obs_s[ts][p][1];
#pragma unroll
        for (int q = 0; q < 4; ++q)
          acc[mi][q][r] = be[q] + wx0[q] * ox + wx1[q] * oy;
      }
#pragma unroll
    for (int ks = 0; ks < 4; ++ks) {
      int p0 = lm, p1 = 16 + lm;
      short8 a0 = *(const short8*)(const void*)&Hs[p0 * 128 + ((ks * 32 + lg * 8) ^ ((p0 & 7) << 3))];
      short8 a1 = *(const short8*)(const void*)&Hs[p1 * 128 + ((ks * 32 + lg * 8) ^ ((p1 & 7) << 3))];
#pragma unroll
      for (int q = 0; q < 4; ++q) {
        acc[0][q] = __builtin_amdgcn_mfma_f32_16x16x32_bf16(a0, bfr[q][ks], acc[0][q], 0, 0, 0);
        acc[1][q] = __builtin_amdgcn_mfma_f32_16x16x32_bf16(a1, bfr[q][ks], acc[1][q], 0, 0, 0);
      }
    }
    __syncthreads();
    int d = w * 16 + lm;
#pragma unroll
    for (int mi = 0; mi < 2; ++mi)
#pragma unroll
      for (int r = 0; r < 4; ++r) {
        int p = mi * 16 + lg * 4 + r;
        float xi = acc[mi][0][r], xf = acc[mi][1][r], xg = acc[mi][2][r], xo = acc[mi][3][r];
        float ig = 1.f / (1.f + __expf(-xi));
        float fg = 1.f / (1.f + __expf(-xf));
        xg = fminf(fmaxf(xg, -30.f), 30.f);
        float eg = __expf(-2.f * xg);
        float gg = (1.f - eg) / (1.f + eg);
        float og = 1.f / (1.f + __expf(-xo));
        float cv = fg * cst[mi][r] + ig * gg;
        cst[mi][r] = cv;
        float cvc = fminf(fmaxf(cv, -30.f), 30.f);
        float ec = __expf(-2.f * cvc);
        float th = (1.f - ec) / (1.f + ec);
        ushort hb = f2bf(og * th);
        Hs[p * 128 + (d ^ ((p & 7) << 3))] = hb;
        if (ts == 7) feat[(size_t)(nb + p) * 128 + d] = hb;
      }
    __syncthreads();
  }
}

// MFMA GEMM, K fully unrolled. A = [A1 | A2] split at K1KS*32.
template<int NF, int NKS, int K1KS>
__global__ __launch_bounds__(256) void mfma_gemm(
    const ushort* __restrict__ A1, int lda1,
    const ushort* __restrict__ A2, int lda2,
    const ushort* __restrict__ Bw,
    const float* __restrict__ bias,
    ushort* __restrict__ out, int ldo, int ooff, int relu) {
  int w = threadIdx.x >> 6, l = threadIdx.x & 63;
  int lm = l & 15, lg = l >> 4;
  int row = blockIdx.x * 64 + w * 16 + lm;
  int col0 = blockIdx.y * (NF * 16);
  f32x4 acc[NF];
#pragma unroll
  for (int i = 0; i < NF; ++i) acc[i] = (f32x4){0.f, 0.f, 0.f, 0.f};
#pragma unroll
  for (int ks = 0; ks < NKS; ++ks) {
    int kb = ks * 32 + lg * 8;
    const ushort* ap = (ks < K1KS) ? (A1 + (size_t)row * lda1 + kb)
                                   : (A2 + (size_t)row * lda2 + (kb - K1KS * 32));
    short8 af = *(const short8*)(const void*)ap;
#pragma unroll
    for (int ni = 0; ni < NF; ++ni) {
      short8 bf = *(const short8*)(const void*)(Bw + (size_t)(col0 + ni * 16 + lm) * (NKS * 32) + kb);
      acc[ni] = __builtin_amdgcn_mfma_f32_16x16x32_bf16(af, bf, acc[ni], 0, 0, 0);
    }
  }
  int orow0 = blockIdx.x * 64 + w * 16 + lg * 4;
#pragma unroll
  for (int ni = 0; ni < NF; ++ni) {
    int c = col0 + ni * 16 + lm;
    float bv = bias[c];
#pragma unroll
    for (int r = 0; r < 4; ++r) {
      float v = acc[ni][r] + bv;
      if (relu) v = fmaxf(v, 0.f);
      out[(size_t)(orow0 + r) * ldo + ooff + c] = f2bf(v);
    }
  }
}

// MP gemm (K=256, NF=8) + probs epilogue fused. No H1 write.
__global__ __launch_bounds__(256) void mp_probs(
    const ushort* __restrict__ feat, const ushort* __restrict__ qkv,
    const ushort* __restrict__ w1b, const float* __restrict__ mpb1,
    const float* __restrict__ mpw2, const float* __restrict__ mpb2,
    float* __restrict__ out) {
  __shared__ float w2s[5][128];
  int t = threadIdx.x;
  for (int i = t; i < 640; i += 256) w2s[i >> 7][i & 127] = mpw2[i];
  __syncthreads();
  int w = t >> 6, l = t & 63, lm = l & 15, lg = l >> 4;
  int row = blockIdx.x * 64 + w * 16 + lm;
  f32x4 acc[8];
#pragma unroll
  for (int i = 0; i < 8; ++i) acc[i] = (f32x4){0.f, 0.f, 0.f, 0.f};
#pragma unroll
  for (int ks = 0; ks < 8; ++ks) {
    int kb = ks * 32 + lg * 8;
    const ushort* ap = (ks < 4) ? (feat + (size_t)row * 128 + kb)
                                : (qkv + (size_t)row * 640 + 256 + (kb - 128));
    short8 af = *(const short8*)(const void*)ap;
#pragma unroll
    for (int ni = 0; ni < 8; ++ni) {
      short8 bf = *(const short8*)(const void*)(w1b + (size_t)(ni * 16 + lm) * 256 + kb);
      acc[ni] = __builtin_amdgcn_mfma_f32_16x16x32_bf16(af, bf, acc[ni], 0, 0, 0);
    }
  }
  float bc[8];
#pragma unroll
  for (int ni = 0; ni < 8; ++ni) bc[ni] = mpb1[ni * 16 + lm];
  float lgt[4][5];
#pragma unroll
  for (int r = 0; r < 4; ++r)
#pragma unroll
    for (int m = 0; m < 5; ++m) {
      float s = 0.f;
#pragma unroll
      for (int ni = 0; ni < 8; ++ni)
        s += fmaxf(acc[ni][r] + bc[ni], 0.f) * w2s[m][ni * 16 + lm];
      lgt[r][m] = s;
    }
#pragma unroll
  for (int mask = 1; mask < 16; mask <<= 1)
#pragma unroll
    for (int r = 0; r < 4; ++r)
#pragma unroll
      for (int m = 0; m < 5; ++m)
        lgt[r][m] += __shfl_xor(lgt[r][m], mask);
  if (lm < 5) {
#pragma unroll
    for (int r = 0; r < 4; ++r) {
      float b0 = lgt[r][0] + mpb2[0];
      float mx = b0;
      float lv[5]; lv[0] = b0;
#pragma unroll
      for (int m = 1; m < 5; ++m) { lv[m] = lgt[r][m] + mpb2[m]; mx = fmaxf(mx, lv[m]); }
      float sm = 0.f;
#pragma unroll
      for (int m = 0; m < 5; ++m) { lv[m] = expf(lv[m] - mx); sm += lv[m]; }
      int n = blockIdx.x * 64 + w * 16 + lg * 4 + r;
      out[983040 + (size_t)n * 5 + lm] = lv[lm] / sm;
    }
  }
}

// TD1 -> TD2 -> traj fused per mode. LDS slab [64][136] bf16, in-place per-wave.
__global__ __launch_bounds__(256) void td_fused(
    const ushort* __restrict__ feat, const ushort* __restrict__ qkv,
    const ushort* __restrict__ w1b, const float* __restrict__ tdb1,
    const ushort* __restrict__ w2b, const float* __restrict__ tdb2,
    const ushort* __restrict__ w3c, const float* __restrict__ b3c,
    const float* __restrict__ obs, float* __restrict__ out) {
  __shared__ ushort slab[64 * 136];
  int t = threadIdx.x, w = t >> 6, l = t & 63, lm = l & 15, lg = l >> 4;
  int m = blockIdx.y;
  int row = blockIdx.x * 64 + w * 16 + lm;
  const ushort* W1 = w1b + (size_t)m * 32768;
  const ushort* W2 = w2b + (size_t)m * 16384;
  const ushort* W3 = w3c + (size_t)m * 4096;
  const float* B1 = tdb1 + m * 128;
  const float* B2 = tdb2 + m * 128;
  // --- TD1: [feat|EDGE] @ W1^T, K=256 ---
  f32x4 a1[8];
#pragma unroll
  for (int i = 0; i < 8; ++i) a1[i] = (f32x4){0.f, 0.f, 0.f, 0.f};
#pragma unroll
  for (int ks = 0; ks < 8; ++ks) {
    int kb = ks * 32 + lg * 8;
    const ushort* ap = (ks < 4) ? (feat + (size_t)row * 128 + kb)
                                : (qkv + (size_t)row * 640 + 256 + (kb - 128));
    short8 af = *(const short8*)(const void*)ap;
#pragma unroll
    for (int ni = 0; ni < 8; ++ni) {
      short8 bf = *(const short8*)(const void*)(W1 + (size_t)(ni * 16 + lm) * 256 + kb);
      a1[ni] = __builtin_amdgcn_mfma_f32_16x16x32_bf16(af, bf, a1[ni], 0, 0, 0);
    }
  }
#pragma unroll
  for (int ni = 0; ni < 8; ++ni) {
    float bb = B1[ni * 16 + lm];
#pragma unroll
    for (int r = 0; r < 4; ++r)
      slab[(w * 16 + lg * 4 + r) * 136 + ni * 16 + lm] = f2bf(fmaxf(a1[ni][r] + bb, 0.f));
  }
  __syncthreads();
  // --- TD2: slab @ W2^T, K=128, in-place (read-all-then-write per wave) ---
  short8 af2[4];
#pragma unroll
  for (int ks = 0; ks < 4; ++ks)
    af2[ks] = *(const short8*)(const void*)&slab[(w * 16 + lm) * 136 + ks * 32 + lg * 8];
  f32x4 a2[8];
#pragma unroll
  for (int i = 0; i < 8; ++i) a2[i] = (f32x4){0.f, 0.f, 0.f, 0.f};
#pragma unroll
  for (int ks = 0; ks < 4; ++ks) {
    int kb = ks * 32 + lg * 8;
#pragma unroll
    for (int ni = 0; ni < 8; ++ni) {
      short8 bf = *(const short8*)(const void*)(W2 + (size_t)(ni * 16 + lm) * 128 + kb);
      a2[ni] = __builtin_amdgcn_mfma_f32_16x16x32_bf16(af2[ks], bf, a2[ni], 0, 0, 0);
    }
  }
  __syncthreads();
#pragma unroll
  for (int ni = 0; ni < 8; ++ni) {
    float bb = B2[ni * 16 + lm];
#pragma unroll
    for (int r = 0; r < 4; ++r)
      slab[(w * 16 + lg * 4 + r) * 136 + ni * 16 + lm] = f2bf(fmaxf(a2[ni][r] + bb, 0.f));
  }
  __syncthreads();
  // --- traj: slab @ w3c^T (+prefix bias + last_pos), N=24 of 32 ---
  short8 af3[4];
#pragma unroll
  for (int ks = 0; ks < 4; ++ks)
    af3[ks] = *(const short8*)(const void*)&slab[(w * 16 + lm) * 136 + ks * 32 + lg * 8];
  f32x4 a3[2];
  a3[0] = (f32x4){0.f, 0.f, 0.f, 0.f}; a3[1] = (f32x4){0.f, 0.f, 0.f, 0.f};
#pragma unroll
  for (int ks = 0; ks < 4; ++ks) {
    int kb = ks * 32 + lg * 8;
#pragma unroll
    for (int ni = 0; ni < 2; ++ni) {
      short8 bf = *(const short8*)(const void*)(W3 + (size_t)(ni * 16 + lm) * 128 + kb);
      a3[ni] = __builtin_amdgcn_mfma_f32_16x16x32_bf16(af3[ks], bf, a3[ni], 0, 0, 0);
    }
  }
#pragma unroll
  for (int ni = 0; ni < 2; ++ni) {
    int o = ni * 16 + lm;
    if (o < 24) {
      float bb = b3c[m * 24 + o];
      int c = o & 1;
#pragma unroll
      for (int r = 0; r < 4; ++r) {
        int n = blockIdx.x * 64 + w * 16 + lg * 4 + r;
        out[(size_t)n * 120 + m * 24 + o] = a3[ni][r] + bb + obs[7 * (NPED * 2) + n * 2 + c];
      }
    }
  }
}

// attention (row layout 640; QW bf16 in cols 384..640; ctx -> cols 0..128)
__global__ __launch_bounds__(256) void attn_kernel(
    const float* __restrict__ obs, ushort* QKV,
    const float* __restrict__ wv2T,
    const float* __restrict__ rpw1, const float* __restrict__ rpb1) {
  __shared__ ushort K0s[32 * 128];
  __shared__ ushort V0s[32 * 128];
  __shared__ ushort renc[4 * 32 * 64];
  __shared__ float Qi[4][128];
  __shared__ float QWs[4][256];
  __shared__ float att[4][4][32];
  __shared__ float AR[4][4][64];
  __shared__ float rpx[64], rpy[64], rpb[64];
  __shared__ float posS[32][2];
  __shared__ float posI[4][2];
  int t = threadIdx.x;
  int scene = blockIdx.x & 255, ic = blockIdx.x >> 8;
  int i0 = ic * 4, sbase = scene * 32;

  for (int idx = t; idx < 1024; idx += 256) {
    int arr = idx >> 9, j = (idx >> 4) & 31, c = idx & 15;
    short8 v = *(const short8*)(const void*)&QKV[(size_t)(sbase + j) * 640 + 128 + arr * 128 + c * 8];
    ushort* dst = arr ? V0s : K0s;
    *(short8*)(void*)&dst[j * 128 + (c ^ (j & 7)) * 8] = v;
  }
  for (int idx = t; idx < 512; idx += 256) {
    int ii = idx >> 7, d = idx & 127;
    Qi[ii][d] = bf2f(QKV[(size_t)(sbase + i0 + ii) * 640 + d]);
  }
  for (int idx = t; idx < 1024; idx += 256) {
    int ii = idx >> 8, e = idx & 255;
    QWs[ii][e] = bf2f(QKV[(size_t)(sbase + i0 + ii) * 640 + 384 + e]);
  }
  if (t < 64) posS[t >> 1][t & 1] = obs[7 * (NPED * 2) + (sbase + (t >> 1)) * 2 + (t & 1)];
  else if (t < 72) {
    int q = t - 64;
    posI[q >> 1][q & 1] = obs[7 * (NPED * 2) + (sbase + i0 + (q >> 1)) * 2 + (q & 1)];
  } else if (t >= 128 && t < 192) {
    int e = t - 128;
    rpx[e] = rpw1[e * 2]; rpy[e] = rpw1[e * 2 + 1]; rpb[e] = rpb1[e];
  }
  __syncthreads();

  for (int idx = t; idx < 1024; idx += 256) {
    int ii = idx >> 8, j = (idx >> 3) & 31, c = idx & 7;
    float dx = posS[j][0] - posI[ii][0], dy = posS[j][1] - posI[ii][1];
    short8 pk;
#pragma unroll
    for (int r = 0; r < 8; ++r) {
      int e = c * 8 + r;
      pk[r] = (short)f2bf(fmaxf(rpx[e] * dx + rpy[e] * dy + rpb[e], 0.f));
    }
    *(short8*)(void*)&renc[(ii * 32 + j) * 64 + (c ^ (j & 7)) * 8] = pk;
  }
  __syncthreads();

  for (int idx = t; idx < 512; idx += 256) {
    int ii = idx >> 7, h = (idx >> 5) & 3, j = idx & 31;
    float s = 0.f;
#pragma unroll
    for (int cc = 0; cc < 4; ++cc) {
      uint4 kv = *(const uint4*)(const void*)&K0s[j * 128 + (((h * 4 + cc) ^ (j & 7)) * 8)];
      const float4 qa = *(const float4*)&Qi[ii][h * 32 + cc * 8];
      const float4 qb = *(const float4*)&Qi[ii][h * 32 + cc * 8 + 4];
      s += blo(kv.x) * qa.x + bhi(kv.x) * qa.y + blo(kv.y) * qa.z + bhi(kv.y) * qa.w;
      s += blo(kv.z) * qb.x + bhi(kv.z) * qb.y + blo(kv.w) * qb.z + bhi(kv.w) * qb.w;
    }
#pragma unroll
    for (int c = 0; c < 8; ++c) {
      uint4 rv = *(const uint4*)(const void*)&renc[(ii * 32 + j) * 64 + ((c ^ (j & 7)) * 8)];
      const float4 ua = *(const float4*)&QWs[ii][h * 64 + c * 8];
      const float4 ub = *(const float4*)&QWs[ii][h * 64 + c * 8 + 4];
      s += blo(rv.x) * ua.x + bhi(rv.x) * ua.y + blo(rv.y) * ua.z + bhi(rv.y) * ua.w;
      s += blo(rv.z) * ub.x + bhi(rv.z) * ub.y + blo(rv.w) * ub.z + bhi(rv.w) * ub.w;
    }
    att[ii][h][j] = s;
  }
  __syncthreads();

  {
    int r = t >> 4, lj = t & 15;
    float v0 = att[r >> 2][r & 3][lj], v1 = att[r >> 2][r & 3][lj + 16];
    float mx = fmaxf(v0, v1);
    mx = fmaxf(mx, __shfl_xor(mx, 8, 16));
    mx = fmaxf(mx, __shfl_xor(mx, 4, 16));
    mx = fmaxf(mx, __shfl_xor(mx, 2, 16));
    mx = fmaxf(mx, __shfl_xor(mx, 1, 16));
    float e0 = expf(v0 - mx), e1 = expf(v1 - mx);
    float sm = e0 + e1;
    sm += __shfl_xor(sm, 8, 16);
    sm += __shfl_xor(sm, 4, 16);
    sm += __shfl_xor(sm, 2, 16);
    sm += __shfl_xor(sm, 1, 16);
    float inv = 1.f / sm;
    att[r >> 2][r & 3][lj] = e0 * inv;
    att[r >> 2][r & 3][lj + 16] = e1 * inv;
  }
  __syncthreads();

  {
    int ii = t >> 6, h = (t >> 4) & 3, e4 = t & 15;
    int c = e4 >> 1, off = (e4 & 1) * 4;
    float a0 = 0.f, a1 = 0.f, a2 = 0.f, a3 = 0.f;
    for (int j = 0; j < 32; ++j) {
      float av = att[ii][h][j];
      uint2 rv = *(const uint2*)(const void*)&renc[(ii * 32 + j) * 64 + ((c ^ (j & 7)) * 8) + off];
      a0 += av * blo(rv.x); a1 += av * bhi(rv.x);
      a2 += av * blo(rv.y); a3 += av * bhi(rv.y);
    }
    *(float4*)&AR[ii][h][e4 * 4] = make_float4(a0, a1, a2, a3);
  }
  __syncthreads();

  {
    int ii = t >> 6, l = t & 63;
    int h5 = l >> 5, hd4 = l & 31;
    int hd = hd4 * 4, h = hd >> 5;
    float c0 = 0.f, c1 = 0.f, c2 = 0.f, c3 = 0.f;
    int cch = hd >> 3, offh = hd & 7;
    for (int j = h5 * 16; j < h5 * 16 + 16; ++j) {
      float av = att[ii][h][j];
      uint2 vv = *(const uint2*)(const void*)&V0s[j * 128 + ((cch ^ (j & 7)) * 8) + offh];
      c0 += av * blo(vv.x); c1 += av * bhi(vv.x);
      c2 += av * blo(vv.y); c3 += av * bhi(vv.y);
    }
    for (int e4 = h5 * 8; e4 < h5 * 8 + 8; ++e4) {
      const float4 ar = *(const float4*)&AR[ii][h][e4 * 4];
#pragma unroll
      for (int r = 0; r < 4; ++r) {
        const float4 wv = *(const float4*)&wv2T[(e4 * 4 + r) * 128 + hd];
        float a = (r == 0) ? ar.x : (r == 1) ? ar.y : (r == 2) ? ar.z : ar.w;
        c0 += a * wv.x; c1 += a * wv.y; c2 += a * wv.z; c3 += a * wv.w;
      }
    }
    c0 += __shfl_xor(c0, 32); c1 += __shfl_xor(c1, 32);
    c2 += __shfl_xor(c2, 32); c3 += __shfl_xor(c3, 32);
    if (h5 == 0) {
      ushort4 o;
      o.x = f2bf(c0); o.y = f2bf(c1); o.z = f2bf(c2); o.w = f2bf(c3);
      *(ushort4*)(void*)&QKV[(size_t)(sbase + i0 + ii) * 640 + hd] = o;
    }
  }
}

extern "C" void kernel_launch(void* const* d_in, const int* in_sizes, int n_in,
                              void* d_out, int out_size, void* d_ws, size_t ws_size,
                              hipStream_t stream) {
  (void)in_sizes; (void)n_in; (void)out_size; (void)ws_size;
  const float* obs  = (const float*)d_in[0];
  const float* pew  = (const float*)d_in[1];
  const float* peb  = (const float*)d_in[2];
  const float* wih  = (const float*)d_in[3];
  const float* bih  = (const float*)d_in[4];
  const float* whh  = (const float*)d_in[5];
  const float* bhh  = (const float*)d_in[6];
  const float* rpw1 = (const float*)d_in[7];
  const float* rpb1 = (const float*)d_in[8];
  const float* rpw2 = (const float*)d_in[9];
  const float* rpb2 = (const float*)d_in[10];
  const float* wq   = (const float*)d_in[11];
  const float* bq   = (const float*)d_in[12];
  const float* wk   = (const float*)d_in[13];
  const float* bk   = (const float*)d_in[14];
  const float* wv   = (const float*)d_in[15];
  const float* bv   = (const float*)d_in[16];
  const float* wo   = (const float*)d_in[17];
  const float* bo   = (const float*)d_in[18];
  const float* opw  = (const float*)d_in[19];
  const float* opb  = (const float*)d_in[20];
  const float* mpw1 = (const float*)d_in[21];
  const float* mpb1 = (const float*)d_in[22];
  const float* mpw2 = (const float*)d_in[23];
  const float* mpb2 = (const float*)d_in[24];
  const float* tdw1 = (const float*)d_in[25];
  const float* tdb1 = (const float*)d_in[26];
  const float* tdw2 = (const float*)d_in[27];
  const float* tdb2 = (const float*)d_in[28];
  const float* tdw3 = (const float*)d_in[29];
  const float* tdb3 = (const float*)d_in[30];
  char* wsb = (char*)d_ws;
  float* out = (float*)d_out;

  ushort* whhb   = (ushort*)(wsb + B_WHH);
  ushort* wqkvb  = (ushort*)(wsb + B_WQKV);
  ushort* wk2pb  = (ushort*)(wsb + B_WK2PAD);
  ushort* opweb  = (ushort*)(wsb + B_OPWE);
  ushort* mpw1b  = (ushort*)(wsb + B_MPW1);
  ushort* tdw1b  = (ushort*)(wsb + B_TDW1);
  ushort* tdw2b  = (ushort*)(wsb + B_TDW2);
  ushort* tdw3cb = (ushort*)(wsb + B_TDW3C);
  ushort* featb  = (ushort*)(wsb + A_FEAT);
  ushort* qkvb   = (ushort*)(wsb + A_QKV);

  prep<<<1910, 256, 0, stream>>>(wih, bih, bhh, pew, peb, wk, wv, rpw2, rpb2,
                                 bq, bk, bv, whh, wq, wo, opw, opb, bo, mpw1,
                                 tdw1, tdw2, tdw3, tdb3, wsb);
  lstm_mfma<<<256, 512, 0, stream>>>(obs, whhb, (float*)(wsb + F_WIHE),
                                     (float*)(wsb + F_BEFF), featb);
  // QKV (cols 0..383 of 640-wide rows)
  mfma_gemm<4, 4, 4><<<dim3(128, 6), 256, 0, stream>>>(
      featb, 128, featb, 128, wqkvb, (float*)(wsb + F_BQKV), qkvb, 640, 0, 0);
  // QW = Q @ wk2pad^T (cols 384..639)
  mfma_gemm<4, 4, 4><<<dim3(128, 4), 256, 0, stream>>>(
      qkvb, 640, qkvb, 640, wk2pb, (float*)(wsb + F_ZERO), qkvb, 640, 384, 0);
  attn_kernel<<<2048, 256, 0, stream>>>(obs, qkvb, (float*)(wsb + F_WV2T), rpw1, rpb1);
  // EDGE = [feat|ctx] @ [opw1|opw2@wo]^T + bedge  -> cols 256..383
  mfma_gemm<4, 8, 4><<<dim3(128, 2), 256, 0, stream>>>(
      featb, 128, qkvb, 640, opweb, (float*)(wsb + F_BEDGE), qkvb, 640, 256, 0);
  // MP head + probs (fused, no H1 write)
  mp_probs<<<128, 256, 0, stream>>>(featb, qkvb, mpw1b, mpb1, mpw2, mpb2, out);
  // TD1+TD2+traj fused per mode
  td_fused<<<dim3(128, 5), 256, 0, stream>>>(featb, qkvb, tdw1b, tdb1, tdw2b, tdb2,
                                             tdw3cb, (float*)(wsb + F_TDB3C), obs, out);
}

// Round 9
// 272.242 us; speedup vs baseline: 3.2276x; 1.0154x over previous
//
#include <hip/hip_runtime.h>
#include <math.h>

typedef __attribute__((ext_vector_type(8))) short short8;
typedef __attribute__((ext_vector_type(4))) float f32x4;

#define NPED 8192
#define INVS 0.1767766952966369f   // 1/sqrt(32)

// ---- workspace layout (BYTE offsets) ----
#define B_WHH    0          // [512][128] bf16
#define B_WQKV   131072     // [640][128] bf16 (wq_s|wk|wv|wqw)
#define B_WK2PAD 294912     // [256][128] bf16
#define B_OPWE   360448     // [128][256] bf16  [opw1 | opw2@wo]
#define B_MPW1   425984     // [128][256] bf16
#define B_TDW1   491520     // [5][128][256] bf16
#define B_TDW2   819200     // [5][128][128] bf16
#define B_TDW3C  983040     // [5][32][128] bf16 prefix-summed tdw3
#define F_WIHE   1024000    // [512][2] f32
#define F_BEFF   1028096    // [512] f32
#define F_WV2T   1030144    // [64][128] f32
#define F_BQKV   1062912    // [640] f32: bq*INVS | bk_eff | bv_eff | qwbias
#define F_BEDGE  1065472    // [128] f32: opb + opw2@bo
#define F_TDB3C  1065984    // [5][24] f32
#define A_FEAT   1066496    // [8192][128] bf16
#define A_QKV    3163648    // [8192][640] bf16: ctx<-Q | K0 | V0 | EDGE | QW
// end ~13.65 MB

__device__ __forceinline__ float bf2f(ushort u) {
  union { unsigned i; float f; } v; v.i = ((unsigned)u) << 16; return v.f;
}
__device__ __forceinline__ float blo(unsigned u) {
  union { unsigned i; float f; } v; v.i = u << 16; return v.f;
}
__device__ __forceinline__ float bhi(unsigned u) {
  union { unsigned i; float f; } v; v.i = u & 0xffff0000u; return v.f;
}
__device__ __forceinline__ ushort f2bf(float f) {
  union { float f; unsigned i; } v; v.f = f;
  unsigned r = v.i + 0x7fffu + ((v.i >> 16) & 1u);
  return (ushort)(r >> 16);
}

__global__ __launch_bounds__(256) void prep(
    const float* __restrict__ wih, const float* __restrict__ bih, const float* __restrict__ bhh,
    const float* __restrict__ pew, const float* __restrict__ peb,
    const float* __restrict__ wk, const float* __restrict__ wv,
    const float* __restrict__ rpw2, const float* __restrict__ rpb2,
    const float* __restrict__ bq, const float* __restrict__ bk, const float* __restrict__ bv,
    const float* __restrict__ whh, const float* __restrict__ wq, const float* __restrict__ wo,
    const float* __restrict__ opw, const float* __restrict__ opb, const float* __restrict__ bo,
    const float* __restrict__ mpw1,
    const float* __restrict__ tdw1, const float* __restrict__ tdw2,
    const float* __restrict__ tdw3, const float* __restrict__ tdb3,
    char* __restrict__ wsb) {
  int tid = blockIdx.x * 256 + threadIdx.x;
  if (tid < 512) {
    int d = tid;
    float s0 = 0.f, s1 = 0.f, sb = 0.f;
    for (int e = 0; e < 64; ++e) {
      float w = wih[d * 64 + e];
      s0 += w * pew[e * 2]; s1 += w * pew[e * 2 + 1]; sb += w * peb[e];
    }
    ((float*)(wsb + F_WIHE))[d * 2] = s0;
    ((float*)(wsb + F_WIHE))[d * 2 + 1] = s1;
    ((float*)(wsb + F_BEFF))[d] = bih[d] + bhh[d] + sb;
  } else if (tid < 49664) {           // wqkv rows 0..383
    int j = tid - 512; int n = j >> 7, k = j & 127;
    float v = (n < 128) ? wq[n * 128 + k] * INVS
                        : (n < 256) ? wk[(n - 128) * 128 + k] : wv[(n - 256) * 128 + k];
    ((ushort*)(wsb + B_WQKV))[j] = f2bf(v);
  } else if (tid < 82432) {           // wk2pad [256][128]
    int idx = tid - 49664; int r = idx >> 7, d = idx & 127;
    int h = r >> 6, e = r & 63;
    float s = 0.f;
    if ((d >> 5) == h)
      for (int c = 0; c < 128; ++c) s += wk[d * 128 + c] * rpw2[c * 64 + e];
    ((ushort*)(wsb + B_WK2PAD))[idx] = f2bf(s);
  } else if (tid < 115200) {          // opwe [128][256]: [opw1 | opw2@wo]
    int idx = tid - 82432; int o = idx >> 8, k = idx & 255;
    float s;
    if (k < 128) s = opw[o * 256 + k];
    else {
      s = 0.f;
      for (int c = 0; c < 128; ++c) s += opw[o * 256 + 128 + c] * wo[c * 128 + (k - 128)];
    }
    ((ushort*)(wsb + B_OPWE))[idx] = f2bf(s);
  } else if (tid < 147968) {          // mpw1
    int j = tid - 115200; ((ushort*)(wsb + B_MPW1))[j] = f2bf(mpw1[j]);
  } else if (tid < 311808) {          // tdw1
    int j = tid - 147968; ((ushort*)(wsb + B_TDW1))[j] = f2bf(tdw1[j]);
  } else if (tid < 393728) {          // tdw2
    int j = tid - 311808; ((ushort*)(wsb + B_TDW2))[j] = f2bf(tdw2[j]);
  } else if (tid < 414208) {          // tdw3c prefix-summed (cols 24..31 zero)
    int j = tid - 393728; int m = j >> 12, r = j & 4095, o = r >> 7, k = r & 127;
    float s = 0.f;
    if (o < 24) {
      int c = o & 1, jj = o >> 1;
      for (int jp = 0; jp <= jj; ++jp) s += tdw3[(m * 24 + jp * 2 + c) * 128 + k];
    }
    ((ushort*)(wsb + B_TDW3C))[j] = f2bf(s);
  } else if (tid < 414328) {          // tdb3c
    int j = tid - 414208; int m = j / 24, o = j % 24;
    int c = o & 1, jj = o >> 1;
    float s = 0.f;
    for (int jp = 0; jp <= jj; ++jp) s += tdb3[m * 24 + jp * 2 + c];
    ((float*)(wsb + F_TDB3C))[j] = s;
  } else if (tid < 414968) {          // bqkv [640] (tail 384+ zero; prep2 fills qwbias)
    int d = tid - 414328;
    float s = 0.f;
    if (d < 128) s = bq[d] * INVS;
    else if (d < 256) {
      int dd = d - 128; s = bk[dd];
      for (int c = 0; c < 128; ++c) s += wk[dd * 128 + c] * rpb2[c];
    } else if (d < 384) {
      int dd = d - 256; s = bv[dd];
      for (int c = 0; c < 128; ++c) s += wv[dd * 128 + c] * rpb2[c];
    }
    ((float*)(wsb + F_BQKV))[d] = s;
  } else if (tid < 415096) {          // bedge = opb + opw2@bo
    int o = tid - 414968;
    float s = opb[o];
    for (int c = 0; c < 128; ++c) s += opw[o * 256 + 128 + c] * bo[c];
    ((float*)(wsb + F_BEDGE))[o] = s;
  } else if (tid < 423288) {          // wv2T [64][128] f32
    int idx = tid - 415096; int e = idx >> 7, hd = idx & 127;
    float s = 0.f;
    for (int c = 0; c < 128; ++c) s += wv[hd * 128 + c] * rpw2[c * 64 + e];
    ((float*)(wsb + F_WV2T))[idx] = s;
  } else if (tid < 488824) {          // whh
    int i = tid - 423288;
    ((ushort*)(wsb + B_WHH))[i] = f2bf(whh[i]);
  }
}

// prep2: wqw rows 384..639 of wqkv  (= wk2pad @ wq_s^T), and qwbias.
__global__ __launch_bounds__(256) void prep2(
    const ushort* __restrict__ wk2pad, const float* __restrict__ wq,
    const float* __restrict__ bq, ushort* __restrict__ wqkv, float* __restrict__ bqkv) {
  int idx = blockIdx.x * 256 + threadIdx.x;
  if (idx < 32768) {
    int e = idx >> 7, k = idx & 127, h = e >> 6;
    float s = 0.f;
    for (int dd = 0; dd < 32; ++dd) {
      int d = h * 32 + dd;
      s += bf2f(wk2pad[e * 128 + d]) * wq[d * 128 + k];
    }
    wqkv[(384 + e) * 128 + k] = f2bf(s * INVS);
  } else if (idx < 33024) {
    int e = idx - 32768, h = e >> 6;
    float s = 0.f;
    for (int dd = 0; dd < 32; ++dd) {
      int d = h * 32 + dd;
      s += bf2f(wk2pad[e * 128 + d]) * bq[d];
    }
    bqkv[384 + e] = s * INVS;
  }
}

// LSTM (unchanged, verified)
__global__ __launch_bounds__(512) void lstm_mfma(
    const float* __restrict__ obs, const ushort* __restrict__ whhb,
    const float* __restrict__ wihe, const float* __restrict__ beff,
    ushort* __restrict__ feat) {
  __shared__ ushort Hs[32 * 128];
  __shared__ float obs_s[8][32][2];
  int tid = threadIdx.x;
  int w = tid >> 6, l = tid & 63;
  int lm = l & 15, lg = l >> 4;
  int nb = blockIdx.x * 32;
  {
    int ts = tid >> 6, p = (tid >> 1) & 31, c = tid & 1;
    obs_s[ts][p][c] = obs[ts * (NPED * 2) + (nb + p) * 2 + c];
  }
  for (int i = tid; i < 4096; i += 512) Hs[i] = 0;
  short8 bfr[4][4];
  float wx0[4], wx1[4], be[4];
#pragma unroll
  for (int q = 0; q < 4; ++q) {
    int g = q * 128 + w * 16 + lm;
    wx0[q] = wihe[g * 2]; wx1[q] = wihe[g * 2 + 1]; be[q] = beff[g];
#pragma unroll
    for (int ks = 0; ks < 4; ++ks)
      bfr[q][ks] = *(const short8*)(const void*)&whhb[g * 128 + ks * 32 + lg * 8];
  }
  float cst[2][4] = {};
  __syncthreads();
  for (int ts = 0; ts < 8; ++ts) {
    f32x4 acc[2][4];
#pragma unroll
    for (int mi = 0; mi < 2; ++mi)
#pragma unroll
      for (int r = 0; r < 4; ++r) {
        int p = mi * 16 + lg * 4 + r;
        float ox = obs_s[ts][p][0], oy = obs_s[ts][p][1];
#pragma unroll
        for (int q = 0; q < 4; ++q)
          acc[mi][q][r] = be[q] + wx0[q] * ox + wx1[q] * oy;
      }
#pragma unroll
    for (int ks = 0; ks < 4; ++ks) {
      int p0 = lm, p1 = 16 + lm;
      short8 a0 = *(const short8*)(const void*)&Hs[p0 * 128 + ((ks * 32 + lg * 8) ^ ((p0 & 7) << 3))];
      short8 a1 = *(const short8*)(const void*)&Hs[p1 * 128 + ((ks * 32 + lg * 8) ^ ((p1 & 7) << 3))];
#pragma unroll
      for (int q = 0; q < 4; ++q) {
        acc[0][q] = __builtin_amdgcn_mfma_f32_16x16x32_bf16(a0, bfr[q][ks], acc[0][q], 0, 0, 0);
        acc[1][q] = __builtin_amdgcn_mfma_f32_16x16x32_bf16(a1, bfr[q][ks], acc[1][q], 0, 0, 0);
      }
    }
    __syncthreads();
    int d = w * 16 + lm;
#pragma unroll
    for (int mi = 0; mi < 2; ++mi)
#pragma unroll
      for (int r = 0; r < 4; ++r) {
        int p = mi * 16 + lg * 4 + r;
        float xi = acc[mi][0][r], xf = acc[mi][1][r], xg = acc[mi][2][r], xo = acc[mi][3][r];
        float ig = 1.f / (1.f + __expf(-xi));
        float fg = 1.f / (1.f + __expf(-xf));
        xg = fminf(fmaxf(xg, -30.f), 30.f);
        float eg = __expf(-2.f * xg);
        float gg = (1.f - eg) / (1.f + eg);
        float og = 1.f / (1.f + __expf(-xo));
        float cv = fg * cst[mi][r] + ig * gg;
        cst[mi][r] = cv;
        float cvc = fminf(fmaxf(cv, -30.f), 30.f);
        float ec = __expf(-2.f * cvc);
        float th = (1.f - ec) / (1.f + ec);
        ushort hb = f2bf(og * th);
        Hs[p * 128 + (d ^ ((p & 7) << 3))] = hb;
        if (ts == 7) feat[(size_t)(nb + p) * 128 + d] = hb;
      }
    __syncthreads();
  }
}

// MFMA GEMM with A-preload + register-double-buffered B (latency pipelining).
template<int NF, int NKS, int K1KS>
__global__ __launch_bounds__(256) void mfma_gemm(
    const ushort* __restrict__ A1, int lda1,
    const ushort* __restrict__ A2, int lda2,
    const ushort* __restrict__ Bw,
    const float* __restrict__ bias,
    ushort* __restrict__ out, int ldo, int ooff, int relu) {
  int w = threadIdx.x >> 6, l = threadIdx.x & 63;
  int lm = l & 15, lg = l >> 4;
  int row = blockIdx.x * 64 + w * 16 + lm;
  int col0 = blockIdx.y * (NF * 16);
  f32x4 acc[NF];
#pragma unroll
  for (int i = 0; i < NF; ++i) acc[i] = (f32x4){0.f, 0.f, 0.f, 0.f};
  short8 afA[NKS];
#pragma unroll
  for (int ks = 0; ks < NKS; ++ks) {
    const ushort* ap = (ks < K1KS) ? (A1 + (size_t)row * lda1 + ks * 32 + lg * 8)
                                   : (A2 + (size_t)row * lda2 + (ks - K1KS) * 32 + lg * 8);
    afA[ks] = *(const short8*)(const void*)ap;
  }
  short8 bA[NF], bB[NF];
#pragma unroll
  for (int ni = 0; ni < NF; ++ni)
    bA[ni] = *(const short8*)(const void*)(Bw + (size_t)(col0 + ni * 16 + lm) * (NKS * 32) + lg * 8);
#pragma unroll
  for (int ks = 0; ks < NKS; ++ks) {
    short8* cur = (ks & 1) ? bB : bA;
    short8* nxt = (ks & 1) ? bA : bB;
    if (ks + 1 < NKS) {
#pragma unroll
      for (int ni = 0; ni < NF; ++ni)
        nxt[ni] = *(const short8*)(const void*)(Bw + (size_t)(col0 + ni * 16 + lm) * (NKS * 32) + (ks + 1) * 32 + lg * 8);
    }
#pragma unroll
    for (int ni = 0; ni < NF; ++ni)
      acc[ni] = __builtin_amdgcn_mfma_f32_16x16x32_bf16(afA[ks], cur[ni], acc[ni], 0, 0, 0);
  }
  int orow0 = blockIdx.x * 64 + w * 16 + lg * 4;
#pragma unroll
  for (int ni = 0; ni < NF; ++ni) {
    int c = col0 + ni * 16 + lm;
    float bv = bias[c];
#pragma unroll
    for (int r = 0; r < 4; ++r) {
      float v = acc[ni][r] + bv;
      if (relu) v = fmaxf(v, 0.f);
      out[(size_t)(orow0 + r) * ldo + ooff + c] = f2bf(v);
    }
  }
}

// MP gemm + probs, 256 blocks x 32 rows. Wave pairs split cols; LDS pair-combine.
__global__ __launch_bounds__(256) void mp_probs(
    const ushort* __restrict__ feat, const ushort* __restrict__ qkv,
    const ushort* __restrict__ w1b, const float* __restrict__ mpb1,
    const float* __restrict__ mpw2, const float* __restrict__ mpb2,
    float* __restrict__ out) {
  __shared__ float w2s[5][128];
  __shared__ float pc[2][16][5];
  int t = threadIdx.x;
  for (int i = t; i < 640; i += 256) w2s[i >> 7][i & 127] = mpw2[i];
  int w = t >> 6, l = t & 63, lm = l & 15, lg = l >> 4;
  int g = w >> 1, ch = w & 1, cb = ch * 64;
  int row = blockIdx.x * 32 + g * 16 + lm;
  f32x4 acc[4];
#pragma unroll
  for (int i = 0; i < 4; ++i) acc[i] = (f32x4){0.f, 0.f, 0.f, 0.f};
  short8 afA[8];
#pragma unroll
  for (int ks = 0; ks < 8; ++ks) {
    const ushort* ap = (ks < 4) ? (feat + (size_t)row * 128 + ks * 32 + lg * 8)
                                : (qkv + (size_t)row * 640 + 256 + (ks - 4) * 32 + lg * 8);
    afA[ks] = *(const short8*)(const void*)ap;
  }
  short8 bA[4], bB[4];
#pragma unroll
  for (int ni = 0; ni < 4; ++ni)
    bA[ni] = *(const short8*)(const void*)(w1b + (size_t)(cb + ni * 16 + lm) * 256 + lg * 8);
#pragma unroll
  for (int ks = 0; ks < 8; ++ks) {
    short8* cur = (ks & 1) ? bB : bA;
    short8* nxt = (ks & 1) ? bA : bB;
    if (ks + 1 < 8) {
#pragma unroll
      for (int ni = 0; ni < 4; ++ni)
        nxt[ni] = *(const short8*)(const void*)(w1b + (size_t)(cb + ni * 16 + lm) * 256 + (ks + 1) * 32 + lg * 8);
    }
#pragma unroll
    for (int ni = 0; ni < 4; ++ni)
      acc[ni] = __builtin_amdgcn_mfma_f32_16x16x32_bf16(afA[ks], cur[ni], acc[ni], 0, 0, 0);
  }
  __syncthreads();   // w2s ready
  float bc[4];
#pragma unroll
  for (int ni = 0; ni < 4; ++ni) bc[ni] = mpb1[cb + ni * 16 + lm];
  float lgt[4][5];
#pragma unroll
  for (int r = 0; r < 4; ++r)
#pragma unroll
    for (int m = 0; m < 5; ++m) {
      float s = 0.f;
#pragma unroll
      for (int ni = 0; ni < 4; ++ni)
        s += fmaxf(acc[ni][r] + bc[ni], 0.f) * w2s[m][cb + ni * 16 + lm];
      lgt[r][m] = s;
    }
#pragma unroll
  for (int mask = 1; mask < 16; mask <<= 1)
#pragma unroll
    for (int r = 0; r < 4; ++r)
#pragma unroll
      for (int m = 0; m < 5; ++m)
        lgt[r][m] += __shfl_xor(lgt[r][m], mask);
  if (ch == 1 && lm < 5) {
#pragma unroll
    for (int r = 0; r < 4; ++r) pc[g][lg * 4 + r][lm] = lgt[r][lm];
  }
  __syncthreads();
  if (ch == 0 && lm < 5) {
#pragma unroll
    for (int r = 0; r < 4; ++r) {
      float lv[5], mx = -1e30f, sm = 0.f;
#pragma unroll
      for (int m = 0; m < 5; ++m) {
        lv[m] = lgt[r][m] + pc[g][lg * 4 + r][m] + mpb2[m];
        mx = fmaxf(mx, lv[m]);
      }
#pragma unroll
      for (int m = 0; m < 5; ++m) { lv[m] = expf(lv[m] - mx); sm += lv[m]; }
      int n = blockIdx.x * 32 + g * 16 + lg * 4 + r;
      out[983040 + (size_t)n * 5 + lm] = lv[lm] / sm;
    }
  }
}

// TD1 -> TD2 -> traj fused, register-pipelined B, LDS slab in-place.
__global__ __launch_bounds__(256) void td_fused(
    const ushort* __restrict__ feat, const ushort* __restrict__ qkv,
    const ushort* __restrict__ w1b, const float* __restrict__ tdb1,
    const ushort* __restrict__ w2b, const float* __restrict__ tdb2,
    const ushort* __restrict__ w3c, const float* __restrict__ b3c,
    const float* __restrict__ obs, float* __restrict__ out) {
  __shared__ ushort slab[64 * 136];
  int t = threadIdx.x, w = t >> 6, l = t & 63, lm = l & 15, lg = l >> 4;
  int m = blockIdx.y;
  int row = blockIdx.x * 64 + w * 16 + lm;
  const ushort* W1 = w1b + (size_t)m * 32768;
  const ushort* W2 = w2b + (size_t)m * 16384;
  const ushort* W3 = w3c + (size_t)m * 4096;
  const float* B1 = tdb1 + m * 128;
  const float* B2 = tdb2 + m * 128;
  // --- TD1: [feat|EDGE] @ W1^T, K=256, pipelined ---
  short8 afA[8];
#pragma unroll
  for (int ks = 0; ks < 8; ++ks) {
    const ushort* ap = (ks < 4) ? (feat + (size_t)row * 128 + ks * 32 + lg * 8)
                                : (qkv + (size_t)row * 640 + 256 + (ks - 4) * 32 + lg * 8);
    afA[ks] = *(const short8*)(const void*)ap;
  }
  f32x4 a1[8];
#pragma unroll
  for (int i = 0; i < 8; ++i) a1[i] = (f32x4){0.f, 0.f, 0.f, 0.f};
  {
    short8 bA[8], bB[8];
#pragma unroll
    for (int ni = 0; ni < 8; ++ni)
      bA[ni] = *(const short8*)(const void*)(W1 + (size_t)(ni * 16 + lm) * 256 + lg * 8);
#pragma unroll
    for (int ks = 0; ks < 8; ++ks) {
      short8* cur = (ks & 1) ? bB : bA;
      short8* nxt = (ks & 1) ? bA : bB;
      if (ks + 1 < 8) {
#pragma unroll
        for (int ni = 0; ni < 8; ++ni)
          nxt[ni] = *(const short8*)(const void*)(W1 + (size_t)(ni * 16 + lm) * 256 + (ks + 1) * 32 + lg * 8);
      }
#pragma unroll
      for (int ni = 0; ni < 8; ++ni)
        a1[ni] = __builtin_amdgcn_mfma_f32_16x16x32_bf16(afA[ks], cur[ni], a1[ni], 0, 0, 0);
    }
  }
#pragma unroll
  for (int ni = 0; ni < 8; ++ni) {
    float bb = B1[ni * 16 + lm];
#pragma unroll
    for (int r = 0; r < 4; ++r)
      slab[(w * 16 + lg * 4 + r) * 136 + ni * 16 + lm] = f2bf(fmaxf(a1[ni][r] + bb, 0.f));
  }
  __syncthreads();
  // --- TD2: slab @ W2^T, K=128, pipelined, in-place ---
  short8 af2[4];
#pragma unroll
  for (int ks = 0; ks < 4; ++ks)
    af2[ks] = *(const short8*)(const void*)&slab[(w * 16 + lm) * 136 + ks * 32 + lg * 8];
  f32x4 a2[8];
#pragma unroll
  for (int i = 0; i < 8; ++i) a2[i] = (f32x4){0.f, 0.f, 0.f, 0.f};
  {
    short8 bA[8], bB[8];
#pragma unroll
    for (int ni = 0; ni < 8; ++ni)
      bA[ni] = *(const short8*)(const void*)(W2 + (size_t)(ni * 16 + lm) * 128 + lg * 8);
#pragma unroll
    for (int ks = 0; ks < 4; ++ks) {
      short8* cur = (ks & 1) ? bB : bA;
      short8* nxt = (ks & 1) ? bA : bB;
      if (ks + 1 < 4) {
#pragma unroll
        for (int ni = 0; ni < 8; ++ni)
          nxt[ni] = *(const short8*)(const void*)(W2 + (size_t)(ni * 16 + lm) * 128 + (ks + 1) * 32 + lg * 8);
      }
#pragma unroll
      for (int ni = 0; ni < 8; ++ni)
        a2[ni] = __builtin_amdgcn_mfma_f32_16x16x32_bf16(af2[ks], cur[ni], a2[ni], 0, 0, 0);
    }
  }
  __syncthreads();
#pragma unroll
  for (int ni = 0; ni < 8; ++ni) {
    float bb = B2[ni * 16 + lm];
#pragma unroll
    for (int r = 0; r < 4; ++r)
      slab[(w * 16 + lg * 4 + r) * 136 + ni * 16 + lm] = f2bf(fmaxf(a2[ni][r] + bb, 0.f));
  }
  __syncthreads();
  // --- traj: slab @ w3c^T (+prefix bias + last_pos) ---
  short8 w3f[2][4];
#pragma unroll
  for (int ni = 0; ni < 2; ++ni)
#pragma unroll
    for (int ks = 0; ks < 4; ++ks)
      w3f[ni][ks] = *(const short8*)(const void*)(W3 + (size_t)(ni * 16 + lm) * 128 + ks * 32 + lg * 8);
  short8 af3[4];
#pragma unroll
  for (int ks = 0; ks < 4; ++ks)
    af3[ks] = *(const short8*)(const void*)&slab[(w * 16 + lm) * 136 + ks * 32 + lg * 8];
  f32x4 a3[2];
  a3[0] = (f32x4){0.f, 0.f, 0.f, 0.f}; a3[1] = (f32x4){0.f, 0.f, 0.f, 0.f};
#pragma unroll
  for (int ks = 0; ks < 4; ++ks)
#pragma unroll
    for (int ni = 0; ni < 2; ++ni)
      a3[ni] = __builtin_amdgcn_mfma_f32_16x16x32_bf16(af3[ks], w3f[ni][ks], a3[ni], 0, 0, 0);
#pragma unroll
  for (int ni = 0; ni < 2; ++ni) {
    int o = ni * 16 + lm;
    if (o < 24) {
      float bb = b3c[m * 24 + o];
      int c = o & 1;
#pragma unroll
      for (int r = 0; r < 4; ++r) {
        int n = blockIdx.x * 64 + w * 16 + lg * 4 + r;
        out[(size_t)n * 120 + m * 24 + o] = a3[ni][r] + bb + obs[7 * (NPED * 2) + n * 2 + c];
      }
    }
  }
}

// attention (unchanged; row layout 640)
__global__ __launch_bounds__(256) void attn_kernel(
    const float* __restrict__ obs, ushort* QKV,
    const float* __restrict__ wv2T,
    const float* __restrict__ rpw1, const float* __restrict__ rpb1) {
  __shared__ ushort K0s[32 * 128];
  __shared__ ushort V0s[32 * 128];
  __shared__ ushort renc[4 * 32 * 64];
  __shared__ float Qi[4][128];
  __shared__ float QWs[4][256];
  __shared__ float att[4][4][32];
  __shared__ float AR[4][4][64];
  __shared__ float rpx[64], rpy[64], rpb[64];
  __shared__ float posS[32][2];
  __shared__ float posI[4][2];
  int t = threadIdx.x;
  int scene = blockIdx.x & 255, ic = blockIdx.x >> 8;
  int i0 = ic * 4, sbase = scene * 32;

  for (int idx = t; idx < 1024; idx += 256) {
    int arr = idx >> 9, j = (idx >> 4) & 31, c = idx & 15;
    short8 v = *(const short8*)(const void*)&QKV[(size_t)(sbase + j) * 640 + 128 + arr * 128 + c * 8];
    ushort* dst = arr ? V0s : K0s;
    *(short8*)(void*)&dst[j * 128 + (c ^ (j & 7)) * 8] = v;
  }
  for (int idx = t; idx < 512; idx += 256) {
    int ii = idx >> 7, d = idx & 127;
    Qi[ii][d] = bf2f(QKV[(size_t)(sbase + i0 + ii) * 640 + d]);
  }
  for (int idx = t; idx < 1024; idx += 256) {
    int ii = idx >> 8, e = idx & 255;
    QWs[ii][e] = bf2f(QKV[(size_t)(sbase + i0 + ii) * 640 + 384 + e]);
  }
  if (t < 64) posS[t >> 1][t & 1] = obs[7 * (NPED * 2) + (sbase + (t >> 1)) * 2 + (t & 1)];
  else if (t < 72) {
    int q = t - 64;
    posI[q >> 1][q & 1] = obs[7 * (NPED * 2) + (sbase + i0 + (q >> 1)) * 2 + (q & 1)];
  } else if (t >= 128 && t < 192) {
    int e = t - 128;
    rpx[e] = rpw1[e * 2]; rpy[e] = rpw1[e * 2 + 1]; rpb[e] = rpb1[e];
  }
  __syncthreads();

  for (int idx = t; idx < 1024; idx += 256) {
    int ii = idx >> 8, j = (idx >> 3) & 31, c = idx & 7;
    float dx = posS[j][0] - posI[ii][0], dy = posS[j][1] - posI[ii][1];
    short8 pk;
#pragma unroll
    for (int r = 0; r < 8; ++r) {
      int e = c * 8 + r;
      pk[r] = (short)f2bf(fmaxf(rpx[e] * dx + rpy[e] * dy + rpb[e], 0.f));
    }
    *(short8*)(void*)&renc[(ii * 32 + j) * 64 + (c ^ (j & 7)) * 8] = pk;
  }
  __syncthreads();

  for (int idx = t; idx < 512; idx += 256) {
    int ii = idx >> 7, h = (idx >> 5) & 3, j = idx & 31;
    float s = 0.f;
#pragma unroll
    for (int cc = 0; cc < 4; ++cc) {
      uint4 kv = *(const uint4*)(const void*)&K0s[j * 128 + (((h * 4 + cc) ^ (j & 7)) * 8)];
      const float4 qa = *(const float4*)&Qi[ii][h * 32 + cc * 8];
      const float4 qb = *(const float4*)&Qi[ii][h * 32 + cc * 8 + 4];
      s += blo(kv.x) * qa.x + bhi(kv.x) * qa.y + blo(kv.y) * qa.z + bhi(kv.y) * qa.w;
      s += blo(kv.z) * qb.x + bhi(kv.z) * qb.y + blo(kv.w) * qb.z + bhi(kv.w) * qb.w;
    }
#pragma unroll
    for (int c = 0; c < 8; ++c) {
      uint4 rv = *(const uint4*)(const void*)&renc[(ii * 32 + j) * 64 + ((c ^ (j & 7)) * 8)];
      const float4 ua = *(const float4*)&QWs[ii][h * 64 + c * 8];
      const float4 ub = *(const float4*)&QWs[ii][h * 64 + c * 8 + 4];
      s += blo(rv.x) * ua.x + bhi(rv.x) * ua.y + blo(rv.y) * ua.z + bhi(rv.y) * ua.w;
      s += blo(rv.z) * ub.x + bhi(rv.z) * ub.y + blo(rv.w) * ub.z + bhi(rv.w) * ub.w;
    }
    att[ii][h][j] = s;
  }
  __syncthreads();

  {
    int r = t >> 4, lj = t & 15;
    float v0 = att[r >> 2][r & 3][lj], v1 = att[r >> 2][r & 3][lj + 16];
    float mx = fmaxf(v0, v1);
    mx = fmaxf(mx, __shfl_xor(mx, 8, 16));
    mx = fmaxf(mx, __shfl_xor(mx, 4, 16));
    mx = fmaxf(mx, __shfl_xor(mx, 2, 16));
    mx = fmaxf(mx, __shfl_xor(mx, 1, 16));
    float e0 = expf(v0 - mx), e1 = expf(v1 - mx);
    float sm = e0 + e1;
    sm += __shfl_xor(sm, 8, 16);
    sm += __shfl_xor(sm, 4, 16);
    sm += __shfl_xor(sm, 2, 16);
    sm += __shfl_xor(sm, 1, 16);
    float inv = 1.f / sm;
    att[r >> 2][r & 3][lj] = e0 * inv;
    att[r >> 2][r & 3][lj + 16] = e1 * inv;
  }
  __syncthreads();

  {
    int ii = t >> 6, h = (t >> 4) & 3, e4 = t & 15;
    int c = e4 >> 1, off = (e4 & 1) * 4;
    float a0 = 0.f, a1 = 0.f, a2 = 0.f, a3 = 0.f;
    for (int j = 0; j < 32; ++j) {
      float av = att[ii][h][j];
      uint2 rv = *(const uint2*)(const void*)&renc[(ii * 32 + j) * 64 + ((c ^ (j & 7)) * 8) + off];
      a0 += av * blo(rv.x); a1 += av * bhi(rv.x);
      a2 += av * blo(rv.y); a3 += av * bhi(rv.y);
    }
    *(float4*)&AR[ii][h][e4 * 4] = make_float4(a0, a1, a2, a3);
  }
  __syncthreads();

  {
    int ii = t >> 6, l = t & 63;
    int h5 = l >> 5, hd4 = l & 31;
    int hd = hd4 * 4, h = hd >> 5;
    float c0 = 0.f, c1 = 0.f, c2 = 0.f, c3 = 0.f;
    int cch = hd >> 3, offh = hd & 7;
    for (int j = h5 * 16; j < h5 * 16 + 16; ++j) {
      float av = att[ii][h][j];
      uint2 vv = *(const uint2*)(const void*)&V0s[j * 128 + ((cch ^ (j & 7)) * 8) + offh];
      c0 += av * blo(vv.x); c1 += av * bhi(vv.x);
      c2 += av * blo(vv.y); c3 += av * bhi(vv.y);
    }
    for (int e4 = h5 * 8; e4 < h5 * 8 + 8; ++e4) {
      const float4 ar = *(const float4*)&AR[ii][h][e4 * 4];
#pragma unroll
      for (int r = 0; r < 4; ++r) {
        const float4 wv = *(const float4*)&wv2T[(e4 * 4 + r) * 128 + hd];
        float a = (r == 0) ? ar.x : (r == 1) ? ar.y : (r == 2) ? ar.z : ar.w;
        c0 += a * wv.x; c1 += a * wv.y; c2 += a * wv.z; c3 += a * wv.w;
      }
    }
    c0 += __shfl_xor(c0, 32); c1 += __shfl_xor(c1, 32);
    c2 += __shfl_xor(c2, 32); c3 += __shfl_xor(c3, 32);
    if (h5 == 0) {
      ushort4 o;
      o.x = f2bf(c0); o.y = f2bf(c1); o.z = f2bf(c2); o.w = f2bf(c3);
      *(ushort4*)(void*)&QKV[(size_t)(sbase + i0 + ii) * 640 + hd] = o;
    }
  }
}

extern "C" void kernel_launch(void* const* d_in, const int* in_sizes, int n_in,
                              void* d_out, int out_size, void* d_ws, size_t ws_size,
                              hipStream_t stream) {
  (void)in_sizes; (void)n_in; (void)out_size; (void)ws_size;
  const float* obs  = (const float*)d_in[0];
  const float* pew  = (const float*)d_in[1];
  const float* peb  = (const float*)d_in[2];
  const float* wih  = (const float*)d_in[3];
  const float* bih  = (const float*)d_in[4];
  const float* whh  = (const float*)d_in[5];
  const float* bhh  = (const float*)d_in[6];
  const float* rpw1 = (const float*)d_in[7];
  const float* rpb1 = (const float*)d_in[8];
  const float* rpw2 = (const float*)d_in[9];
  const float* rpb2 = (const float*)d_in[10];
  const float* wq   = (const float*)d_in[11];
  const float* bq   = (const float*)d_in[12];
  const float* wk   = (const float*)d_in[13];
  const float* bk   = (const float*)d_in[14];
  const float* wv   = (const float*)d_in[15];
  const float* bv   = (const float*)d_in[16];
  const float* wo   = (const float*)d_in[17];
  const float* bo   = (const float*)d_in[18];
  const float* opw  = (const float*)d_in[19];
  const float* opb  = (const float*)d_in[20];
  const float* mpw1 = (const float*)d_in[21];
  const float* mpb1 = (const float*)d_in[22];
  const float* mpw2 = (const float*)d_in[23];
  const float* mpb2 = (const float*)d_in[24];
  const float* tdw1 = (const float*)d_in[25];
  const float* tdb1 = (const float*)d_in[26];
  const float* tdw2 = (const float*)d_in[27];
  const float* tdb2 = (const float*)d_in[28];
  const float* tdw3 = (const float*)d_in[29];
  const float* tdb3 = (const float*)d_in[30];
  char* wsb = (char*)d_ws;
  float* out = (float*)d_out;

  ushort* whhb   = (ushort*)(wsb + B_WHH);
  ushort* wqkvb  = (ushort*)(wsb + B_WQKV);
  ushort* wk2pb  = (ushort*)(wsb + B_WK2PAD);
  ushort* opweb  = (ushort*)(wsb + B_OPWE);
  ushort* mpw1b  = (ushort*)(wsb + B_MPW1);
  ushort* tdw1b  = (ushort*)(wsb + B_TDW1);
  ushort* tdw2b  = (ushort*)(wsb + B_TDW2);
  ushort* tdw3cb = (ushort*)(wsb + B_TDW3C);
  ushort* featb  = (ushort*)(wsb + A_FEAT);
  ushort* qkvb   = (ushort*)(wsb + A_QKV);

  prep<<<1910, 256, 0, stream>>>(wih, bih, bhh, pew, peb, wk, wv, rpw2, rpb2,
                                 bq, bk, bv, whh, wq, wo, opw, opb, bo, mpw1,
                                 tdw1, tdw2, tdw3, tdb3, wsb);
  prep2<<<129, 256, 0, stream>>>(wk2pb, wq, bq, wqkvb, (float*)(wsb + F_BQKV));
  lstm_mfma<<<256, 512, 0, stream>>>(obs, whhb, (float*)(wsb + F_WIHE),
                                     (float*)(wsb + F_BEFF), featb);
  // QKV+QW: feat @ [wq_s|wk|wv|wqw]^T + bqkv  -> all 640 cols
  mfma_gemm<4, 4, 4><<<dim3(128, 10), 256, 0, stream>>>(
      featb, 128, featb, 128, wqkvb, (float*)(wsb + F_BQKV), qkvb, 640, 0, 0);
  attn_kernel<<<2048, 256, 0, stream>>>(obs, qkvb, (float*)(wsb + F_WV2T), rpw1, rpb1);
  // EDGE = [feat|ctx] @ [opw1|opw2@wo]^T + bedge  -> cols 256..383
  mfma_gemm<4, 8, 4><<<dim3(128, 2), 256, 0, stream>>>(
      featb, 128, qkvb, 640, opweb, (float*)(wsb + F_BEDGE), qkvb, 640, 256, 0);
  // MP head + probs
  mp_probs<<<256, 256, 0, stream>>>(featb, qkvb, mpw1b, mpb1, mpw2, mpb2, out);
  // TD1+TD2+traj fused per mode
  td_fused<<<dim3(128, 5), 256, 0, stream>>>(featb, qkvb, tdw1b, tdb1, tdw2b, tdb2,
                                             tdw3cb, (float*)(wsb + F_TDB3C), obs, out);
}

// Round 10
// 265.496 us; speedup vs baseline: 3.3096x; 1.0254x over previous
//
#include <hip/hip_runtime.h>
#include <math.h>

typedef __attribute__((ext_vector_type(8))) short short8;
typedef __attribute__((ext_vector_type(4))) float f32x4;

#define NPED 8192
#define INVS 0.1767766952966369f   // 1/sqrt(32)

// ---- workspace layout (BYTE offsets) ----
#define B_WHH    0          // [512][128] bf16
#define B_WQKV   131072     // [640][128] bf16 (wq_s|wk|wv|wqw)
#define B_WK2PAD 294912     // [256][128] bf16
#define B_OPWE   360448     // [128][256] bf16  [opw1 | opw2@wo]
#define B_MPW1   425984     // [128][256] bf16
#define B_TDW1   491520     // [5][128][256] bf16
#define B_TDW2   819200     // [5][128][128] bf16
#define B_TDW3C  983040     // [5][32][128] bf16 prefix-summed tdw3
#define F_WIHE   1024000    // [512][2] f32
#define F_BEFF   1028096    // [512] f32
#define F_WV2T   1030144    // [64][128] f32
#define F_BQKV   1062912    // [640] f32: bq*INVS | bk_eff | bv_eff | qwbias
#define F_BEDGE  1065472    // [128] f32: opb + opw2@bo
#define F_TDB3C  1065984    // [5][24] f32
#define A_FEAT   1066496    // [8192][128] bf16
#define A_QKV    3163648    // [8192][640] bf16: ctx<-Q | K0 | V0 | EDGE | QW
// end ~13.65 MB

__device__ __forceinline__ float bf2f(ushort u) {
  union { unsigned i; float f; } v; v.i = ((unsigned)u) << 16; return v.f;
}
__device__ __forceinline__ float blo(unsigned u) {
  union { unsigned i; float f; } v; v.i = u << 16; return v.f;
}
__device__ __forceinline__ float bhi(unsigned u) {
  union { unsigned i; float f; } v; v.i = u & 0xffff0000u; return v.f;
}
__device__ __forceinline__ ushort f2bf(float f) {
  union { float f; unsigned i; } v; v.f = f;
  unsigned r = v.i + 0x7fffu + ((v.i >> 16) & 1u);
  return (ushort)(r >> 16);
}

__global__ __launch_bounds__(256) void prep(
    const float* __restrict__ wih, const float* __restrict__ bih, const float* __restrict__ bhh,
    const float* __restrict__ pew, const float* __restrict__ peb,
    const float* __restrict__ wk, const float* __restrict__ wv,
    const float* __restrict__ rpw2, const float* __restrict__ rpb2,
    const float* __restrict__ bq, const float* __restrict__ bk, const float* __restrict__ bv,
    const float* __restrict__ whh, const float* __restrict__ wq, const float* __restrict__ wo,
    const float* __restrict__ opw, const float* __restrict__ opb, const float* __restrict__ bo,
    const float* __restrict__ mpw1,
    const float* __restrict__ tdw1, const float* __restrict__ tdw2,
    const float* __restrict__ tdw3, const float* __restrict__ tdb3,
    char* __restrict__ wsb) {
  int tid = blockIdx.x * 256 + threadIdx.x;
  if (tid < 512) {
    int d = tid;
    float s0 = 0.f, s1 = 0.f, sb = 0.f;
    for (int e = 0; e < 64; ++e) {
      float w = wih[d * 64 + e];
      s0 += w * pew[e * 2]; s1 += w * pew[e * 2 + 1]; sb += w * peb[e];
    }
    ((float*)(wsb + F_WIHE))[d * 2] = s0;
    ((float*)(wsb + F_WIHE))[d * 2 + 1] = s1;
    ((float*)(wsb + F_BEFF))[d] = bih[d] + bhh[d] + sb;
  } else if (tid < 49664) {           // wqkv rows 0..383
    int j = tid - 512; int n = j >> 7, k = j & 127;
    float v = (n < 128) ? wq[n * 128 + k] * INVS
                        : (n < 256) ? wk[(n - 128) * 128 + k] : wv[(n - 256) * 128 + k];
    ((ushort*)(wsb + B_WQKV))[j] = f2bf(v);
  } else if (tid < 82432) {           // wk2pad [256][128]
    int idx = tid - 49664; int r = idx >> 7, d = idx & 127;
    int h = r >> 6, e = r & 63;
    float s = 0.f;
    if ((d >> 5) == h)
      for (int c = 0; c < 128; ++c) s += wk[d * 128 + c] * rpw2[c * 64 + e];
    ((ushort*)(wsb + B_WK2PAD))[idx] = f2bf(s);
  } else if (tid < 115200) {          // opwe [128][256]: [opw1 | opw2@wo]
    int idx = tid - 82432; int o = idx >> 8, k = idx & 255;
    float s;
    if (k < 128) s = opw[o * 256 + k];
    else {
      s = 0.f;
      for (int c = 0; c < 128; ++c) s += opw[o * 256 + 128 + c] * wo[c * 128 + (k - 128)];
    }
    ((ushort*)(wsb + B_OPWE))[idx] = f2bf(s);
  } else if (tid < 147968) {          // mpw1
    int j = tid - 115200; ((ushort*)(wsb + B_MPW1))[j] = f2bf(mpw1[j]);
  } else if (tid < 311808) {          // tdw1
    int j = tid - 147968; ((ushort*)(wsb + B_TDW1))[j] = f2bf(tdw1[j]);
  } else if (tid < 393728) {          // tdw2
    int j = tid - 311808; ((ushort*)(wsb + B_TDW2))[j] = f2bf(tdw2[j]);
  } else if (tid < 414208) {          // tdw3c prefix-summed (cols 24..31 zero)
    int j = tid - 393728; int m = j >> 12, r = j & 4095, o = r >> 7, k = r & 127;
    float s = 0.f;
    if (o < 24) {
      int c = o & 1, jj = o >> 1;
      for (int jp = 0; jp <= jj; ++jp) s += tdw3[(m * 24 + jp * 2 + c) * 128 + k];
    }
    ((ushort*)(wsb + B_TDW3C))[j] = f2bf(s);
  } else if (tid < 414328) {          // tdb3c
    int j = tid - 414208; int m = j / 24, o = j % 24;
    int c = o & 1, jj = o >> 1;
    float s = 0.f;
    for (int jp = 0; jp <= jj; ++jp) s += tdb3[m * 24 + jp * 2 + c];
    ((float*)(wsb + F_TDB3C))[j] = s;
  } else if (tid < 414968) {          // bqkv [640] (tail 384+ zero; prep2 fills qwbias)
    int d = tid - 414328;
    float s = 0.f;
    if (d < 128) s = bq[d] * INVS;
    else if (d < 256) {
      int dd = d - 128; s = bk[dd];
      for (int c = 0; c < 128; ++c) s += wk[dd * 128 + c] * rpb2[c];
    } else if (d < 384) {
      int dd = d - 256; s = bv[dd];
      for (int c = 0; c < 128; ++c) s += wv[dd * 128 + c] * rpb2[c];
    }
    ((float*)(wsb + F_BQKV))[d] = s;
  } else if (tid < 415096) {          // bedge = opb + opw2@bo
    int o = tid - 414968;
    float s = opb[o];
    for (int c = 0; c < 128; ++c) s += opw[o * 256 + 128 + c] * bo[c];
    ((float*)(wsb + F_BEDGE))[o] = s;
  } else if (tid < 423288) {          // wv2T [64][128] f32
    int idx = tid - 415096; int e = idx >> 7, hd = idx & 127;
    float s = 0.f;
    for (int c = 0; c < 128; ++c) s += wv[hd * 128 + c] * rpw2[c * 64 + e];
    ((float*)(wsb + F_WV2T))[idx] = s;
  } else if (tid < 488824) {          // whh
    int i = tid - 423288;
    ((ushort*)(wsb + B_WHH))[i] = f2bf(whh[i]);
  }
}

// prep2: wqw rows 384..639 of wqkv  (= wk2pad @ wq_s^T), and qwbias.
__global__ __launch_bounds__(256) void prep2(
    const ushort* __restrict__ wk2pad, const float* __restrict__ wq,
    const float* __restrict__ bq, ushort* __restrict__ wqkv, float* __restrict__ bqkv) {
  int idx = blockIdx.x * 256 + threadIdx.x;
  if (idx < 32768) {
    int e = idx >> 7, k = idx & 127, h = e >> 6;
    float s = 0.f;
    for (int dd = 0; dd < 32; ++dd) {
      int d = h * 32 + dd;
      s += bf2f(wk2pad[e * 128 + d]) * wq[d * 128 + k];
    }
    wqkv[(384 + e) * 128 + k] = f2bf(s * INVS);
  } else if (idx < 33024) {
    int e = idx - 32768, h = e >> 6;
    float s = 0.f;
    for (int dd = 0; dd < 32; ++dd) {
      int d = h * 32 + dd;
      s += bf2f(wk2pad[e * 128 + d]) * bq[d];
    }
    bqkv[384 + e] = s * INVS;
  }
}

// LSTM (unchanged, verified)
__global__ __launch_bounds__(512) void lstm_mfma(
    const float* __restrict__ obs, const ushort* __restrict__ whhb,
    const float* __restrict__ wihe, const float* __restrict__ beff,
    ushort* __restrict__ feat) {
  __shared__ ushort Hs[32 * 128];
  __shared__ float obs_s[8][32][2];
  int tid = threadIdx.x;
  int w = tid >> 6, l = tid & 63;
  int lm = l & 15, lg = l >> 4;
  int nb = blockIdx.x * 32;
  {
    int ts = tid >> 6, p = (tid >> 1) & 31, c = tid & 1;
    obs_s[ts][p][c] = obs[ts * (NPED * 2) + (nb + p) * 2 + c];
  }
  for (int i = tid; i < 4096; i += 512) Hs[i] = 0;
  short8 bfr[4][4];
  float wx0[4], wx1[4], be[4];
#pragma unroll
  for (int q = 0; q < 4; ++q) {
    int g = q * 128 + w * 16 + lm;
    wx0[q] = wihe[g * 2]; wx1[q] = wihe[g * 2 + 1]; be[q] = beff[g];
#pragma unroll
    for (int ks = 0; ks < 4; ++ks)
      bfr[q][ks] = *(const short8*)(const void*)&whhb[g * 128 + ks * 32 + lg * 8];
  }
  float cst[2][4] = {};
  __syncthreads();
  for (int ts = 0; ts < 8; ++ts) {
    f32x4 acc[2][4];
#pragma unroll
    for (int mi = 0; mi < 2; ++mi)
#pragma unroll
      for (int r = 0; r < 4; ++r) {
        int p = mi * 16 + lg * 4 + r;
        float ox = obs_s[ts][p][0], oy = obs_s[ts][p][1];
#pragma unroll
        for (int q = 0; q < 4; ++q)
          acc[mi][q][r] = be[q] + wx0[q] * ox + wx1[q] * oy;
      }
#pragma unroll
    for (int ks = 0; ks < 4; ++ks) {
      int p0 = lm, p1 = 16 + lm;
      short8 a0 = *(const short8*)(const void*)&Hs[p0 * 128 + ((ks * 32 + lg * 8) ^ ((p0 & 7) << 3))];
      short8 a1 = *(const short8*)(const void*)&Hs[p1 * 128 + ((ks * 32 + lg * 8) ^ ((p1 & 7) << 3))];
#pragma unroll
      for (int q = 0; q < 4; ++q) {
        acc[0][q] = __builtin_amdgcn_mfma_f32_16x16x32_bf16(a0, bfr[q][ks], acc[0][q], 0, 0, 0);
        acc[1][q] = __builtin_amdgcn_mfma_f32_16x16x32_bf16(a1, bfr[q][ks], acc[1][q], 0, 0, 0);
      }
    }
    __syncthreads();
    int d = w * 16 + lm;
#pragma unroll
    for (int mi = 0; mi < 2; ++mi)
#pragma unroll
      for (int r = 0; r < 4; ++r) {
        int p = mi * 16 + lg * 4 + r;
        float xi = acc[mi][0][r], xf = acc[mi][1][r], xg = acc[mi][2][r], xo = acc[mi][3][r];
        float ig = 1.f / (1.f + __expf(-xi));
        float fg = 1.f / (1.f + __expf(-xf));
        xg = fminf(fmaxf(xg, -30.f), 30.f);
        float eg = __expf(-2.f * xg);
        float gg = (1.f - eg) / (1.f + eg);
        float og = 1.f / (1.f + __expf(-xo));
        float cv = fg * cst[mi][r] + ig * gg;
        cst[mi][r] = cv;
        float cvc = fminf(fmaxf(cv, -30.f), 30.f);
        float ec = __expf(-2.f * cvc);
        float th = (1.f - ec) / (1.f + ec);
        ushort hb = f2bf(og * th);
        Hs[p * 128 + (d ^ ((p & 7) << 3))] = hb;
        if (ts == 7) feat[(size_t)(nb + p) * 128 + d] = hb;
      }
    __syncthreads();
  }
}

// MFMA GEMM. RS=0: 64 rows, 4 waves in M. RS=1: 32 rows, 2x2 waves (rows x col-halves).
template<int NF, int NKS, int K1KS, int RS>
__global__ __launch_bounds__(256) void mfma_gemm(
    const ushort* __restrict__ A1, int lda1,
    const ushort* __restrict__ A2, int lda2,
    const ushort* __restrict__ Bw,
    const float* __restrict__ bias,
    ushort* __restrict__ out, int ldo, int ooff, int relu) {
  int w = threadIdx.x >> 6, l = threadIdx.x & 63;
  int lm = l & 15, lg = l >> 4;
  int row, col0, orow0;
  if (RS) {
    row = blockIdx.x * 32 + (w >> 1) * 16 + lm;
    col0 = blockIdx.y * (NF * 32) + (w & 1) * (NF * 16);
    orow0 = blockIdx.x * 32 + (w >> 1) * 16 + lg * 4;
  } else {
    row = blockIdx.x * 64 + w * 16 + lm;
    col0 = blockIdx.y * (NF * 16);
    orow0 = blockIdx.x * 64 + w * 16 + lg * 4;
  }
  f32x4 acc[NF];
#pragma unroll
  for (int i = 0; i < NF; ++i) acc[i] = (f32x4){0.f, 0.f, 0.f, 0.f};
#pragma unroll
  for (int ks = 0; ks < NKS; ++ks) {
    int kb = ks * 32 + lg * 8;
    const ushort* ap = (ks < K1KS) ? (A1 + (size_t)row * lda1 + kb)
                                   : (A2 + (size_t)row * lda2 + (kb - K1KS * 32));
    short8 af = *(const short8*)(const void*)ap;
#pragma unroll
    for (int ni = 0; ni < NF; ++ni) {
      short8 bf = *(const short8*)(const void*)(Bw + (size_t)(col0 + ni * 16 + lm) * (NKS * 32) + kb);
      acc[ni] = __builtin_amdgcn_mfma_f32_16x16x32_bf16(af, bf, acc[ni], 0, 0, 0);
    }
  }
#pragma unroll
  for (int ni = 0; ni < NF; ++ni) {
    int c = col0 + ni * 16 + lm;
    float bv = bias[c];
#pragma unroll
    for (int r = 0; r < 4; ++r) {
      float v = acc[ni][r] + bv;
      if (relu) v = fmaxf(v, 0.f);
      out[(size_t)(orow0 + r) * ldo + ooff + c] = f2bf(v);
    }
  }
}

// Tail kernel: grid (256, 6). y<5: TD1->TD2->traj for mode y, 32 rows/block, 2x2 waves.
// y==5: MP gemm + probs epilogue (32 rows/block, col-half waves).
__global__ __launch_bounds__(256) void td_mp(
    const ushort* __restrict__ feat, const ushort* __restrict__ qkv,
    const ushort* __restrict__ w1b, const float* __restrict__ tdb1,
    const ushort* __restrict__ w2b, const float* __restrict__ tdb2,
    const ushort* __restrict__ w3c, const float* __restrict__ b3c,
    const float* __restrict__ mpw1b, const float* __restrict__ mpb1,
    const float* __restrict__ mpw2, const float* __restrict__ mpb2,
    const float* __restrict__ obs, float* __restrict__ out) {
  __shared__ float smem[32 * 72];   // td: slab 32x136 bf16 = 8704 B; mp: w2s+pc
  int t = threadIdx.x, w = t >> 6, l = t & 63, lm = l & 15, lg = l >> 4;
  int wr = w >> 1, wc = w & 1;
  int z = blockIdx.y;

  if (z < 5) {
    ushort* slab = (ushort*)smem;   // [32][136]
    int m = z;
    int row = blockIdx.x * 32 + wr * 16 + lm;
    const ushort* W1 = w1b + (size_t)m * 32768;
    const ushort* W2 = w2b + (size_t)m * 16384;
    const ushort* W3 = w3c + (size_t)m * 4096;
    const float* B1 = tdb1 + m * 128;
    const float* B2 = tdb2 + m * 128;
    // --- TD1: [feat|EDGE] @ W1^T, K=256, wave covers 16 rows x 64 cols ---
    f32x4 a1[4];
#pragma unroll
    for (int i = 0; i < 4; ++i) a1[i] = (f32x4){0.f, 0.f, 0.f, 0.f};
#pragma unroll
    for (int ks = 0; ks < 8; ++ks) {
      int kb = ks * 32 + lg * 8;
      const ushort* ap = (ks < 4) ? (feat + (size_t)row * 128 + kb)
                                  : (qkv + (size_t)row * 640 + 256 + (kb - 128));
      short8 af = *(const short8*)(const void*)ap;
#pragma unroll
      for (int ni = 0; ni < 4; ++ni) {
        short8 bf = *(const short8*)(const void*)(W1 + (size_t)(wc * 64 + ni * 16 + lm) * 256 + kb);
        a1[ni] = __builtin_amdgcn_mfma_f32_16x16x32_bf16(af, bf, a1[ni], 0, 0, 0);
      }
    }
#pragma unroll
    for (int ni = 0; ni < 4; ++ni) {
      int c = wc * 64 + ni * 16 + lm;
      float bb = B1[c];
#pragma unroll
      for (int r = 0; r < 4; ++r)
        slab[(wr * 16 + lg * 4 + r) * 136 + c] = f2bf(fmaxf(a1[ni][r] + bb, 0.f));
    }
    __syncthreads();
    // --- TD2: slab @ W2^T, K=128, in-place (reads before barrier-gated writes) ---
    short8 af2[4];
#pragma unroll
    for (int ks = 0; ks < 4; ++ks)
      af2[ks] = *(const short8*)(const void*)&slab[(wr * 16 + lm) * 136 + ks * 32 + lg * 8];
    f32x4 a2[4];
#pragma unroll
    for (int i = 0; i < 4; ++i) a2[i] = (f32x4){0.f, 0.f, 0.f, 0.f};
#pragma unroll
    for (int ks = 0; ks < 4; ++ks) {
      int kb = ks * 32 + lg * 8;
#pragma unroll
      for (int ni = 0; ni < 4; ++ni) {
        short8 bf = *(const short8*)(const void*)(W2 + (size_t)(wc * 64 + ni * 16 + lm) * 128 + kb);
        a2[ni] = __builtin_amdgcn_mfma_f32_16x16x32_bf16(af2[ks], bf, a2[ni], 0, 0, 0);
      }
    }
    __syncthreads();
#pragma unroll
    for (int ni = 0; ni < 4; ++ni) {
      int c = wc * 64 + ni * 16 + lm;
      float bb = B2[c];
#pragma unroll
      for (int r = 0; r < 4; ++r)
        slab[(wr * 16 + lg * 4 + r) * 136 + c] = f2bf(fmaxf(a2[ni][r] + bb, 0.f));
    }
    __syncthreads();
    // --- traj: slab @ w3c^T; wave covers 16 rows x 16 cols (wc = col half of 32) ---
    short8 af3[4], w3f[4];
#pragma unroll
    for (int ks = 0; ks < 4; ++ks) {
      af3[ks] = *(const short8*)(const void*)&slab[(wr * 16 + lm) * 136 + ks * 32 + lg * 8];
      w3f[ks] = *(const short8*)(const void*)(W3 + (size_t)(wc * 16 + lm) * 128 + ks * 32 + lg * 8);
    }
    f32x4 a3 = (f32x4){0.f, 0.f, 0.f, 0.f};
#pragma unroll
    for (int ks = 0; ks < 4; ++ks)
      a3 = __builtin_amdgcn_mfma_f32_16x16x32_bf16(af3[ks], w3f[ks], a3, 0, 0, 0);
    int o = wc * 16 + lm;
    if (o < 24) {
      float bb = b3c[m * 24 + o];
      int c = o & 1;
#pragma unroll
      for (int r = 0; r < 4; ++r) {
        int n = blockIdx.x * 32 + wr * 16 + lg * 4 + r;
        out[(size_t)n * 120 + m * 24 + o] = a3[r] + bb + obs[7 * (NPED * 2) + n * 2 + c];
      }
    }
  } else {
    // ---- MP + probs ----
    float* w2s = smem;              // [5][128]
    float* pc  = smem + 640;        // [2][16][5]
    for (int i = t; i < 640; i += 256) w2s[(i >> 7) * 128 + (i & 127)] = mpw2[i];
    int g = wr, ch = wc, cb = ch * 64;
    int row = blockIdx.x * 32 + g * 16 + lm;
    f32x4 acc[4];
#pragma unroll
    for (int i = 0; i < 4; ++i) acc[i] = (f32x4){0.f, 0.f, 0.f, 0.f};
#pragma unroll
    for (int ks = 0; ks < 8; ++ks) {
      int kb = ks * 32 + lg * 8;
      const ushort* ap = (ks < 4) ? (feat + (size_t)row * 128 + kb)
                                  : (qkv + (size_t)row * 640 + 256 + (kb - 128));
      short8 af = *(const short8*)(const void*)ap;
#pragma unroll
      for (int ni = 0; ni < 4; ++ni) {
        short8 bf = *(const short8*)(const void*)((const ushort*)mpw1b + (size_t)(cb + ni * 16 + lm) * 256 + kb);
        acc[ni] = __builtin_amdgcn_mfma_f32_16x16x32_bf16(af, bf, acc[ni], 0, 0, 0);
      }
    }
    __syncthreads();
    float bc[4];
#pragma unroll
    for (int ni = 0; ni < 4; ++ni) bc[ni] = mpb1[cb + ni * 16 + lm];
    float lgt[4][5];
#pragma unroll
    for (int r = 0; r < 4; ++r)
#pragma unroll
      for (int m = 0; m < 5; ++m) {
        float s = 0.f;
#pragma unroll
        for (int ni = 0; ni < 4; ++ni)
          s += fmaxf(acc[ni][r] + bc[ni], 0.f) * w2s[m * 128 + cb + ni * 16 + lm];
        lgt[r][m] = s;
      }
#pragma unroll
    for (int mask = 1; mask < 16; mask <<= 1)
#pragma unroll
      for (int r = 0; r < 4; ++r)
#pragma unroll
        for (int m = 0; m < 5; ++m)
          lgt[r][m] += __shfl_xor(lgt[r][m], mask);
    if (ch == 1 && lm < 5) {
#pragma unroll
      for (int r = 0; r < 4; ++r) pc[(g * 16 + lg * 4 + r) * 5 + lm] = lgt[r][lm];
    }
    __syncthreads();
    if (ch == 0 && lm < 5) {
#pragma unroll
      for (int r = 0; r < 4; ++r) {
        float lv[5], mx = -1e30f, sm = 0.f;
#pragma unroll
        for (int m = 0; m < 5; ++m) {
          lv[m] = lgt[r][m] + pc[(g * 16 + lg * 4 + r) * 5 + m] + mpb2[m];
          mx = fmaxf(mx, lv[m]);
        }
#pragma unroll
        for (int m = 0; m < 5; ++m) { lv[m] = expf(lv[m] - mx); sm += lv[m]; }
        int n = blockIdx.x * 32 + g * 16 + lg * 4 + r;
        out[983040 + (size_t)n * 5 + lm] = lv[lm] / sm;
      }
    }
  }
}

// attention (unchanged; row layout 640)
__global__ __launch_bounds__(256) void attn_kernel(
    const float* __restrict__ obs, ushort* QKV,
    const float* __restrict__ wv2T,
    const float* __restrict__ rpw1, const float* __restrict__ rpb1) {
  __shared__ ushort K0s[32 * 128];
  __shared__ ushort V0s[32 * 128];
  __shared__ ushort renc[4 * 32 * 64];
  __shared__ float Qi[4][128];
  __shared__ float QWs[4][256];
  __shared__ float att[4][4][32];
  __shared__ float AR[4][4][64];
  __shared__ float rpx[64], rpy[64], rpb[64];
  __shared__ float posS[32][2];
  __shared__ float posI[4][2];
  int t = threadIdx.x;
  int scene = blockIdx.x & 255, ic = blockIdx.x >> 8;
  int i0 = ic * 4, sbase = scene * 32;

  for (int idx = t; idx < 1024; idx += 256) {
    int arr = idx >> 9, j = (idx >> 4) & 31, c = idx & 15;
    short8 v = *(const short8*)(const void*)&QKV[(size_t)(sbase + j) * 640 + 128 + arr * 128 + c * 8];
    ushort* dst = arr ? V0s : K0s;
    *(short8*)(void*)&dst[j * 128 + (c ^ (j & 7)) * 8] = v;
  }
  for (int idx = t; idx < 512; idx += 256) {
    int ii = idx >> 7, d = idx & 127;
    Qi[ii][d] = bf2f(QKV[(size_t)(sbase + i0 + ii) * 640 + d]);
  }
  for (int idx = t; idx < 1024; idx += 256) {
    int ii = idx >> 8, e = idx & 255;
    QWs[ii][e] = bf2f(QKV[(size_t)(sbase + i0 + ii) * 640 + 384 + e]);
  }
  if (t < 64) posS[t >> 1][t & 1] = obs[7 * (NPED * 2) + (sbase + (t >> 1)) * 2 + (t & 1)];
  else if (t < 72) {
    int q = t - 64;
    posI[q >> 1][q & 1] = obs[7 * (NPED * 2) + (sbase + i0 + (q >> 1)) * 2 + (q & 1)];
  } else if (t >= 128 && t < 192) {
    int e = t - 128;
    rpx[e] = rpw1[e * 2]; rpy[e] = rpw1[e * 2 + 1]; rpb[e] = rpb1[e];
  }
  __syncthreads();

  for (int idx = t; idx < 1024; idx += 256) {
    int ii = idx >> 8, j = (idx >> 3) & 31, c = idx & 7;
    float dx = posS[j][0] - posI[ii][0], dy = posS[j][1] - posI[ii][1];
    short8 pk;
#pragma unroll
    for (int r = 0; r < 8; ++r) {
      int e = c * 8 + r;
      pk[r] = (short)f2bf(fmaxf(rpx[e] * dx + rpy[e] * dy + rpb[e], 0.f));
    }
    *(short8*)(void*)&renc[(ii * 32 + j) * 64 + (c ^ (j & 7)) * 8] = pk;
  }
  __syncthreads();

  for (int idx = t; idx < 512; idx += 256) {
    int ii = idx >> 7, h = (idx >> 5) & 3, j = idx & 31;
    float s = 0.f;
#pragma unroll
    for (int cc = 0; cc < 4; ++cc) {
      uint4 kv = *(const uint4*)(const void*)&K0s[j * 128 + (((h * 4 + cc) ^ (j & 7)) * 8)];
      const float4 qa = *(const float4*)&Qi[ii][h * 32 + cc * 8];
      const float4 qb = *(const float4*)&Qi[ii][h * 32 + cc * 8 + 4];
      s += blo(kv.x) * qa.x + bhi(kv.x) * qa.y + blo(kv.y) * qa.z + bhi(kv.y) * qa.w;
      s += blo(kv.z) * qb.x + bhi(kv.z) * qb.y + blo(kv.w) * qb.z + bhi(kv.w) * qb.w;
    }
#pragma unroll
    for (int c = 0; c < 8; ++c) {
      uint4 rv = *(const uint4*)(const void*)&renc[(ii * 32 + j) * 64 + ((c ^ (j & 7)) * 8)];
      const float4 ua = *(const float4*)&QWs[ii][h * 64 + c * 8];
      const float4 ub = *(const float4*)&QWs[ii][h * 64 + c * 8 + 4];
      s += blo(rv.x) * ua.x + bhi(rv.x) * ua.y + blo(rv.y) * ua.z + bhi(rv.y) * ua.w;
      s += blo(rv.z) * ub.x + bhi(rv.z) * ub.y + blo(rv.w) * ub.z + bhi(rv.w) * ub.w;
    }
    att[ii][h][j] = s;
  }
  __syncthreads();

  {
    int r = t >> 4, lj = t & 15;
    float v0 = att[r >> 2][r & 3][lj], v1 = att[r >> 2][r & 3][lj + 16];
    float mx = fmaxf(v0, v1);
    mx = fmaxf(mx, __shfl_xor(mx, 8, 16));
    mx = fmaxf(mx, __shfl_xor(mx, 4, 16));
    mx = fmaxf(mx, __shfl_xor(mx, 2, 16));
    mx = fmaxf(mx, __shfl_xor(mx, 1, 16));
    float e0 = expf(v0 - mx), e1 = expf(v1 - mx);
    float sm = e0 + e1;
    sm += __shfl_xor(sm, 8, 16);
    sm += __shfl_xor(sm, 4, 16);
    sm += __shfl_xor(sm, 2, 16);
    sm += __shfl_xor(sm, 1, 16);
    float inv = 1.f / sm;
    att[r >> 2][r & 3][lj] = e0 * inv;
    att[r >> 2][r & 3][lj + 16] = e1 * inv;
  }
  __syncthreads();

  {
    int ii = t >> 6, h = (t >> 4) & 3, e4 = t & 15;
    int c = e4 >> 1, off = (e4 & 1) * 4;
    float a0 = 0.f, a1 = 0.f, a2 = 0.f, a3 = 0.f;
    for (int j = 0; j < 32; ++j) {
      float av = att[ii][h][j];
      uint2 rv = *(const uint2*)(const void*)&renc[(ii * 32 + j) * 64 + ((c ^ (j & 7)) * 8) + off];
      a0 += av * blo(rv.x); a1 += av * bhi(rv.x);
      a2 += av * blo(rv.y); a3 += av * bhi(rv.y);
    }
    *(float4*)&AR[ii][h][e4 * 4] = make_float4(a0, a1, a2, a3);
  }
  __syncthreads();

  {
    int ii = t >> 6, l = t & 63;
    int h5 = l >> 5, hd4 = l & 31;
    int hd = hd4 * 4, h = hd >> 5;
    float c0 = 0.f, c1 = 0.f, c2 = 0.f, c3 = 0.f;
    int cch = hd >> 3, offh = hd & 7;
    for (int j = h5 * 16; j < h5 * 16 + 16; ++j) {
      float av = att[ii][h][j];
      uint2 vv = *(const uint2*)(const void*)&V0s[j * 128 + ((cch ^ (j & 7)) * 8) + offh];
      c0 += av * blo(vv.x); c1 += av * bhi(vv.x);
      c2 += av * blo(vv.y); c3 += av * bhi(vv.y);
    }
    for (int e4 = h5 * 8; e4 < h5 * 8 + 8; ++e4) {
      const float4 ar = *(const float4*)&AR[ii][h][e4 * 4];
#pragma unroll
      for (int r = 0; r < 4; ++r) {
        const float4 wv = *(const float4*)&wv2T[(e4 * 4 + r) * 128 + hd];
        float a = (r == 0) ? ar.x : (r == 1) ? ar.y : (r == 2) ? ar.z : ar.w;
        c0 += a * wv.x; c1 += a * wv.y; c2 += a * wv.z; c3 += a * wv.w;
      }
    }
    c0 += __shfl_xor(c0, 32); c1 += __shfl_xor(c1, 32);
    c2 += __shfl_xor(c2, 32); c3 += __shfl_xor(c3, 32);
    if (h5 == 0) {
      ushort4 o;
      o.x = f2bf(c0); o.y = f2bf(c1); o.z = f2bf(c2); o.w = f2bf(c3);
      *(ushort4*)(void*)&QKV[(size_t)(sbase + i0 + ii) * 640 + hd] = o;
    }
  }
}

extern "C" void kernel_launch(void* const* d_in, const int* in_sizes, int n_in,
                              void* d_out, int out_size, void* d_ws, size_t ws_size,
                              hipStream_t stream) {
  (void)in_sizes; (void)n_in; (void)out_size; (void)ws_size;
  const float* obs  = (const float*)d_in[0];
  const float* pew  = (const float*)d_in[1];
  const float* peb  = (const float*)d_in[2];
  const float* wih  = (const float*)d_in[3];
  const float* bih  = (const float*)d_in[4];
  const float* whh  = (const float*)d_in[5];
  const float* bhh  = (const float*)d_in[6];
  const float* rpw1 = (const float*)d_in[7];
  const float* rpb1 = (const float*)d_in[8];
  const float* rpw2 = (const float*)d_in[9];
  const float* rpb2 = (const float*)d_in[10];
  const float* wq   = (const float*)d_in[11];
  const float* bq   = (const float*)d_in[12];
  const float* wk   = (const float*)d_in[13];
  const float* bk   = (const float*)d_in[14];
  const float* wv   = (const float*)d_in[15];
  const float* bv   = (const float*)d_in[16];
  const float* wo   = (const float*)d_in[17];
  const float* bo   = (const float*)d_in[18];
  const float* opw  = (const float*)d_in[19];
  const float* opb  = (const float*)d_in[20];
  const float* mpw1 = (const float*)d_in[21];
  const float* mpb1 = (const float*)d_in[22];
  const float* mpw2 = (const float*)d_in[23];
  const float* mpb2 = (const float*)d_in[24];
  const float* tdw1 = (const float*)d_in[25];
  const float* tdb1 = (const float*)d_in[26];
  const float* tdw2 = (const float*)d_in[27];
  const float* tdb2 = (const float*)d_in[28];
  const float* tdw3 = (const float*)d_in[29];
  const float* tdb3 = (const float*)d_in[30];
  char* wsb = (char*)d_ws;
  float* out = (float*)d_out;

  ushort* whhb   = (ushort*)(wsb + B_WHH);
  ushort* wqkvb  = (ushort*)(wsb + B_WQKV);
  ushort* wk2pb  = (ushort*)(wsb + B_WK2PAD);
  ushort* opweb  = (ushort*)(wsb + B_OPWE);
  ushort* mpw1b  = (ushort*)(wsb + B_MPW1);
  ushort* tdw1b  = (ushort*)(wsb + B_TDW1);
  ushort* tdw2b  = (ushort*)(wsb + B_TDW2);
  ushort* tdw3cb = (ushort*)(wsb + B_TDW3C);
  ushort* featb  = (ushort*)(wsb + A_FEAT);
  ushort* qkvb   = (ushort*)(wsb + A_QKV);

  prep<<<1910, 256, 0, stream>>>(wih, bih, bhh, pew, peb, wk, wv, rpw2, rpb2,
                                 bq, bk, bv, whh, wq, wo, opw, opb, bo, mpw1,
                                 tdw1, tdw2, tdw3, tdb3, wsb);
  prep2<<<129, 256, 0, stream>>>(wk2pb, wq, bq, wqkvb, (float*)(wsb + F_BQKV));
  lstm_mfma<<<256, 512, 0, stream>>>(obs, whhb, (float*)(wsb + F_WIHE),
                                     (float*)(wsb + F_BEFF), featb);
  // QKV+QW: feat @ [wq_s|wk|wv|wqw]^T + bqkv  -> all 640 cols
  mfma_gemm<4, 4, 4, 0><<<dim3(128, 10), 256, 0, stream>>>(
      featb, 128, featb, 128, wqkvb, (float*)(wsb + F_BQKV), qkvb, 640, 0, 0);
  attn_kernel<<<2048, 256, 0, stream>>>(obs, qkvb, (float*)(wsb + F_WV2T), rpw1, rpb1);
  // EDGE = [feat|ctx] @ [opw1|opw2@wo]^T + bedge -> cols 256..383 (32-row split blocks)
  mfma_gemm<2, 8, 4, 1><<<dim3(256, 2), 256, 0, stream>>>(
      featb, 128, qkvb, 640, opweb, (float*)(wsb + F_BEDGE), qkvb, 640, 256, 0);
  // Tail: TD1+TD2+traj (modes 0..4) and MP+probs (y==5), one dispatch
  td_mp<<<dim3(256, 6), 256, 0, stream>>>(featb, qkvb, tdw1b, tdb1, tdw2b, tdb2,
                                          tdw3cb, (float*)(wsb + F_TDB3C),
                                          (const float*)mpw1b, mpb1, mpw2, mpb2, obs, out);
}